// Round 1
// baseline (14506.038 us; speedup 1.0000x reference)
//
#include <hip/hip_runtime.h>
#include <cmath>
#include <cstdint>
#include <cstddef>

#define B_   4
#define L_   2048
#define E_   512
#define H_   8
#define DH_  64
#define M_   2048
#define NL_  4
#define NB_  32
#define BS_  64

// ---------------------------------------------------------------------------
// MT19937 (numpy legacy RandomState) replication for the BigBird random blocks
// ---------------------------------------------------------------------------
struct MT19937 {
    unsigned key[624];
    int pos;
};

__device__ void mt_seed(MT19937& st, unsigned seed) {
    for (int i = 0; i < 624; ++i) {
        st.key[i] = seed;
        seed = 1812433253u * (seed ^ (seed >> 30)) + (unsigned)i + 1u;
    }
    st.pos = 624;
}

__device__ unsigned mt_next(MT19937& st) {
    if (st.pos >= 624) {
        for (int i = 0; i < 624; ++i) {
            unsigned y = (st.key[i] & 0x80000000u) | (st.key[(i + 1) % 624] & 0x7fffffffu);
            st.key[i] = st.key[(i + 397) % 624] ^ (y >> 1) ^ ((y & 1u) ? 0x9908b0dfu : 0u);
        }
        st.pos = 0;
    }
    unsigned y = st.key[st.pos++];
    y ^= y >> 11;
    y ^= (y << 7) & 0x9d2c5680u;
    y ^= (y << 15) & 0xefc60000u;
    y ^= y >> 18;
    return y;
}

__device__ unsigned mt_interval(MT19937& st, unsigned maxv) {
    if (maxv == 0u) return 0u;
    unsigned mask = maxv;
    mask |= mask >> 1; mask |= mask >> 2; mask |= mask >> 4;
    mask |= mask >> 8; mask |= mask >> 16;
    unsigned v;
    do { v = mt_next(st) & mask; } while (v > maxv);
    return v;
}

__global__ void mask_kernel(unsigned* __restrict__ maskbits) {
    if (threadIdx.x != 0 || blockIdx.x != 0) return;
    MT19937 st;
    for (int lyr = 0; lyr < NL_; ++lyr) {
        unsigned m[NB_];
        for (int i = 0; i < NB_; ++i) {
            unsigned w = (1u << i);
            if (i > 0) w |= 1u << (i - 1);
            if (i < NB_ - 1) w |= 1u << (i + 1);
            w |= 1u | (1u << (NB_ - 1));   // global cols 0 and 31
            m[i] = w;
        }
        m[0] = 0xffffffffu;                // global rows
        m[NB_ - 1] = 0xffffffffu;
        mt_seed(st, (unsigned)lyr);
        for (int i = 1; i < NB_ - 1; ++i) {
            int cand[NB_];
            int n = 0;
            for (int j = 0; j < NB_; ++j) {
                if (j == 0 || j == NB_ - 1 || j == i - 1 || j == i || j == i + 1) continue;
                cand[n++] = j;
            }
            // numpy shuffle: for i in reversed(range(1,n)): j = interval(i); swap
            for (int kk = n - 1; kk >= 1; --kk) {
                int jj = (int)mt_interval(st, (unsigned)kk);
                int tmp = cand[kk]; cand[kk] = cand[jj]; cand[jj] = tmp;
            }
            m[i] |= (1u << cand[0]) | (1u << cand[1]) | (1u << cand[2]);
        }
        for (int i = 0; i < NB_; ++i) maskbits[lyr * NB_ + i] = m[i];
    }
}

// ---------------------------------------------------------------------------
// Embedding + sinusoidal PE
// ---------------------------------------------------------------------------
__global__ __launch_bounds__(256) void embed_kernel(const int* __restrict__ tokens,
                                                    const float* __restrict__ embed,
                                                    float* __restrict__ x) {
    size_t i = (size_t)blockIdx.x * 256 + threadIdx.x;   // < B*L*E
    int e = (int)(i & (E_ - 1));
    size_t bl = i >> 9;
    int l = (int)(bl & (L_ - 1));
    int tok = tokens[bl];
    int j = e & 255;
    float div = expf((float)j * -0.03597789207717895f);  // -ln(10000)/256
    float arg = (float)l * div;
    float pe = (e < 256) ? sinf(arg) : cosf(arg);
    x[i] = embed[(size_t)tok * E_ + e] + pe;
}

// ---------------------------------------------------------------------------
// LayerNorm (two-pass, one block per row of E=512)
// ---------------------------------------------------------------------------
__global__ __launch_bounds__(256) void ln_kernel(const float* __restrict__ x,
                                                 const float* __restrict__ gamma,
                                                 const float* __restrict__ beta,
                                                 float* __restrict__ y) {
    __shared__ float sh[4];
    int row = blockIdx.x, t = threadIdx.x;
    const float* xr = x + (size_t)row * E_;
    float a = xr[t], c = xr[t + 256];
    float s = a + c;
    #pragma unroll
    for (int off = 1; off < 64; off <<= 1) s += __shfl_xor(s, off, 64);
    if ((t & 63) == 0) sh[t >> 6] = s;
    __syncthreads();
    s = sh[0] + sh[1] + sh[2] + sh[3];
    float mu = s * (1.0f / E_);
    float da = a - mu, dc = c - mu;
    float q = da * da + dc * dc;
    __syncthreads();   // done reading sh from pass 1
    #pragma unroll
    for (int off = 1; off < 64; off <<= 1) q += __shfl_xor(q, off, 64);
    if ((t & 63) == 0) sh[t >> 6] = q;
    __syncthreads();
    q = sh[0] + sh[1] + sh[2] + sh[3];
    float rstd = rsqrtf(q * (1.0f / E_) + 1e-6f);
    float* yr = y + (size_t)row * E_;
    yr[t]       = da * rstd * gamma[t] + beta[t];
    yr[t + 256] = dc * rstd * gamma[t + 256] + beta[t + 256];
}

// ---------------------------------------------------------------------------
// FP32 tiled GEMM: C[M,N] = act(A[M,K]*W[K,N] + bias) + res
// ACT: 0 none, 1 tanh-gelu. bias/res nullable. 64x64 tile, TK=16, 256 thr.
// ---------------------------------------------------------------------------
__device__ __forceinline__ float gelu_tanh(float x) {
    float x3 = x * x * x;
    return 0.5f * x * (1.0f + tanhf(0.7978845608028654f * (x + 0.044715f * x3)));
}

template<int ACT>
__global__ __launch_bounds__(256) void gemm_kernel(const float* __restrict__ A,
                                                   const float* __restrict__ W,
                                                   const float* __restrict__ bias,
                                                   const float* __restrict__ res,
                                                   float* __restrict__ C,
                                                   int M, int N, int K) {
    __shared__ float As[64][17];
    __shared__ float Ws[16][64];
    int t = threadIdx.x;
    int bcol = blockIdx.x * 64, brow = blockIdx.y * 64;
    int tr = t >> 4, tc = t & 15;
    float acc[4][4] = {};
    for (int k0 = 0; k0 < K; k0 += 16) {
        #pragma unroll
        for (int it = 0; it < 4; ++it) {
            int idx = t + it * 256;
            int rr = idx >> 4, cc = idx & 15;
            As[rr][cc] = A[(size_t)(brow + rr) * K + k0 + cc];
        }
        #pragma unroll
        for (int it = 0; it < 4; ++it) {
            int idx = t + it * 256;
            int kk = idx >> 6, cc = idx & 63;
            Ws[kk][cc] = W[(size_t)(k0 + kk) * N + bcol + cc];
        }
        __syncthreads();
        #pragma unroll
        for (int kk = 0; kk < 16; ++kk) {
            float a[4], b[4];
            #pragma unroll
            for (int i = 0; i < 4; ++i) a[i] = As[tr * 4 + i][kk];
            #pragma unroll
            for (int j = 0; j < 4; ++j) b[j] = Ws[kk][tc * 4 + j];
            #pragma unroll
            for (int i = 0; i < 4; ++i)
                #pragma unroll
                for (int j = 0; j < 4; ++j)
                    acc[i][j] += a[i] * b[j];
        }
        __syncthreads();
    }
    #pragma unroll
    for (int i = 0; i < 4; ++i) {
        int row = brow + tr * 4 + i;
        #pragma unroll
        for (int j = 0; j < 4; ++j) {
            int col = bcol + tc * 4 + j;
            float vv = acc[i][j];
            if (bias) vv += bias[col];
            if (ACT == 1) vv = gelu_tanh(vv);
            if (res) vv += res[(size_t)row * N + col];
            C[(size_t)row * N + col] = vv;
        }
    }
}

// ---------------------------------------------------------------------------
// Sparse block attention (flash-style over active 64x64 blocks)
// grid: (32 qblocks, H, B), 256 threads. thread t: row r=t>>2, group g=t&3
// q,k,v,o layout: [B, L, H, DH]
// ---------------------------------------------------------------------------
__global__ __launch_bounds__(256) void attn_kernel(const float* __restrict__ q,
                                                   const float* __restrict__ k,
                                                   const float* __restrict__ v,
                                                   const int* __restrict__ tokens,
                                                   const unsigned* __restrict__ maskrow,
                                                   float* __restrict__ o) {
    __shared__ float Qs[64][65];
    __shared__ float Ks[64][65];
    __shared__ float Vs[64][65];
    __shared__ float Ps[64][65];
    __shared__ int padk_s[64];
    int qb = blockIdx.x, h = blockIdx.y, b = blockIdx.z;
    unsigned rowm = maskrow[qb];
    int t = threadIdx.x;
    int r = t >> 2, g = t & 3;
    for (int i = t; i < 64 * 64; i += 256) {
        int rr = i >> 6, dd = i & 63;
        int l = qb * 64 + rr;
        Qs[rr][dd] = q[(((size_t)b * L_ + l) * H_ + h) * DH_ + dd] * 0.125f;  // 1/sqrt(DH)
    }
    int lq = qb * 64 + r;
    bool padq = tokens[b * L_ + lq] > 0;
    float m_r = -INFINITY, l_r = 0.0f;
    float acc[16];
    #pragma unroll
    for (int dd = 0; dd < 16; ++dd) acc[dd] = 0.0f;
    __syncthreads();
    for (int jb = 0; jb < NB_; ++jb) {
        if (!((rowm >> jb) & 1u)) continue;
        __syncthreads();   // previous iteration done with Ks/Vs/Ps
        for (int i = t; i < 64 * 64; i += 256) {
            int cc = i >> 6, dd = i & 63;
            size_t base = (((size_t)b * L_ + jb * 64 + cc) * H_ + h) * DH_ + dd;
            Ks[cc][dd] = k[base];
            Vs[cc][dd] = v[base];
        }
        if (t < 64) padk_s[t] = tokens[b * L_ + jb * 64 + t] > 0;
        __syncthreads();
        float s[16];
        unsigned actm = 0;
        float lmax = -INFINITY;
        #pragma unroll
        for (int cc = 0; cc < 16; ++cc) {
            int col = g * 16 + cc;
            float sv = 0.0f;
            for (int kk = 0; kk < 64; ++kk) sv += Qs[r][kk] * Ks[col][kk];
            s[cc] = sv;
            if (padq && padk_s[col] != 0) {
                actm |= 1u << cc;
                lmax = fmaxf(lmax, sv);
            }
        }
        lmax = fmaxf(lmax, __shfl_xor(lmax, 1, 64));
        lmax = fmaxf(lmax, __shfl_xor(lmax, 2, 64));
        float newmax = fmaxf(m_r, lmax);
        float psum = 0.0f;
        #pragma unroll
        for (int cc = 0; cc < 16; ++cc) {
            float p = ((actm >> cc) & 1u) ? expf(s[cc] - newmax) : 0.0f;
            Ps[r][g * 16 + cc] = p;
            psum += p;
        }
        psum += __shfl_xor(psum, 1, 64);
        psum += __shfl_xor(psum, 2, 64);
        float alpha = (newmax == -INFINITY) ? 1.0f : expf(m_r - newmax);
        m_r = newmax;
        l_r = l_r * alpha + psum;
        #pragma unroll
        for (int dd = 0; dd < 16; ++dd) acc[dd] *= alpha;
        __syncthreads();   // Ps fully written
        for (int c = 0; c < 64; ++c) {
            float p = Ps[r][c];
            #pragma unroll
            for (int dd = 0; dd < 16; ++dd) acc[dd] += p * Vs[c][g * 16 + dd];
        }
    }
    size_t obase = (((size_t)b * L_ + lq) * H_ + h) * DH_ + g * 16;
    if (padq && l_r > 0.0f) {
        float inv = 1.0f / l_r;
        #pragma unroll
        for (int dd = 0; dd < 16; ++dd) o[obase + dd] = acc[dd] * inv;
    } else {
        // fully-masked row: softmax over all -1e9 -> uniform 1/L -> mean of V
        float sum[16];
        #pragma unroll
        for (int dd = 0; dd < 16; ++dd) sum[dd] = 0.0f;
        for (int l = 0; l < L_; ++l) {
            size_t vb = (((size_t)b * L_ + l) * H_ + h) * DH_ + g * 16;
            #pragma unroll
            for (int dd = 0; dd < 16; ++dd) sum[dd] += v[vb + dd];
        }
        #pragma unroll
        for (int dd = 0; dd < 16; ++dd) o[obase + dd] = sum[dd] * (1.0f / L_);
    }
}

// ---------------------------------------------------------------------------
// Launch
// ---------------------------------------------------------------------------
extern "C" void kernel_launch(void* const* d_in, const int* in_sizes, int n_in,
                              void* d_out, int out_size, void* d_ws, size_t ws_size,
                              hipStream_t stream) {
    (void)in_sizes; (void)n_in; (void)out_size; (void)ws_size;
    const int*   tokens = (const int*)d_in[0];
    const float* embed  = (const float*)d_in[1];
    const float* ln1_s  = (const float*)d_in[2];
    const float* ln1_b  = (const float*)d_in[3];
    const float* wq     = (const float*)d_in[4];
    const float* wk     = (const float*)d_in[5];
    const float* wv     = (const float*)d_in[6];
    const float* wo     = (const float*)d_in[7];
    const float* ln2_s  = (const float*)d_in[8];
    const float* ln2_b  = (const float*)d_in[9];
    const float* w1     = (const float*)d_in[10];
    const float* b1     = (const float*)d_in[11];
    const float* w2     = (const float*)d_in[12];
    const float* b2     = (const float*)d_in[13];
    const float* lnf_s  = (const float*)d_in[14];
    const float* lnf_b  = (const float*)d_in[15];
    float* out = (float*)d_out;

    const size_t BLE = (size_t)B_ * L_ * E_;          // 4M floats = 16 MB
    char* ws = (char*)d_ws;
    unsigned* maskbits = (unsigned*)ws;               // NL*32 words
    float* x  = (float*)(ws + 1024);
    float* y  = x + BLE;
    float* R  = y + BLE;                              // 64 MB shared region
    float* qb = R;
    float* kb = qb + BLE;
    float* vb = kb + BLE;
    float* ob = vb + BLE;
    float* hb = R;                                    // reuses q/k/v/o after out-proj

    mask_kernel<<<1, 64, 0, stream>>>(maskbits);
    embed_kernel<<<(unsigned)(BLE / 256), 256, 0, stream>>>(tokens, embed, x);

    dim3 g512(512 / 64, (B_ * L_) / 64);
    dim3 g2048(2048 / 64, (B_ * L_) / 64);
    for (int lyr = 0; lyr < NL_; ++lyr) {
        ln_kernel<<<B_ * L_, 256, 0, stream>>>(x, ln1_s + lyr * E_, ln1_b + lyr * E_, y);
        gemm_kernel<0><<<g512, 256, 0, stream>>>(y, wq + (size_t)lyr * E_ * E_, nullptr, nullptr, qb, B_ * L_, 512, 512);
        gemm_kernel<0><<<g512, 256, 0, stream>>>(y, wk + (size_t)lyr * E_ * E_, nullptr, nullptr, kb, B_ * L_, 512, 512);
        gemm_kernel<0><<<g512, 256, 0, stream>>>(y, wv + (size_t)lyr * E_ * E_, nullptr, nullptr, vb, B_ * L_, 512, 512);
        attn_kernel<<<dim3(NB_, H_, B_), 256, 0, stream>>>(qb, kb, vb, tokens, maskbits + lyr * NB_, ob);
        gemm_kernel<0><<<g512, 256, 0, stream>>>(ob, wo + (size_t)lyr * E_ * E_, nullptr, x, x, B_ * L_, 512, 512);
        ln_kernel<<<B_ * L_, 256, 0, stream>>>(x, ln2_s + lyr * E_, ln2_b + lyr * E_, y);
        gemm_kernel<1><<<g2048, 256, 0, stream>>>(y, w1 + (size_t)lyr * E_ * M_, b1 + (size_t)lyr * M_, nullptr, hb, B_ * L_, M_, E_);
        gemm_kernel<0><<<g512, 256, 0, stream>>>(hb, w2 + (size_t)lyr * M_ * E_, b2 + (size_t)lyr * E_, x, x, B_ * L_, E_, M_);
    }
    ln_kernel<<<B_ * L_, 256, 0, stream>>>(x, lnf_s, lnf_b, out);
}

// Round 2
// 6078.555 us; speedup vs baseline: 2.3864x; 2.3864x over previous
//
#include <hip/hip_runtime.h>
#include <hip/hip_bf16.h>
#include <cmath>
#include <cstdint>
#include <cstddef>

#define B_   4
#define L_   2048
#define E_   512
#define H_   8
#define DH_  64
#define M_   2048
#define NL_  4
#define NB_  32
#define BS_  64

typedef short bf16x8 __attribute__((ext_vector_type(8)));
typedef float f32x4 __attribute__((ext_vector_type(4)));

__device__ __forceinline__ short f2bf(float f) {
    union { __hip_bfloat16 h; short s; } u;
    u.h = __float2bfloat16(f);
    return u.s;
}

// ---------------------------------------------------------------------------
// MT19937 (numpy legacy RandomState) replication for the BigBird random blocks
// ---------------------------------------------------------------------------
struct MT19937 {
    unsigned key[624];
    int pos;
};

__device__ void mt_seed(MT19937& st, unsigned seed) {
    for (int i = 0; i < 624; ++i) {
        st.key[i] = seed;
        seed = 1812433253u * (seed ^ (seed >> 30)) + (unsigned)i + 1u;
    }
    st.pos = 624;
}

__device__ unsigned mt_next(MT19937& st) {
    if (st.pos >= 624) {
        for (int i = 0; i < 624; ++i) {
            unsigned y = (st.key[i] & 0x80000000u) | (st.key[(i + 1) % 624] & 0x7fffffffu);
            st.key[i] = st.key[(i + 397) % 624] ^ (y >> 1) ^ ((y & 1u) ? 0x9908b0dfu : 0u);
        }
        st.pos = 0;
    }
    unsigned y = st.key[st.pos++];
    y ^= y >> 11;
    y ^= (y << 7) & 0x9d2c5680u;
    y ^= (y << 15) & 0xefc60000u;
    y ^= y >> 18;
    return y;
}

__device__ unsigned mt_interval(MT19937& st, unsigned maxv) {
    if (maxv == 0u) return 0u;
    unsigned mask = maxv;
    mask |= mask >> 1; mask |= mask >> 2; mask |= mask >> 4;
    mask |= mask >> 8; mask |= mask >> 16;
    unsigned v;
    do { v = mt_next(st) & mask; } while (v > maxv);
    return v;
}

__global__ void mask_kernel(unsigned* __restrict__ maskbits) {
    if (threadIdx.x != 0 || blockIdx.x != 0) return;
    MT19937 st;
    for (int lyr = 0; lyr < NL_; ++lyr) {
        unsigned m[NB_];
        for (int i = 0; i < NB_; ++i) {
            unsigned w = (1u << i);
            if (i > 0) w |= 1u << (i - 1);
            if (i < NB_ - 1) w |= 1u << (i + 1);
            w |= 1u | (1u << (NB_ - 1));   // global cols 0 and 31
            m[i] = w;
        }
        m[0] = 0xffffffffu;                // global rows
        m[NB_ - 1] = 0xffffffffu;
        mt_seed(st, (unsigned)lyr);
        for (int i = 1; i < NB_ - 1; ++i) {
            int cand[NB_];
            int n = 0;
            for (int j = 0; j < NB_; ++j) {
                if (j == 0 || j == NB_ - 1 || j == i - 1 || j == i || j == i + 1) continue;
                cand[n++] = j;
            }
            for (int kk = n - 1; kk >= 1; --kk) {
                int jj = (int)mt_interval(st, (unsigned)kk);
                int tmp = cand[kk]; cand[kk] = cand[jj]; cand[jj] = tmp;
            }
            m[i] |= (1u << cand[0]) | (1u << cand[1]) | (1u << cand[2]);
        }
        for (int i = 0; i < NB_; ++i) maskbits[lyr * NB_ + i] = m[i];
    }
}

// ---------------------------------------------------------------------------
// Embedding + sinusoidal PE
// ---------------------------------------------------------------------------
__global__ __launch_bounds__(256) void embed_kernel(const int* __restrict__ tokens,
                                                    const float* __restrict__ embed,
                                                    float* __restrict__ x) {
    size_t i = (size_t)blockIdx.x * 256 + threadIdx.x;   // < B*L*E
    int e = (int)(i & (E_ - 1));
    size_t bl = i >> 9;
    int l = (int)(bl & (L_ - 1));
    int tok = tokens[bl];
    int j = e & 255;
    float div = expf((float)j * -0.03597789207717895f);  // -ln(10000)/256
    float arg = (float)l * div;
    float pe = (e < 256) ? sinf(arg) : cosf(arg);
    x[i] = embed[(size_t)tok * E_ + e] + pe;
}

// ---------------------------------------------------------------------------
// LayerNorm (two-pass, one block per row of E=512)
// ---------------------------------------------------------------------------
__global__ __launch_bounds__(256) void ln_kernel(const float* __restrict__ x,
                                                 const float* __restrict__ gamma,
                                                 const float* __restrict__ beta,
                                                 float* __restrict__ y) {
    __shared__ float sh[4];
    int row = blockIdx.x, t = threadIdx.x;
    const float* xr = x + (size_t)row * E_;
    float a = xr[t], c = xr[t + 256];
    float s = a + c;
    #pragma unroll
    for (int off = 1; off < 64; off <<= 1) s += __shfl_xor(s, off, 64);
    if ((t & 63) == 0) sh[t >> 6] = s;
    __syncthreads();
    s = sh[0] + sh[1] + sh[2] + sh[3];
    float mu = s * (1.0f / E_);
    float da = a - mu, dc = c - mu;
    float q = da * da + dc * dc;
    __syncthreads();
    #pragma unroll
    for (int off = 1; off < 64; off <<= 1) q += __shfl_xor(q, off, 64);
    if ((t & 63) == 0) sh[t >> 6] = q;
    __syncthreads();
    q = sh[0] + sh[1] + sh[2] + sh[3];
    float rstd = rsqrtf(q * (1.0f / E_) + 1e-6f);
    float* yr = y + (size_t)row * E_;
    yr[t]       = da * rstd * gamma[t] + beta[t];
    yr[t + 256] = dc * rstd * gamma[t + 256] + beta[t + 256];
}

// ---------------------------------------------------------------------------
// FP32 tiled GEMM: C[M,N] = act(A[M,K]*W[K,N] + bias) + res
// ---------------------------------------------------------------------------
__device__ __forceinline__ float gelu_tanh(float x) {
    float x3 = x * x * x;
    return 0.5f * x * (1.0f + tanhf(0.7978845608028654f * (x + 0.044715f * x3)));
}

template<int ACT>
__global__ __launch_bounds__(256) void gemm_kernel(const float* __restrict__ A,
                                                   const float* __restrict__ W,
                                                   const float* __restrict__ bias,
                                                   const float* __restrict__ res,
                                                   float* __restrict__ C,
                                                   int M, int N, int K) {
    __shared__ float As[64][17];
    __shared__ float Ws[16][64];
    int t = threadIdx.x;
    int bcol = blockIdx.x * 64, brow = blockIdx.y * 64;
    int tr = t >> 4, tc = t & 15;
    float acc[4][4] = {};
    for (int k0 = 0; k0 < K; k0 += 16) {
        #pragma unroll
        for (int it = 0; it < 4; ++it) {
            int idx = t + it * 256;
            int rr = idx >> 4, cc = idx & 15;
            As[rr][cc] = A[(size_t)(brow + rr) * K + k0 + cc];
        }
        #pragma unroll
        for (int it = 0; it < 4; ++it) {
            int idx = t + it * 256;
            int kk = idx >> 6, cc = idx & 63;
            Ws[kk][cc] = W[(size_t)(k0 + kk) * N + bcol + cc];
        }
        __syncthreads();
        #pragma unroll
        for (int kk = 0; kk < 16; ++kk) {
            float a[4], b[4];
            #pragma unroll
            for (int i = 0; i < 4; ++i) a[i] = As[tr * 4 + i][kk];
            #pragma unroll
            for (int j = 0; j < 4; ++j) b[j] = Ws[kk][tc * 4 + j];
            #pragma unroll
            for (int i = 0; i < 4; ++i)
                #pragma unroll
                for (int j = 0; j < 4; ++j)
                    acc[i][j] += a[i] * b[j];
        }
        __syncthreads();
    }
    #pragma unroll
    for (int i = 0; i < 4; ++i) {
        int row = brow + tr * 4 + i;
        #pragma unroll
        for (int j = 0; j < 4; ++j) {
            int col = bcol + tc * 4 + j;
            float vv = acc[i][j];
            if (bias) vv += bias[col];
            if (ACT == 1) vv = gelu_tanh(vv);
            if (res) vv += res[(size_t)row * N + col];
            C[(size_t)row * N + col] = vv;
        }
    }
}

// ---------------------------------------------------------------------------
// Sparse block attention, MFMA bf16 version.
// grid (32 qb, H, B), 256 threads = 4 waves; wave w owns Q rows w*16..w*16+15.
// q,k,v,o layout: [B, L, H, DH] fp32.
// mfma_f32_16x16x32_bf16 layouts:
//   A: row = lane&15, k = (lane>>4)*8 + b      (b = 0..7 within bf16x8)
//   B: col = lane&15, k = (lane>>4)*8 + b
//   D: col = lane&15, row = (lane>>4)*4 + reg
// ---------------------------------------------------------------------------
#define KSTR 88   // LDS row stride in bf16: 176 B = 16B-aligned, 2-way bank alias only

__global__ __launch_bounds__(256) void attn_kernel(const float* __restrict__ q,
                                                   const float* __restrict__ k,
                                                   const float* __restrict__ v,
                                                   const int* __restrict__ tokens,
                                                   const unsigned* __restrict__ maskrow,
                                                   float* __restrict__ o) {
    __shared__ __align__(16) short Ks[64][KSTR];     // K rows (bf16)
    __shared__ __align__(16) short Vt[64][KSTR];     // V transposed: Vt[d][c]
    __shared__ __align__(16) short Pw[4][16][KSTR];  // per-wave P tile
    __shared__ int padk[64];
    __shared__ int padq[64];

    int qb = blockIdx.x, h = blockIdx.y, b = blockIdx.z;
    unsigned rowm = maskrow[qb];
    int t = threadIdx.x;
    int l = t & 63, w = t >> 6;
    int l15 = l & 15, lg = l >> 4;

    if (t < 64) padq[t] = tokens[b * L_ + qb * 64 + t] > 0;

    // Q fragments (A-layout), scaled by 1/sqrt(DH), resident in registers
    int qrow = qb * 64 + w * 16 + l15;
    const float* qp = q + (((size_t)b * L_ + qrow) * H_ + h) * DH_;
    bf16x8 qf[2];
    #pragma unroll
    for (int s = 0; s < 2; ++s)
        #pragma unroll
        for (int j = 0; j < 8; ++j)
            qf[s][j] = f2bf(qp[lg * 8 + 32 * s + j] * 0.125f);

    f32x4 acc[4] = {};     // O fragments: acc[fd] covers d = 16*fd + l15
    float m_r[4], l_r[4];
    #pragma unroll
    for (int r = 0; r < 4; ++r) { m_r[r] = -INFINITY; l_r[r] = 0.0f; }

    for (int jb = 0; jb < NB_; ++jb) {
        if (!((rowm >> jb) & 1u)) continue;
        __syncthreads();   // all waves done with previous Ks/Vt
        for (int i = t; i < 64 * 64; i += 256) {
            int cc = i >> 6, dd = i & 63;
            size_t base = (((size_t)b * L_ + jb * 64 + cc) * H_ + h) * DH_ + dd;
            Ks[cc][dd] = f2bf(k[base]);
            Vt[dd][cc] = f2bf(v[base]);
        }
        if (t < 64) padk[t] = tokens[b * L_ + jb * 64 + t] > 0;
        __syncthreads();

        // S = Q K^T : 4 col-fragments x 2 k-steps
        f32x4 sacc[4];
        #pragma unroll
        for (int f = 0; f < 4; ++f) {
            bf16x8 k0 = *(const bf16x8*)&Ks[16 * f + l15][lg * 8];
            bf16x8 k1 = *(const bf16x8*)&Ks[16 * f + l15][lg * 8 + 32];
            f32x4 z = {};
            z = __builtin_amdgcn_mfma_f32_16x16x32_bf16(qf[0], k0, z, 0, 0, 0);
            z = __builtin_amdgcn_mfma_f32_16x16x32_bf16(qf[1], k1, z, 0, 0, 0);
            sacc[f] = z;
        }

        int mc[4], mrow[4];
        #pragma unroll
        for (int f = 0; f < 4; ++f) mc[f] = padk[16 * f + l15];
        #pragma unroll
        for (int r = 0; r < 4; ++r) mrow[r] = padq[w * 16 + lg * 4 + r];

        float alpha[4];
        #pragma unroll
        for (int r = 0; r < 4; ++r) {
            float mx = -INFINITY;
            #pragma unroll
            for (int f = 0; f < 4; ++f)
                if (mc[f] && mrow[r]) mx = fmaxf(mx, sacc[f][r]);
            mx = fmaxf(mx, __shfl_xor(mx, 1, 64));
            mx = fmaxf(mx, __shfl_xor(mx, 2, 64));
            mx = fmaxf(mx, __shfl_xor(mx, 4, 64));
            mx = fmaxf(mx, __shfl_xor(mx, 8, 64));
            float nm = fmaxf(m_r[r], mx);
            float sum = 0.0f;
            #pragma unroll
            for (int f = 0; f < 4; ++f) {
                float p = (mc[f] && mrow[r]) ? expf(sacc[f][r] - nm) : 0.0f;
                Pw[w][lg * 4 + r][16 * f + l15] = f2bf(p);
                sum += p;
            }
            sum += __shfl_xor(sum, 1, 64);
            sum += __shfl_xor(sum, 2, 64);
            sum += __shfl_xor(sum, 4, 64);
            sum += __shfl_xor(sum, 8, 64);
            float al = (nm == -INFINITY) ? 1.0f : expf(m_r[r] - nm);
            m_r[r] = nm;
            l_r[r] = l_r[r] * al + sum;
            alpha[r] = al;
        }
        #pragma unroll
        for (int fd = 0; fd < 4; ++fd)
            #pragma unroll
            for (int r = 0; r < 4; ++r) acc[fd][r] *= alpha[r];

        // P in A-layout from per-wave LDS (same-wave RAW, no barrier needed)
        bf16x8 pa0 = *(const bf16x8*)&Pw[w][l15][lg * 8];
        bf16x8 pa1 = *(const bf16x8*)&Pw[w][l15][lg * 8 + 32];
        #pragma unroll
        for (int fd = 0; fd < 4; ++fd) {
            bf16x8 v0 = *(const bf16x8*)&Vt[16 * fd + l15][lg * 8];
            bf16x8 v1 = *(const bf16x8*)&Vt[16 * fd + l15][lg * 8 + 32];
            acc[fd] = __builtin_amdgcn_mfma_f32_16x16x32_bf16(pa0, v0, acc[fd], 0, 0, 0);
            acc[fd] = __builtin_amdgcn_mfma_f32_16x16x32_bf16(pa1, v1, acc[fd], 0, 0, 0);
        }
    }

    // Epilogue: D-layout rows (lg*4+r), cols 16*fd + l15
    #pragma unroll
    for (int r = 0; r < 4; ++r) {
        int rw = lg * 4 + r;
        int gl = qb * 64 + w * 16 + rw;
        size_t ob = (((size_t)b * L_ + gl) * H_ + h) * DH_ + l15;
        bool ok = (padq[w * 16 + rw] != 0) && (l_r[r] > 0.0f);
        if (ok) {
            float inv = 1.0f / l_r[r];
            #pragma unroll
            for (int fd = 0; fd < 4; ++fd) o[ob + 16 * fd] = acc[fd][r] * inv;
        } else {
            // fully-masked row: uniform softmax over all L -> mean of V
            #pragma unroll
            for (int fd = 0; fd < 4; ++fd) {
                float s = 0.0f;
                for (int m = 0; m < L_; ++m)
                    s += v[(((size_t)b * L_ + m) * H_ + h) * DH_ + 16 * fd + l15];
                o[ob + 16 * fd] = s * (1.0f / L_);
            }
        }
    }
}

// ---------------------------------------------------------------------------
// Launch
// ---------------------------------------------------------------------------
extern "C" void kernel_launch(void* const* d_in, const int* in_sizes, int n_in,
                              void* d_out, int out_size, void* d_ws, size_t ws_size,
                              hipStream_t stream) {
    (void)in_sizes; (void)n_in; (void)out_size; (void)ws_size;
    const int*   tokens = (const int*)d_in[0];
    const float* embed  = (const float*)d_in[1];
    const float* ln1_s  = (const float*)d_in[2];
    const float* ln1_b  = (const float*)d_in[3];
    const float* wq     = (const float*)d_in[4];
    const float* wk     = (const float*)d_in[5];
    const float* wv     = (const float*)d_in[6];
    const float* wo     = (const float*)d_in[7];
    const float* ln2_s  = (const float*)d_in[8];
    const float* ln2_b  = (const float*)d_in[9];
    const float* w1     = (const float*)d_in[10];
    const float* b1     = (const float*)d_in[11];
    const float* w2     = (const float*)d_in[12];
    const float* b2     = (const float*)d_in[13];
    const float* lnf_s  = (const float*)d_in[14];
    const float* lnf_b  = (const float*)d_in[15];
    float* out = (float*)d_out;

    const size_t BLE = (size_t)B_ * L_ * E_;          // 4M floats = 16 MB
    char* ws = (char*)d_ws;
    unsigned* maskbits = (unsigned*)ws;               // NL*32 words
    float* x  = (float*)(ws + 1024);
    float* y  = x + BLE;
    float* R  = y + BLE;
    float* qb = R;
    float* kb = qb + BLE;
    float* vb = kb + BLE;
    float* ob = vb + BLE;
    float* hb = R;                                    // reuses q/k/v/o after out-proj

    mask_kernel<<<1, 64, 0, stream>>>(maskbits);
    embed_kernel<<<(unsigned)(BLE / 256), 256, 0, stream>>>(tokens, embed, x);

    dim3 g512(512 / 64, (B_ * L_) / 64);
    dim3 g2048(2048 / 64, (B_ * L_) / 64);
    for (int lyr = 0; lyr < NL_; ++lyr) {
        ln_kernel<<<B_ * L_, 256, 0, stream>>>(x, ln1_s + lyr * E_, ln1_b + lyr * E_, y);
        gemm_kernel<0><<<g512, 256, 0, stream>>>(y, wq + (size_t)lyr * E_ * E_, nullptr, nullptr, qb, B_ * L_, 512, 512);
        gemm_kernel<0><<<g512, 256, 0, stream>>>(y, wk + (size_t)lyr * E_ * E_, nullptr, nullptr, kb, B_ * L_, 512, 512);
        gemm_kernel<0><<<g512, 256, 0, stream>>>(y, wv + (size_t)lyr * E_ * E_, nullptr, nullptr, vb, B_ * L_, 512, 512);
        attn_kernel<<<dim3(NB_, H_, B_), 256, 0, stream>>>(qb, kb, vb, tokens, maskbits + lyr * NB_, ob);
        gemm_kernel<0><<<g512, 256, 0, stream>>>(ob, wo + (size_t)lyr * E_ * E_, nullptr, x, x, B_ * L_, 512, 512);
        ln_kernel<<<B_ * L_, 256, 0, stream>>>(x, ln2_s + lyr * E_, ln2_b + lyr * E_, y);
        gemm_kernel<1><<<g2048, 256, 0, stream>>>(y, w1 + (size_t)lyr * E_ * M_, b1 + (size_t)lyr * M_, nullptr, hb, B_ * L_, M_, E_);
        gemm_kernel<0><<<g512, 256, 0, stream>>>(hb, w2 + (size_t)lyr * M_ * E_, b2 + (size_t)lyr * E_, x, x, B_ * L_, E_, M_);
    }
    ln_kernel<<<B_ * L_, 256, 0, stream>>>(x, lnf_s, lnf_b, out);
}

// Round 3
// 1537.181 us; speedup vs baseline: 9.4368x; 3.9544x over previous
//
#include <hip/hip_runtime.h>
#include <hip/hip_bf16.h>
#include <cmath>
#include <cstdint>
#include <cstddef>

#define B_   4
#define L_   2048
#define E_   512
#define H_   8
#define DH_  64
#define M_   2048
#define NL_  4
#define NB_  32
#define BS_  64

typedef short bf16x8 __attribute__((ext_vector_type(8)));
typedef float f32x4 __attribute__((ext_vector_type(4)));

__device__ __forceinline__ short f2bf(float f) {
    union { __hip_bfloat16 h; short s; } u;
    u.h = __float2bfloat16(f);
    return u.s;
}
__device__ __forceinline__ float bf2f(short s) {
    union { short s; __hip_bfloat16 h; } u;
    u.s = s;
    return __bfloat162float(u.h);
}

// ---------------------------------------------------------------------------
// BigBird masks: full numpy-RandomState MT19937 replication, evaluated at
// COMPILE TIME (constexpr) into a __constant__ table. (The single-thread
// device version cost 1.9 ms/launch: 624-word state -> scratch, rule #20.)
// ---------------------------------------------------------------------------
struct MaskTable { unsigned m[NL_][NB_]; };

struct CxMT { unsigned key[624]; int pos; };

constexpr unsigned cx_next(CxMT& st) {
    if (st.pos >= 624) {
        for (int i = 0; i < 624; ++i) {
            unsigned y = (st.key[i] & 0x80000000u) | (st.key[(i + 1) % 624] & 0x7fffffffu);
            st.key[i] = st.key[(i + 397) % 624] ^ (y >> 1) ^ ((y & 1u) ? 0x9908b0dfu : 0u);
        }
        st.pos = 0;
    }
    unsigned y = st.key[st.pos++];
    y ^= y >> 11;
    y ^= (y << 7) & 0x9d2c5680u;
    y ^= (y << 15) & 0xefc60000u;
    y ^= y >> 18;
    return y;
}

constexpr unsigned cx_interval(CxMT& st, unsigned maxv) {
    if (maxv == 0u) return 0u;
    unsigned mask = maxv;
    mask |= mask >> 1; mask |= mask >> 2; mask |= mask >> 4;
    mask |= mask >> 8; mask |= mask >> 16;
    unsigned v = cx_next(st) & mask;
    while (v > maxv) v = cx_next(st) & mask;
    return v;
}

constexpr MaskTable compute_masks() {
    MaskTable T{};
    for (int lyr = 0; lyr < NL_; ++lyr) {
        unsigned m[NB_] = {};
        for (int i = 0; i < NB_; ++i) {
            unsigned w = 1u << i;
            if (i > 0) w |= 1u << (i - 1);
            if (i < NB_ - 1) w |= 1u << (i + 1);
            w |= 1u | (1u << (NB_ - 1));
            m[i] = w;
        }
        m[0] = 0xffffffffu;
        m[NB_ - 1] = 0xffffffffu;
        CxMT st{};
        unsigned s = (unsigned)lyr;
        for (int i = 0; i < 624; ++i) {
            st.key[i] = s;
            s = 1812433253u * (s ^ (s >> 30)) + (unsigned)i + 1u;
        }
        st.pos = 624;
        for (int i = 1; i < NB_ - 1; ++i) {
            int cand[NB_] = {};
            int n = 0;
            for (int j = 0; j < NB_; ++j) {
                if (j == 0 || j == NB_ - 1 || j == i - 1 || j == i || j == i + 1) continue;
                cand[n++] = j;
            }
            for (int kk = n - 1; kk >= 1; --kk) {
                int jj = (int)cx_interval(st, (unsigned)kk);
                int tmp = cand[kk]; cand[kk] = cand[jj]; cand[jj] = tmp;
            }
            m[i] |= (1u << cand[0]) | (1u << cand[1]) | (1u << cand[2]);
        }
        for (int i = 0; i < NB_; ++i) T.m[lyr][i] = m[i];
    }
    return T;
}

__constant__ MaskTable g_masks = compute_masks();

// ---------------------------------------------------------------------------
// Embedding + sinusoidal PE (fp32 residual stream)
// ---------------------------------------------------------------------------
__global__ __launch_bounds__(256) void embed_kernel(const int* __restrict__ tokens,
                                                    const float* __restrict__ embed,
                                                    float* __restrict__ x) {
    size_t i = (size_t)blockIdx.x * 256 + threadIdx.x;   // < B*L*E
    int e = (int)(i & (E_ - 1));
    size_t bl = i >> 9;
    int l = (int)(bl & (L_ - 1));
    int tok = tokens[bl];
    int j = e & 255;
    float div = expf((float)j * -0.03597789207717895f);  // -ln(10000)/256
    float arg = (float)l * div;
    float pe = (e < 256) ? sinf(arg) : cosf(arg);
    x[i] = embed[(size_t)tok * E_ + e] + pe;
}

// ---------------------------------------------------------------------------
// LayerNorm: fp32 input, bf16 (OUTBF=1) or fp32 (OUTBF=0) output
// ---------------------------------------------------------------------------
template<int OUTBF>
__global__ __launch_bounds__(256) void ln_kernel(const float* __restrict__ x,
                                                 const float* __restrict__ gamma,
                                                 const float* __restrict__ beta,
                                                 void* __restrict__ yout) {
    __shared__ float sh[4];
    int row = blockIdx.x, t = threadIdx.x;
    const float* xr = x + (size_t)row * E_;
    float a = xr[t], c = xr[t + 256];
    float s = a + c;
    #pragma unroll
    for (int off = 1; off < 64; off <<= 1) s += __shfl_xor(s, off, 64);
    if ((t & 63) == 0) sh[t >> 6] = s;
    __syncthreads();
    s = sh[0] + sh[1] + sh[2] + sh[3];
    float mu = s * (1.0f / E_);
    float da = a - mu, dc = c - mu;
    float q = da * da + dc * dc;
    __syncthreads();
    #pragma unroll
    for (int off = 1; off < 64; off <<= 1) q += __shfl_xor(q, off, 64);
    if ((t & 63) == 0) sh[t >> 6] = q;
    __syncthreads();
    q = sh[0] + sh[1] + sh[2] + sh[3];
    float rstd = rsqrtf(q * (1.0f / E_) + 1e-6f);
    float v0 = da * rstd * gamma[t] + beta[t];
    float v1 = dc * rstd * gamma[t + 256] + beta[t + 256];
    if (OUTBF) {
        short* yr = (short*)yout + (size_t)row * E_;
        yr[t] = f2bf(v0);
        yr[t + 256] = f2bf(v1);
    } else {
        float* yr = (float*)yout + (size_t)row * E_;
        yr[t] = v0;
        yr[t + 256] = v1;
    }
}

// ---------------------------------------------------------------------------
// Weight convert + transpose: Wt[n][k] = bf16(W[k][n] * scale), per layer (z)
// grid: (N/64, K/64, NL)
// ---------------------------------------------------------------------------
__global__ __launch_bounds__(256) void convT_kernel(const float* __restrict__ W,
                                                    short* __restrict__ Wt,
                                                    int K, int N,
                                                    size_t wStride, size_t wtStride,
                                                    float scale) {
    __shared__ float Ts[64][65];
    const float* Wl = W + blockIdx.z * wStride;
    short* Wtl = Wt + blockIdx.z * wtStride;
    int n0 = blockIdx.x * 64, k0 = blockIdx.y * 64;
    int t = threadIdx.x;
    int c = t & 63, r0 = t >> 6;
    #pragma unroll
    for (int i = 0; i < 16; ++i) {
        int r = r0 * 16 + i;
        Ts[r][c] = Wl[(size_t)(k0 + r) * N + n0 + c] * scale;
    }
    __syncthreads();
    #pragma unroll
    for (int i = 0; i < 16; ++i) {
        int r = r0 * 16 + i;           // output row within tile = n index
        Wtl[(size_t)(n0 + r) * K + k0 + c] = f2bf(Ts[c][r]);
    }
}

// ---------------------------------------------------------------------------
// MFMA bf16 GEMM: C[M,N] = act(A[M,K] * Bt[N,K]^T + bias) + res
// 128x128 tile, BK=64, 4 waves (2x2), global_load_lds width-16 staging.
// ACT: 0 none, 1 tanh-gelu.  OUTBF: 1 -> bf16 C, 0 -> fp32 C.
// ---------------------------------------------------------------------------
__device__ __forceinline__ float gelu_tanh(float x) {
    float x3 = x * x * x;
    return 0.5f * x * (1.0f + tanhf(0.7978845608028654f * (x + 0.044715f * x3)));
}

template<int ACT, int OUTBF>
__global__ __launch_bounds__(256) void mgemm_kernel(const short* __restrict__ A,
                                                    const short* __restrict__ Bt,
                                                    const float* __restrict__ bias,
                                                    const float* __restrict__ res,
                                                    void* __restrict__ Cout,
                                                    int M, int N, int K) {
    __shared__ short Als[128][64];
    __shared__ short Bls[128][64];
    int t = threadIdx.x;
    int w = t >> 6, l = t & 63;
    int l15 = l & 15, lg = l >> 4;
    int wr = w >> 1, wc = w & 1;
    int brow = blockIdx.y * 128, bcol = blockIdx.x * 128;
    f32x4 acc[4][4] = {};

    for (int k0 = 0; k0 < K; k0 += 64) {
        __syncthreads();
        #pragma unroll
        for (int j = 0; j < 4; ++j) {
            int row = w * 32 + j * 8 + (l >> 3);
            const short* ga = A + (size_t)(brow + row) * K + k0 + (l & 7) * 8;
            __builtin_amdgcn_global_load_lds(
                (const __attribute__((address_space(1))) unsigned int*)ga,
                (__attribute__((address_space(3))) unsigned int*)&Als[w * 32 + j * 8][0],
                16, 0, 0);
            const short* gb = Bt + (size_t)(bcol + row) * K + k0 + (l & 7) * 8;
            __builtin_amdgcn_global_load_lds(
                (const __attribute__((address_space(1))) unsigned int*)gb,
                (__attribute__((address_space(3))) unsigned int*)&Bls[w * 32 + j * 8][0],
                16, 0, 0);
        }
        __syncthreads();
        #pragma unroll
        for (int kk = 0; kk < 64; kk += 32) {
            bf16x8 af[4], bfr[4];
            #pragma unroll
            for (int m = 0; m < 4; ++m)
                af[m] = *(const bf16x8*)&Als[wr * 64 + m * 16 + l15][kk + lg * 8];
            #pragma unroll
            for (int n = 0; n < 4; ++n)
                bfr[n] = *(const bf16x8*)&Bls[wc * 64 + n * 16 + l15][kk + lg * 8];
            #pragma unroll
            for (int m = 0; m < 4; ++m)
                #pragma unroll
                for (int n = 0; n < 4; ++n)
                    acc[m][n] = __builtin_amdgcn_mfma_f32_16x16x32_bf16(af[m], bfr[n], acc[m][n], 0, 0, 0);
        }
    }

    #pragma unroll
    for (int m = 0; m < 4; ++m) {
        int row = brow + wr * 64 + m * 16 + lg * 4;
        #pragma unroll
        for (int n = 0; n < 4; ++n) {
            int col = bcol + wc * 64 + n * 16 + l15;
            float bv = bias ? bias[col] : 0.0f;
            #pragma unroll
            for (int r = 0; r < 4; ++r) {
                float vv = acc[m][n][r] + bv;
                if (ACT == 1) vv = gelu_tanh(vv);
                if (res) vv += res[(size_t)(row + r) * N + col];
                if (OUTBF) ((short*)Cout)[(size_t)(row + r) * N + col] = f2bf(vv);
                else       ((float*)Cout)[(size_t)(row + r) * N + col] = vv;
            }
        }
    }
}

// ---------------------------------------------------------------------------
// Sparse block attention, MFMA bf16, fused-QKV input [B*L][1536] bf16
// (q pre-scaled by 1/sqrt(DH) via wq). Output o: [B*L][512] bf16.
// grid (32 qb, H, B), 256 threads = 4 waves; wave w owns Q rows w*16..+15.
// ---------------------------------------------------------------------------
#define KSTR 88   // LDS row stride in bf16: 176 B, 16B-aligned

__global__ __launch_bounds__(256) void attn_kernel(const short* __restrict__ qkv,
                                                   const int* __restrict__ tokens,
                                                   short* __restrict__ o,
                                                   int lyr) {
    __shared__ __align__(16) short Ks[64][KSTR];
    __shared__ __align__(16) short Vt[64][KSTR];     // V transposed: Vt[d][c]
    __shared__ __align__(16) short Pw[4][16][KSTR];  // per-wave P tile
    __shared__ int padk[64];
    __shared__ int padq[64];

    int qb = blockIdx.x, h = blockIdx.y, b = blockIdx.z;
    unsigned rowm = g_masks.m[lyr][qb];
    int t = threadIdx.x;
    int l = t & 63, w = t >> 6;
    int l15 = l & 15, lg = l >> 4;

    if (t < 64) padq[t] = tokens[b * L_ + qb * 64 + t] > 0;

    int qrow = qb * 64 + w * 16 + l15;
    const short* qp = qkv + (size_t)(b * L_ + qrow) * 1536 + h * 64;
    bf16x8 qf0 = *(const bf16x8*)(qp + lg * 8);
    bf16x8 qf1 = *(const bf16x8*)(qp + lg * 8 + 32);

    f32x4 acc[4] = {};
    float m_r[4], l_r[4];
    #pragma unroll
    for (int r = 0; r < 4; ++r) { m_r[r] = -INFINITY; l_r[r] = 0.0f; }

    for (int jb = 0; jb < NB_; ++jb) {
        if (!((rowm >> jb) & 1u)) continue;
        __syncthreads();
        for (int i = t; i < 64 * 8; i += 256) {       // K rows, vectorized
            int cc = i >> 3, j = i & 7;
            *(bf16x8*)&Ks[cc][j * 8] =
                *(const bf16x8*)(qkv + (size_t)(b * L_ + jb * 64 + cc) * 1536 + 512 + h * 64 + j * 8);
        }
        for (int i = t; i < 64 * 64; i += 256) {      // V transpose
            int cc = i >> 6, dd = i & 63;
            Vt[dd][cc] = qkv[(size_t)(b * L_ + jb * 64 + cc) * 1536 + 1024 + h * 64 + dd];
        }
        if (t < 64) padk[t] = tokens[b * L_ + jb * 64 + t] > 0;
        __syncthreads();

        f32x4 sacc[4];
        #pragma unroll
        for (int f = 0; f < 4; ++f) {
            bf16x8 k0 = *(const bf16x8*)&Ks[16 * f + l15][lg * 8];
            bf16x8 k1 = *(const bf16x8*)&Ks[16 * f + l15][lg * 8 + 32];
            f32x4 z = {};
            z = __builtin_amdgcn_mfma_f32_16x16x32_bf16(qf0, k0, z, 0, 0, 0);
            z = __builtin_amdgcn_mfma_f32_16x16x32_bf16(qf1, k1, z, 0, 0, 0);
            sacc[f] = z;
        }

        int mc[4], mrow[4];
        #pragma unroll
        for (int f = 0; f < 4; ++f) mc[f] = padk[16 * f + l15];
        #pragma unroll
        for (int r = 0; r < 4; ++r) mrow[r] = padq[w * 16 + lg * 4 + r];

        float alpha[4];
        #pragma unroll
        for (int r = 0; r < 4; ++r) {
            float mx = -INFINITY;
            #pragma unroll
            for (int f = 0; f < 4; ++f)
                if (mc[f] && mrow[r]) mx = fmaxf(mx, sacc[f][r]);
            mx = fmaxf(mx, __shfl_xor(mx, 1, 64));
            mx = fmaxf(mx, __shfl_xor(mx, 2, 64));
            mx = fmaxf(mx, __shfl_xor(mx, 4, 64));
            mx = fmaxf(mx, __shfl_xor(mx, 8, 64));
            float nm = fmaxf(m_r[r], mx);
            float sum = 0.0f;
            #pragma unroll
            for (int f = 0; f < 4; ++f) {
                float p = (mc[f] && mrow[r]) ? expf(sacc[f][r] - nm) : 0.0f;
                Pw[w][lg * 4 + r][16 * f + l15] = f2bf(p);
                sum += p;
            }
            sum += __shfl_xor(sum, 1, 64);
            sum += __shfl_xor(sum, 2, 64);
            sum += __shfl_xor(sum, 4, 64);
            sum += __shfl_xor(sum, 8, 64);
            float al = (nm == -INFINITY) ? 1.0f : expf(m_r[r] - nm);
            m_r[r] = nm;
            l_r[r] = l_r[r] * al + sum;
            alpha[r] = al;
        }
        #pragma unroll
        for (int fd = 0; fd < 4; ++fd)
            #pragma unroll
            for (int r = 0; r < 4; ++r) acc[fd][r] *= alpha[r];

        bf16x8 pa0 = *(const bf16x8*)&Pw[w][l15][lg * 8];
        bf16x8 pa1 = *(const bf16x8*)&Pw[w][l15][lg * 8 + 32];
        #pragma unroll
        for (int fd = 0; fd < 4; ++fd) {
            bf16x8 v0 = *(const bf16x8*)&Vt[16 * fd + l15][lg * 8];
            bf16x8 v1 = *(const bf16x8*)&Vt[16 * fd + l15][lg * 8 + 32];
            acc[fd] = __builtin_amdgcn_mfma_f32_16x16x32_bf16(pa0, v0, acc[fd], 0, 0, 0);
            acc[fd] = __builtin_amdgcn_mfma_f32_16x16x32_bf16(pa1, v1, acc[fd], 0, 0, 0);
        }
    }

    #pragma unroll
    for (int r = 0; r < 4; ++r) {
        int rw = lg * 4 + r;
        int gl = qb * 64 + w * 16 + rw;
        size_t ob = (size_t)(b * L_ + gl) * 512 + h * 64 + l15;
        bool ok = (padq[w * 16 + rw] != 0) && (l_r[r] > 0.0f);
        if (ok) {
            float inv = 1.0f / l_r[r];
            #pragma unroll
            for (int fd = 0; fd < 4; ++fd) o[ob + 16 * fd] = f2bf(acc[fd][r] * inv);
        } else {
            #pragma unroll
            for (int fd = 0; fd < 4; ++fd) {
                float s = 0.0f;
                for (int m = 0; m < L_; ++m)
                    s += bf2f(qkv[(size_t)(b * L_ + m) * 1536 + 1024 + h * 64 + 16 * fd + l15]);
                o[ob + 16 * fd] = f2bf(s * (1.0f / L_));
            }
        }
    }
}

// ---------------------------------------------------------------------------
// Launch
// ---------------------------------------------------------------------------
extern "C" void kernel_launch(void* const* d_in, const int* in_sizes, int n_in,
                              void* d_out, int out_size, void* d_ws, size_t ws_size,
                              hipStream_t stream) {
    (void)in_sizes; (void)n_in; (void)out_size; (void)ws_size;
    const int*   tokens = (const int*)d_in[0];
    const float* embed  = (const float*)d_in[1];
    const float* ln1_s  = (const float*)d_in[2];
    const float* ln1_b  = (const float*)d_in[3];
    const float* wq     = (const float*)d_in[4];
    const float* wk     = (const float*)d_in[5];
    const float* wv     = (const float*)d_in[6];
    const float* wo     = (const float*)d_in[7];
    const float* ln2_s  = (const float*)d_in[8];
    const float* ln2_b  = (const float*)d_in[9];
    const float* w1     = (const float*)d_in[10];
    const float* b1     = (const float*)d_in[11];
    const float* w2     = (const float*)d_in[12];
    const float* b2     = (const float*)d_in[13];
    const float* lnf_s  = (const float*)d_in[14];
    const float* lnf_b  = (const float*)d_in[15];
    float* out = (float*)d_out;

    const size_t BLE = (size_t)B_ * L_ * E_;              // 4,194,304
    char* ws = (char*)d_ws;
    float* x    = (float*)ws;                             // BLE f32      (16 MB)
    short* yb   = (short*)(x + BLE);                      // BLE bf16     ( 8 MB)
    short* R    = yb + BLE;                               // 4*BLE bf16   (33.6 MB)
    short* qkv  = R;                                      // 3*BLE bf16
    short* ob   = R + 3 * BLE;                            //   BLE bf16
    short* hb   = R;                                      // 4*BLE bf16 (reuse)
    short* qkvt = R + 4 * BLE;                            // 4*1536*512
    short* wot  = qkvt + (size_t)NL_ * 1536 * 512;        // 4*512*512
    short* w1t  = wot + (size_t)NL_ * 512 * 512;          // 4*2048*512
    short* w2t  = w1t + (size_t)NL_ * 2048 * 512;         // 4*512*2048

    // Weight conversion (bf16, transposed to [N][K]); q-scale folded into wq.
    convT_kernel<<<dim3(8, 8, NL_), 256, 0, stream>>>(wq, qkvt,          512, 512, 262144, 786432, 0.125f);
    convT_kernel<<<dim3(8, 8, NL_), 256, 0, stream>>>(wk, qkvt + 262144, 512, 512, 262144, 786432, 1.0f);
    convT_kernel<<<dim3(8, 8, NL_), 256, 0, stream>>>(wv, qkvt + 524288, 512, 512, 262144, 786432, 1.0f);
    convT_kernel<<<dim3(8, 8, NL_), 256, 0, stream>>>(wo, wot,           512, 512, 262144, 262144, 1.0f);
    convT_kernel<<<dim3(32, 8, NL_), 256, 0, stream>>>(w1, w1t,          512, 2048, 1048576, 1048576, 1.0f);
    convT_kernel<<<dim3(8, 32, NL_), 256, 0, stream>>>(w2, w2t,          2048, 512, 1048576, 1048576, 1.0f);

    embed_kernel<<<(unsigned)(BLE / 256), 256, 0, stream>>>(tokens, embed, x);

    const int MR = B_ * L_;                                // 8192 rows
    for (int lyr = 0; lyr < NL_; ++lyr) {
        ln_kernel<1><<<MR, 256, 0, stream>>>(x, ln1_s + lyr * E_, ln1_b + lyr * E_, yb);
        mgemm_kernel<0, 1><<<dim3(12, 64), 256, 0, stream>>>(
            yb, qkvt + (size_t)lyr * 786432, nullptr, nullptr, qkv, MR, 1536, 512);
        attn_kernel<<<dim3(NB_, H_, B_), 256, 0, stream>>>(qkv, tokens, ob, lyr);
        mgemm_kernel<0, 0><<<dim3(4, 64), 256, 0, stream>>>(
            ob, wot + (size_t)lyr * 262144, nullptr, x, x, MR, 512, 512);
        ln_kernel<1><<<MR, 256, 0, stream>>>(x, ln2_s + lyr * E_, ln2_b + lyr * E_, yb);
        mgemm_kernel<1, 1><<<dim3(16, 64), 256, 0, stream>>>(
            yb, w1t + (size_t)lyr * 1048576, b1 + (size_t)lyr * M_, nullptr, hb, MR, 2048, 512);
        mgemm_kernel<0, 0><<<dim3(4, 64), 256, 0, stream>>>(
            hb, w2t + (size_t)lyr * 1048576, b2 + (size_t)lyr * E_, x, x, MR, 512, 2048);
    }
    ln_kernel<0><<<MR, 256, 0, stream>>>(x, lnf_s, lnf_b, out);
}

// Round 4
// 1045.646 us; speedup vs baseline: 13.8728x; 1.4701x over previous
//
#include <hip/hip_runtime.h>
#include <hip/hip_bf16.h>
#include <cmath>
#include <cstdint>
#include <cstddef>

#define B_   4
#define L_   2048
#define E_   512
#define H_   8
#define DH_  64
#define M_   2048
#define NL_  4
#define NB_  32
#define BS_  64
#define CH_  12   // max jb-blocks per attention work item

typedef short bf16x8 __attribute__((ext_vector_type(8)));
typedef float f32x4 __attribute__((ext_vector_type(4)));

__device__ __forceinline__ short f2bf(float f) {
    union { __hip_bfloat16 h; short s; } u;
    u.h = __float2bfloat16(f);
    return u.s;
}
__device__ __forceinline__ float bf2f(short s) {
    union { short s; __hip_bfloat16 h; } u;
    u.s = s;
    return __bfloat162float(u.h);
}

// ---------------------------------------------------------------------------
// BigBird masks + work partition, all at COMPILE TIME.
// numpy legacy RandomState MT19937 replicated in constexpr.
// ---------------------------------------------------------------------------
struct MaskTable { unsigned m[NL_][NB_]; };
struct CxMT { unsigned key[624]; int pos; };

constexpr unsigned cx_next(CxMT& st) {
    if (st.pos >= 624) {
        for (int i = 0; i < 624; ++i) {
            unsigned y = (st.key[i] & 0x80000000u) | (st.key[(i + 1) % 624] & 0x7fffffffu);
            st.key[i] = st.key[(i + 397) % 624] ^ (y >> 1) ^ ((y & 1u) ? 0x9908b0dfu : 0u);
        }
        st.pos = 0;
    }
    unsigned y = st.key[st.pos++];
    y ^= y >> 11;
    y ^= (y << 7) & 0x9d2c5680u;
    y ^= (y << 15) & 0xefc60000u;
    y ^= y >> 18;
    return y;
}
constexpr unsigned cx_interval(CxMT& st, unsigned maxv) {
    if (maxv == 0u) return 0u;
    unsigned mask = maxv;
    mask |= mask >> 1; mask |= mask >> 2; mask |= mask >> 4;
    mask |= mask >> 8; mask |= mask >> 16;
    unsigned v = cx_next(st) & mask;
    while (v > maxv) v = cx_next(st) & mask;
    return v;
}
constexpr MaskTable compute_masks() {
    MaskTable T{};
    for (int lyr = 0; lyr < NL_; ++lyr) {
        unsigned m[NB_] = {};
        for (int i = 0; i < NB_; ++i) {
            unsigned w = 1u << i;
            if (i > 0) w |= 1u << (i - 1);
            if (i < NB_ - 1) w |= 1u << (i + 1);
            w |= 1u | (1u << (NB_ - 1));
            m[i] = w;
        }
        m[0] = 0xffffffffu;
        m[NB_ - 1] = 0xffffffffu;
        CxMT st{};
        unsigned s = (unsigned)lyr;
        for (int i = 0; i < 624; ++i) {
            st.key[i] = s;
            s = 1812433253u * (s ^ (s >> 30)) + (unsigned)i + 1u;
        }
        st.pos = 624;
        for (int i = 1; i < NB_ - 1; ++i) {
            int cand[NB_] = {};
            int n = 0;
            for (int j = 0; j < NB_; ++j) {
                if (j == 0 || j == NB_ - 1 || j == i - 1 || j == i || j == i + 1) continue;
                cand[n++] = j;
            }
            for (int kk = n - 1; kk >= 1; --kk) {
                int jj = (int)cx_interval(st, (unsigned)kk);
                int tmp = cand[kk]; cand[kk] = cand[jj]; cand[jj] = tmp;
            }
            m[i] |= (1u << cand[0]) | (1u << cand[1]) | (1u << cand[2]);
        }
        for (int i = 0; i < NB_; ++i) T.m[lyr][i] = m[i];
    }
    return T;
}

struct WorkTable {
    int n_items[NL_];
    int n_cmb[NL_];
    unsigned char itm_qb[NL_][40];
    unsigned char itm_j0[NL_][40];
    unsigned char itm_jn[NL_][40];
    unsigned char itm_slot[NL_][40];   // 0xFF = direct write to o
    unsigned char cmb_qb[NL_][8];
    unsigned char cmb_slot0[NL_][8];
    unsigned char cmb_nch[NL_][8];
    unsigned char jlist[NL_][NB_][NB_];
};

constexpr WorkTable compute_work() {
    WorkTable T{};
    MaskTable M = compute_masks();
    for (int lyr = 0; lyr < NL_; ++lyr) {
        int items = 0, slots = 0, ncmb = 0;
        for (int qb = 0; qb < NB_; ++qb) {
            int cnt = 0;
            for (int j = 0; j < NB_; ++j)
                if ((M.m[lyr][qb] >> j) & 1u)
                    T.jlist[lyr][qb][cnt++] = (unsigned char)j;
            int nch = (cnt + CH_ - 1) / CH_;
            if (nch == 1) {
                T.itm_qb[lyr][items] = (unsigned char)qb;
                T.itm_j0[lyr][items] = 0;
                T.itm_jn[lyr][items] = (unsigned char)cnt;
                T.itm_slot[lyr][items] = 0xFF;
                items++;
            } else {
                T.cmb_qb[lyr][ncmb] = (unsigned char)qb;
                T.cmb_slot0[lyr][ncmb] = (unsigned char)slots;
                T.cmb_nch[lyr][ncmb] = (unsigned char)nch;
                ncmb++;
                int base = cnt / nch, rem = cnt % nch, off = 0;
                for (int c = 0; c < nch; ++c) {
                    int cl = base + (c < rem ? 1 : 0);
                    T.itm_qb[lyr][items] = (unsigned char)qb;
                    T.itm_j0[lyr][items] = (unsigned char)off;
                    T.itm_jn[lyr][items] = (unsigned char)cl;
                    T.itm_slot[lyr][items] = (unsigned char)slots;
                    items++; slots++; off += cl;
                }
            }
        }
        T.n_items[lyr] = items;
        T.n_cmb[lyr] = ncmb;
    }
    return T;
}

static constexpr WorkTable WT_HOST = compute_work();
__constant__ WorkTable g_wt = compute_work();

// ---------------------------------------------------------------------------
// Embedding + sinusoidal PE (fp32 residual stream)
// ---------------------------------------------------------------------------
__global__ __launch_bounds__(256) void embed_kernel(const int* __restrict__ tokens,
                                                    const float* __restrict__ embed,
                                                    float* __restrict__ x) {
    size_t i = (size_t)blockIdx.x * 256 + threadIdx.x;
    int e = (int)(i & (E_ - 1));
    size_t bl = i >> 9;
    int l = (int)(bl & (L_ - 1));
    int tok = tokens[bl];
    int j = e & 255;
    float div = expf((float)j * -0.03597789207717895f);  // -ln(10000)/256
    float arg = (float)l * div;
    float pe = (e < 256) ? sinf(arg) : cosf(arg);
    x[i] = embed[(size_t)tok * E_ + e] + pe;
}

// ---------------------------------------------------------------------------
// LayerNorm: fp32 input, bf16 (OUTBF=1) or fp32 (OUTBF=0) output
// ---------------------------------------------------------------------------
template<int OUTBF>
__global__ __launch_bounds__(256) void ln_kernel(const float* __restrict__ x,
                                                 const float* __restrict__ gamma,
                                                 const float* __restrict__ beta,
                                                 void* __restrict__ yout) {
    __shared__ float sh[4];
    int row = blockIdx.x, t = threadIdx.x;
    const float* xr = x + (size_t)row * E_;
    float a = xr[t], c = xr[t + 256];
    float s = a + c;
    #pragma unroll
    for (int off = 1; off < 64; off <<= 1) s += __shfl_xor(s, off, 64);
    if ((t & 63) == 0) sh[t >> 6] = s;
    __syncthreads();
    s = sh[0] + sh[1] + sh[2] + sh[3];
    float mu = s * (1.0f / E_);
    float da = a - mu, dc = c - mu;
    float q = da * da + dc * dc;
    __syncthreads();
    #pragma unroll
    for (int off = 1; off < 64; off <<= 1) q += __shfl_xor(q, off, 64);
    if ((t & 63) == 0) sh[t >> 6] = q;
    __syncthreads();
    q = sh[0] + sh[1] + sh[2] + sh[3];
    float rstd = rsqrtf(q * (1.0f / E_) + 1e-6f);
    float v0 = da * rstd * gamma[t] + beta[t];
    float v1 = dc * rstd * gamma[t + 256] + beta[t + 256];
    if (OUTBF) {
        short* yr = (short*)yout + (size_t)row * E_;
        yr[t] = f2bf(v0);
        yr[t + 256] = f2bf(v1);
    } else {
        float* yr = (float*)yout + (size_t)row * E_;
        yr[t] = v0;
        yr[t + 256] = v1;
    }
}

// ---------------------------------------------------------------------------
// Weight convert + transpose: Wt[n][k] = bf16(W[k][n] * scale), per layer (z)
// ---------------------------------------------------------------------------
__global__ __launch_bounds__(256) void convT_kernel(const float* __restrict__ W,
                                                    short* __restrict__ Wt,
                                                    int K, int N,
                                                    size_t wStride, size_t wtStride,
                                                    float scale) {
    __shared__ float Ts[64][65];
    const float* Wl = W + blockIdx.z * wStride;
    short* Wtl = Wt + blockIdx.z * wtStride;
    int n0 = blockIdx.x * 64, k0 = blockIdx.y * 64;
    int t = threadIdx.x;
    int c = t & 63, r0 = t >> 6;
    #pragma unroll
    for (int i = 0; i < 16; ++i) {
        int r = r0 * 16 + i;
        Ts[r][c] = Wl[(size_t)(k0 + r) * N + n0 + c] * scale;
    }
    __syncthreads();
    #pragma unroll
    for (int i = 0; i < 16; ++i) {
        int r = r0 * 16 + i;
        Wtl[(size_t)(n0 + r) * K + k0 + c] = f2bf(Ts[c][r]);
    }
}

// ---------------------------------------------------------------------------
// MFMA bf16 GEMM: C[M,N] = act(A[M,K] * Bt[N,K]^T + bias) + res
// ---------------------------------------------------------------------------
__device__ __forceinline__ float gelu_tanh(float x) {
    float x3 = x * x * x;
    return 0.5f * x * (1.0f + tanhf(0.7978845608028654f * (x + 0.044715f * x3)));
}

template<int ACT, int OUTBF>
__global__ __launch_bounds__(256) void mgemm_kernel(const short* __restrict__ A,
                                                    const short* __restrict__ Bt,
                                                    const float* __restrict__ bias,
                                                    const float* __restrict__ res,
                                                    void* __restrict__ Cout,
                                                    int M, int N, int K) {
    __shared__ short Als[128][64];
    __shared__ short Bls[128][64];
    int t = threadIdx.x;
    int w = t >> 6, l = t & 63;
    int l15 = l & 15, lg = l >> 4;
    int wr = w >> 1, wc = w & 1;
    int brow = blockIdx.y * 128, bcol = blockIdx.x * 128;
    f32x4 acc[4][4] = {};

    for (int k0 = 0; k0 < K; k0 += 64) {
        __syncthreads();
        #pragma unroll
        for (int j = 0; j < 4; ++j) {
            int row = w * 32 + j * 8 + (l >> 3);
            const short* ga = A + (size_t)(brow + row) * K + k0 + (l & 7) * 8;
            __builtin_amdgcn_global_load_lds(
                (const __attribute__((address_space(1))) unsigned int*)ga,
                (__attribute__((address_space(3))) unsigned int*)&Als[w * 32 + j * 8][0],
                16, 0, 0);
            const short* gb = Bt + (size_t)(bcol + row) * K + k0 + (l & 7) * 8;
            __builtin_amdgcn_global_load_lds(
                (const __attribute__((address_space(1))) unsigned int*)gb,
                (__attribute__((address_space(3))) unsigned int*)&Bls[w * 32 + j * 8][0],
                16, 0, 0);
        }
        __syncthreads();
        #pragma unroll
        for (int kk = 0; kk < 64; kk += 32) {
            bf16x8 af[4], bfr[4];
            #pragma unroll
            for (int m = 0; m < 4; ++m)
                af[m] = *(const bf16x8*)&Als[wr * 64 + m * 16 + l15][kk + lg * 8];
            #pragma unroll
            for (int n = 0; n < 4; ++n)
                bfr[n] = *(const bf16x8*)&Bls[wc * 64 + n * 16 + l15][kk + lg * 8];
            #pragma unroll
            for (int m = 0; m < 4; ++m)
                #pragma unroll
                for (int n = 0; n < 4; ++n)
                    acc[m][n] = __builtin_amdgcn_mfma_f32_16x16x32_bf16(af[m], bfr[n], acc[m][n], 0, 0, 0);
        }
    }

    #pragma unroll
    for (int m = 0; m < 4; ++m) {
        int row = brow + wr * 64 + m * 16 + lg * 4;
        #pragma unroll
        for (int n = 0; n < 4; ++n) {
            int col = bcol + wc * 64 + n * 16 + l15;
            float bv = bias ? bias[col] : 0.0f;
            #pragma unroll
            for (int r = 0; r < 4; ++r) {
                float vv = acc[m][n][r] + bv;
                if (ACT == 1) vv = gelu_tanh(vv);
                if (res) vv += res[(size_t)(row + r) * N + col];
                if (OUTBF) ((short*)Cout)[(size_t)(row + r) * N + col] = f2bf(vv);
                else       ((float*)Cout)[(size_t)(row + r) * N + col] = vv;
            }
        }
    }
}

// ---------------------------------------------------------------------------
// Sparse block attention, MFMA bf16, chunked work items + flash-split.
// grid (n_items, H, B), 256 threads = 4 waves; wave w owns q rows w*16..+15.
// qkv: [B*L][1536] bf16 (q pre-scaled). o: [B*L][512] bf16.
// Pipelined staging: K/V for jb+1 loaded into regs during compute of jb.
// Vt stored with XOR block swizzle: Vt[d][(c&7) + 8*((c>>3)^(d>>3 /~dblk~/))]
// ---------------------------------------------------------------------------
#define KSTR 72

__global__ __launch_bounds__(256) void attn_kernel(const short* __restrict__ qkv,
                                                   const int* __restrict__ tokens,
                                                   short* __restrict__ o,
                                                   float* __restrict__ pacc,
                                                   float* __restrict__ pm,
                                                   float* __restrict__ pl,
                                                   int lyr) {
    __shared__ __align__(16) short Ks[64][KSTR];
    __shared__ __align__(16) short Vt[64][KSTR];
    __shared__ __align__(16) short Pw[4][16][KSTR];
    __shared__ int padk[64];
    __shared__ int padq[64];

    int item = blockIdx.x, h = blockIdx.y, b = blockIdx.z;
    int qb   = g_wt.itm_qb[lyr][item];
    int j0   = g_wt.itm_j0[lyr][item];
    int jn   = g_wt.itm_jn[lyr][item];
    int slot = g_wt.itm_slot[lyr][item];
    const unsigned char* jl = g_wt.jlist[lyr][qb];

    int t = threadIdx.x;
    int l = t & 63, w = t >> 6;
    int l15 = l & 15, lg = l >> 4;
    int srow = t >> 3, sdb = t & 7;      // staging: row (0..31, +32), d-block (0..7)

    if (t < 64) padq[t] = tokens[b * L_ + qb * 64 + t] > 0;

    // Q fragments (A-layout), resident
    int qrow = qb * 64 + w * 16 + l15;
    const short* qp = qkv + (size_t)(b * L_ + qrow) * 1536 + h * 64;
    bf16x8 qf0 = *(const bf16x8*)(qp + lg * 8);
    bf16x8 qf1 = *(const bf16x8*)(qp + lg * 8 + 32);

    f32x4 acc[4] = {};
    float m_r[4], l_r[4];
    #pragma unroll
    for (int r = 0; r < 4; ++r) { m_r[r] = -INFINITY; l_r[r] = 0.0f; }

    // prologue: stage first jb into regs
    bf16x8 k0, k1, v0, v1;
    int pn = 0;
    {
        int jb = jl[j0];
        const short* base = qkv + (size_t)(b * L_ + jb * 64 + srow) * 1536 + h * 64;
        k0 = *(const bf16x8*)(base + 512 + sdb * 8);
        k1 = *(const bf16x8*)(base + (size_t)32 * 1536 + 512 + sdb * 8);
        v0 = *(const bf16x8*)(base + 1024 + sdb * 8);
        v1 = *(const bf16x8*)(base + (size_t)32 * 1536 + 1024 + sdb * 8);
        if (t < 64) pn = tokens[b * L_ + jb * 64 + t];
    }

    for (int ci = 0; ci < jn; ++ci) {
        __syncthreads();   // previous iteration done reading LDS
        *(bf16x8*)&Ks[srow][sdb * 8] = k0;
        *(bf16x8*)&Ks[srow + 32][sdb * 8] = k1;
        #pragma unroll
        for (int j = 0; j < 8; ++j) {
            Vt[sdb * 8 + j][(srow & 7) + 8 * ((srow >> 3) ^ sdb)] = v0[j];
            Vt[sdb * 8 + j][(srow & 7) + 8 * (((srow >> 3) + 4) ^ sdb)] = v1[j];
        }
        if (t < 64) padk[t] = pn > 0;
        __syncthreads();

        if (ci + 1 < jn) {
            int jb = jl[j0 + ci + 1];
            const short* base = qkv + (size_t)(b * L_ + jb * 64 + srow) * 1536 + h * 64;
            k0 = *(const bf16x8*)(base + 512 + sdb * 8);
            k1 = *(const bf16x8*)(base + (size_t)32 * 1536 + 512 + sdb * 8);
            v0 = *(const bf16x8*)(base + 1024 + sdb * 8);
            v1 = *(const bf16x8*)(base + (size_t)32 * 1536 + 1024 + sdb * 8);
            if (t < 64) pn = tokens[b * L_ + jb * 64 + t];
        }

        // S = Q K^T
        f32x4 sacc[4];
        #pragma unroll
        for (int f = 0; f < 4; ++f) {
            bf16x8 kk0 = *(const bf16x8*)&Ks[16 * f + l15][lg * 8];
            bf16x8 kk1 = *(const bf16x8*)&Ks[16 * f + l15][lg * 8 + 32];
            f32x4 z = {};
            z = __builtin_amdgcn_mfma_f32_16x16x32_bf16(qf0, kk0, z, 0, 0, 0);
            z = __builtin_amdgcn_mfma_f32_16x16x32_bf16(qf1, kk1, z, 0, 0, 0);
            sacc[f] = z;
        }

        int mc[4], mrow[4];
        #pragma unroll
        for (int f = 0; f < 4; ++f) mc[f] = padk[16 * f + l15];
        #pragma unroll
        for (int r = 0; r < 4; ++r) mrow[r] = padq[w * 16 + lg * 4 + r];

        float alpha[4];
        #pragma unroll
        for (int r = 0; r < 4; ++r) {
            float mx = -INFINITY;
            #pragma unroll
            for (int f = 0; f < 4; ++f)
                if (mc[f] && mrow[r]) mx = fmaxf(mx, sacc[f][r]);
            mx = fmaxf(mx, __shfl_xor(mx, 1, 64));
            mx = fmaxf(mx, __shfl_xor(mx, 2, 64));
            mx = fmaxf(mx, __shfl_xor(mx, 4, 64));
            mx = fmaxf(mx, __shfl_xor(mx, 8, 64));
            float nm = fmaxf(m_r[r], mx);
            float sum = 0.0f;
            #pragma unroll
            for (int f = 0; f < 4; ++f) {
                float p = (mc[f] && mrow[r]) ? __expf(sacc[f][r] - nm) : 0.0f;
                Pw[w][lg * 4 + r][16 * f + l15] = f2bf(p);
                sum += p;
            }
            sum += __shfl_xor(sum, 1, 64);
            sum += __shfl_xor(sum, 2, 64);
            sum += __shfl_xor(sum, 4, 64);
            sum += __shfl_xor(sum, 8, 64);
            float al = (nm == -INFINITY) ? 1.0f : __expf(m_r[r] - nm);
            m_r[r] = nm;
            l_r[r] = l_r[r] * al + sum;
            alpha[r] = al;
        }
        #pragma unroll
        for (int fd = 0; fd < 4; ++fd)
            #pragma unroll
            for (int r = 0; r < 4; ++r) acc[fd][r] *= alpha[r];

        bf16x8 pa0 = *(const bf16x8*)&Pw[w][l15][lg * 8];
        bf16x8 pa1 = *(const bf16x8*)&Pw[w][l15][lg * 8 + 32];
        #pragma unroll
        for (int fd = 0; fd < 4; ++fd) {
            int dd = 16 * fd + l15;
            bf16x8 vv0 = *(const bf16x8*)&Vt[dd][8 * (lg ^ (dd >> 3))];
            bf16x8 vv1 = *(const bf16x8*)&Vt[dd][8 * ((4 + lg) ^ (dd >> 3))];
            acc[fd] = __builtin_amdgcn_mfma_f32_16x16x32_bf16(pa0, vv0, acc[fd], 0, 0, 0);
            acc[fd] = __builtin_amdgcn_mfma_f32_16x16x32_bf16(pa1, vv1, acc[fd], 0, 0, 0);
        }
    }

    if (slot == 0xFF) {
        // direct: normalize and write o
        #pragma unroll
        for (int r = 0; r < 4; ++r) {
            int rw = lg * 4 + r;
            int gl = qb * 64 + w * 16 + rw;
            size_t ob = (size_t)(b * L_ + gl) * 512 + h * 64 + l15;
            bool ok = (padq[w * 16 + rw] != 0) && (l_r[r] > 0.0f);
            if (ok) {
                float inv = 1.0f / l_r[r];
                #pragma unroll
                for (int fd = 0; fd < 4; ++fd) o[ob + 16 * fd] = f2bf(acc[fd][r] * inv);
            } else {
                #pragma unroll
                for (int fd = 0; fd < 4; ++fd) {
                    float s = 0.0f;
                    for (int m = 0; m < L_; ++m)
                        s += bf2f(qkv[(size_t)(b * L_ + m) * 1536 + 1024 + h * 64 + 16 * fd + l15]);
                    o[ob + 16 * fd] = f2bf(s * (1.0f / L_));
                }
            }
        }
    } else {
        // partial: write (m, l, acc) for combine
        size_t pb = ((size_t)slot * B_ + b) * H_ + h;
        #pragma unroll
        for (int r = 0; r < 4; ++r) {
            int rloc = w * 16 + lg * 4 + r;
            #pragma unroll
            for (int fd = 0; fd < 4; ++fd)
                pacc[pb * 4096 + (size_t)rloc * 64 + 16 * fd + l15] = acc[fd][r];
            if (l15 == 0) {
                pm[pb * 64 + rloc] = m_r[r];
                pl[pb * 64 + rloc] = l_r[r];
            }
        }
    }
}

// ---------------------------------------------------------------------------
// Combine partial flash results for split q-blocks. grid (n_cmb, H, B), 256 thr
// ---------------------------------------------------------------------------
__global__ __launch_bounds__(256) void attn_combine(const short* __restrict__ qkv,
                                                    const int* __restrict__ tokens,
                                                    short* __restrict__ o,
                                                    const float* __restrict__ pacc,
                                                    const float* __restrict__ pm,
                                                    const float* __restrict__ pl,
                                                    int lyr) {
    int ci = blockIdx.x, h = blockIdx.y, b = blockIdx.z;
    int qb  = g_wt.cmb_qb[lyr][ci];
    int s0  = g_wt.cmb_slot0[lyr][ci];
    int nch = g_wt.cmb_nch[lyr][ci];
    int t = threadIdx.x;
    int r = t >> 2, dq = t & 3;
    int grow = qb * 64 + r;
    bool pq = tokens[b * L_ + grow] > 0;
    float M = -INFINITY;
    for (int c = 0; c < nch; ++c)
        M = fmaxf(M, pm[(((size_t)(s0 + c) * B_ + b) * H_ + h) * 64 + r]);
    size_t ob = (size_t)(b * L_ + grow) * 512 + h * 64 + dq * 16;
    if (pq && M > -1e30f) {
        float lsum = 0.0f;
        float accd[16] = {};
        for (int c = 0; c < nch; ++c) {
            size_t pb = ((size_t)(s0 + c) * B_ + b) * H_ + h;
            float wgt = __expf(pm[pb * 64 + r] - M);
            lsum += pl[pb * 64 + r] * wgt;
            const float* pa = pacc + pb * 4096 + (size_t)r * 64 + dq * 16;
            #pragma unroll
            for (int j = 0; j < 16; ++j) accd[j] += pa[j] * wgt;
        }
        float inv = 1.0f / lsum;
        #pragma unroll
        for (int j = 0; j < 16; ++j) o[ob + j] = f2bf(accd[j] * inv);
    } else {
        #pragma unroll
        for (int j = 0; j < 16; ++j) {
            float s = 0.0f;
            for (int m = 0; m < L_; ++m)
                s += bf2f(qkv[(size_t)(b * L_ + m) * 1536 + 1024 + h * 64 + dq * 16 + j]);
            o[ob + j] = f2bf(s * (1.0f / L_));
        }
    }
}

// ---------------------------------------------------------------------------
// Launch
// ---------------------------------------------------------------------------
extern "C" void kernel_launch(void* const* d_in, const int* in_sizes, int n_in,
                              void* d_out, int out_size, void* d_ws, size_t ws_size,
                              hipStream_t stream) {
    (void)in_sizes; (void)n_in; (void)out_size; (void)ws_size;
    const int*   tokens = (const int*)d_in[0];
    const float* embed  = (const float*)d_in[1];
    const float* ln1_s  = (const float*)d_in[2];
    const float* ln1_b  = (const float*)d_in[3];
    const float* wq     = (const float*)d_in[4];
    const float* wk     = (const float*)d_in[5];
    const float* wv     = (const float*)d_in[6];
    const float* wo     = (const float*)d_in[7];
    const float* ln2_s  = (const float*)d_in[8];
    const float* ln2_b  = (const float*)d_in[9];
    const float* w1     = (const float*)d_in[10];
    const float* b1     = (const float*)d_in[11];
    const float* w2     = (const float*)d_in[12];
    const float* b2     = (const float*)d_in[13];
    const float* lnf_s  = (const float*)d_in[14];
    const float* lnf_b  = (const float*)d_in[15];
    float* out = (float*)d_out;

    const size_t BLE = (size_t)B_ * L_ * E_;              // 4,194,304
    char* ws = (char*)d_ws;
    float* x    = (float*)ws;                             // 16 MB
    short* yb   = (short*)(x + BLE);                      //  8 MB
    short* R    = yb + BLE;                               // 32 MB (qkv+ob / hb)
    short* qkv  = R;
    short* ob   = R + 3 * BLE;
    short* hb   = R;
    short* qkvt = R + 4 * BLE;                            // bf16 weights
    short* wot  = qkvt + (size_t)NL_ * 1536 * 512;
    short* w1t  = wot + (size_t)NL_ * 512 * 512;
    short* w2t  = w1t + (size_t)NL_ * 2048 * 512;
    float* pacc = (float*)(w2t + (size_t)NL_ * 512 * 2048);   // 8 slots x 32 x 4096 f32
    float* pm   = pacc + (size_t)8 * B_ * H_ * 4096;
    float* pl   = pm + (size_t)8 * B_ * H_ * 64;

    convT_kernel<<<dim3(8, 8, NL_), 256, 0, stream>>>(wq, qkvt,          512, 512, 262144, 786432, 0.125f);
    convT_kernel<<<dim3(8, 8, NL_), 256, 0, stream>>>(wk, qkvt + 262144, 512, 512, 262144, 786432, 1.0f);
    convT_kernel<<<dim3(8, 8, NL_), 256, 0, stream>>>(wv, qkvt + 524288, 512, 512, 262144, 786432, 1.0f);
    convT_kernel<<<dim3(8, 8, NL_), 256, 0, stream>>>(wo, wot,           512, 512, 262144, 262144, 1.0f);
    convT_kernel<<<dim3(32, 8, NL_), 256, 0, stream>>>(w1, w1t,          512, 2048, 1048576, 1048576, 1.0f);
    convT_kernel<<<dim3(8, 32, NL_), 256, 0, stream>>>(w2, w2t,          2048, 512, 1048576, 1048576, 1.0f);

    embed_kernel<<<(unsigned)(BLE / 256), 256, 0, stream>>>(tokens, embed, x);

    const int MR = B_ * L_;
    for (int lyr = 0; lyr < NL_; ++lyr) {
        ln_kernel<1><<<MR, 256, 0, stream>>>(x, ln1_s + lyr * E_, ln1_b + lyr * E_, yb);
        mgemm_kernel<0, 1><<<dim3(12, 64), 256, 0, stream>>>(
            yb, qkvt + (size_t)lyr * 786432, nullptr, nullptr, qkv, MR, 1536, 512);
        attn_kernel<<<dim3(WT_HOST.n_items[lyr], H_, B_), 256, 0, stream>>>(
            qkv, tokens, ob, pacc, pm, pl, lyr);
        attn_combine<<<dim3(WT_HOST.n_cmb[lyr], H_, B_), 256, 0, stream>>>(
            qkv, tokens, ob, pacc, pm, pl, lyr);
        mgemm_kernel<0, 0><<<dim3(4, 64), 256, 0, stream>>>(
            ob, wot + (size_t)lyr * 262144, nullptr, x, x, MR, 512, 512);
        ln_kernel<1><<<MR, 256, 0, stream>>>(x, ln2_s + lyr * E_, ln2_b + lyr * E_, yb);
        mgemm_kernel<1, 1><<<dim3(16, 64), 256, 0, stream>>>(
            yb, w1t + (size_t)lyr * 1048576, b1 + (size_t)lyr * M_, nullptr, hb, MR, 2048, 512);
        mgemm_kernel<0, 0><<<dim3(4, 64), 256, 0, stream>>>(
            hb, w2t + (size_t)lyr * 1048576, b2 + (size_t)lyr * E_, x, x, MR, 512, 2048);
    }
    ln_kernel<0><<<MR, 256, 0, stream>>>(x, lnf_s, lnf_b, out);
}

// Round 5
// 848.547 us; speedup vs baseline: 17.0951x; 1.2323x over previous
//
#include <hip/hip_runtime.h>
#include <hip/hip_bf16.h>
#include <cmath>
#include <cstdint>
#include <cstddef>

#define B_   4
#define L_   2048
#define E_   512
#define H_   8
#define DH_  64
#define M_   2048
#define NL_  4
#define NB_  32
#define BS_  64
#define CH_  12   // max jb-blocks per attention work item

typedef short bf16x8 __attribute__((ext_vector_type(8)));
typedef float f32x4 __attribute__((ext_vector_type(4)));

__device__ __forceinline__ short f2bf(float f) {
    union { __hip_bfloat16 h; short s; } u;
    u.h = __float2bfloat16(f);
    return u.s;
}
__device__ __forceinline__ float bf2f(short s) {
    union { short s; __hip_bfloat16 h; } u;
    u.s = s;
    return __bfloat162float(u.h);
}

// ---------------------------------------------------------------------------
// BigBird masks + work partition, all at COMPILE TIME.
// ---------------------------------------------------------------------------
struct MaskTable { unsigned m[NL_][NB_]; };
struct CxMT { unsigned key[624]; int pos; };

constexpr unsigned cx_next(CxMT& st) {
    if (st.pos >= 624) {
        for (int i = 0; i < 624; ++i) {
            unsigned y = (st.key[i] & 0x80000000u) | (st.key[(i + 1) % 624] & 0x7fffffffu);
            st.key[i] = st.key[(i + 397) % 624] ^ (y >> 1) ^ ((y & 1u) ? 0x9908b0dfu : 0u);
        }
        st.pos = 0;
    }
    unsigned y = st.key[st.pos++];
    y ^= y >> 11;
    y ^= (y << 7) & 0x9d2c5680u;
    y ^= (y << 15) & 0xefc60000u;
    y ^= y >> 18;
    return y;
}
constexpr unsigned cx_interval(CxMT& st, unsigned maxv) {
    if (maxv == 0u) return 0u;
    unsigned mask = maxv;
    mask |= mask >> 1; mask |= mask >> 2; mask |= mask >> 4;
    mask |= mask >> 8; mask |= mask >> 16;
    unsigned v = cx_next(st) & mask;
    while (v > maxv) v = cx_next(st) & mask;
    return v;
}
constexpr MaskTable compute_masks() {
    MaskTable T{};
    for (int lyr = 0; lyr < NL_; ++lyr) {
        unsigned m[NB_] = {};
        for (int i = 0; i < NB_; ++i) {
            unsigned w = 1u << i;
            if (i > 0) w |= 1u << (i - 1);
            if (i < NB_ - 1) w |= 1u << (i + 1);
            w |= 1u | (1u << (NB_ - 1));
            m[i] = w;
        }
        m[0] = 0xffffffffu;
        m[NB_ - 1] = 0xffffffffu;
        CxMT st{};
        unsigned s = (unsigned)lyr;
        for (int i = 0; i < 624; ++i) {
            st.key[i] = s;
            s = 1812433253u * (s ^ (s >> 30)) + (unsigned)i + 1u;
        }
        st.pos = 624;
        for (int i = 1; i < NB_ - 1; ++i) {
            int cand[NB_] = {};
            int n = 0;
            for (int j = 0; j < NB_; ++j) {
                if (j == 0 || j == NB_ - 1 || j == i - 1 || j == i || j == i + 1) continue;
                cand[n++] = j;
            }
            for (int kk = n - 1; kk >= 1; --kk) {
                int jj = (int)cx_interval(st, (unsigned)kk);
                int tmp = cand[kk]; cand[kk] = cand[jj]; cand[jj] = tmp;
            }
            m[i] |= (1u << cand[0]) | (1u << cand[1]) | (1u << cand[2]);
        }
        for (int i = 0; i < NB_; ++i) T.m[lyr][i] = m[i];
    }
    return T;
}

struct WorkTable {
    int n_items[NL_];
    int n_cmb[NL_];
    unsigned char itm_qb[NL_][40];
    unsigned char itm_j0[NL_][40];
    unsigned char itm_jn[NL_][40];
    unsigned char itm_slot[NL_][40];   // 0xFF = direct write to o
    unsigned char cmb_qb[NL_][8];
    unsigned char cmb_slot0[NL_][8];
    unsigned char cmb_nch[NL_][8];
    unsigned char jlist[NL_][NB_][NB_];
};

constexpr WorkTable compute_work() {
    WorkTable T{};
    MaskTable M = compute_masks();
    for (int lyr = 0; lyr < NL_; ++lyr) {
        int items = 0, slots = 0, ncmb = 0;
        for (int qb = 0; qb < NB_; ++qb) {
            int cnt = 0;
            for (int j = 0; j < NB_; ++j)
                if ((M.m[lyr][qb] >> j) & 1u)
                    T.jlist[lyr][qb][cnt++] = (unsigned char)j;
            int nch = (cnt + CH_ - 1) / CH_;
            if (nch == 1) {
                T.itm_qb[lyr][items] = (unsigned char)qb;
                T.itm_j0[lyr][items] = 0;
                T.itm_jn[lyr][items] = (unsigned char)cnt;
                T.itm_slot[lyr][items] = 0xFF;
                items++;
            } else {
                T.cmb_qb[lyr][ncmb] = (unsigned char)qb;
                T.cmb_slot0[lyr][ncmb] = (unsigned char)slots;
                T.cmb_nch[lyr][ncmb] = (unsigned char)nch;
                ncmb++;
                int base = cnt / nch, rem = cnt % nch, off = 0;
                for (int c = 0; c < nch; ++c) {
                    int cl = base + (c < rem ? 1 : 0);
                    T.itm_qb[lyr][items] = (unsigned char)qb;
                    T.itm_j0[lyr][items] = (unsigned char)off;
                    T.itm_jn[lyr][items] = (unsigned char)cl;
                    T.itm_slot[lyr][items] = (unsigned char)slots;
                    items++; slots++; off += cl;
                }
            }
        }
        T.n_items[lyr] = items;
        T.n_cmb[lyr] = ncmb;
    }
    return T;
}

static constexpr WorkTable WT_HOST = compute_work();
__constant__ WorkTable g_wt = compute_work();

// ---------------------------------------------------------------------------
// Embedding + sinusoidal PE (fp32 residual stream)
// ---------------------------------------------------------------------------
__global__ __launch_bounds__(256) void embed_kernel(const int* __restrict__ tokens,
                                                    const float* __restrict__ embed,
                                                    float* __restrict__ x) {
    size_t i = (size_t)blockIdx.x * 256 + threadIdx.x;
    int e = (int)(i & (E_ - 1));
    size_t bl = i >> 9;
    int l = (int)(bl & (L_ - 1));
    int tok = tokens[bl];
    int j = e & 255;
    float div = expf((float)j * -0.03597789207717895f);  // -ln(10000)/256
    float arg = (float)l * div;
    float pe = (e < 256) ? sinf(arg) : cosf(arg);
    x[i] = embed[(size_t)tok * E_ + e] + pe;
}

// ---------------------------------------------------------------------------
// LayerNorm: fp32 input, bf16 (OUTBF=1) or fp32 (OUTBF=0) output
// ---------------------------------------------------------------------------
template<int OUTBF>
__global__ __launch_bounds__(256) void ln_kernel(const float* __restrict__ x,
                                                 const float* __restrict__ gamma,
                                                 const float* __restrict__ beta,
                                                 void* __restrict__ yout) {
    __shared__ float sh[4];
    int row = blockIdx.x, t = threadIdx.x;
    const float* xr = x + (size_t)row * E_;
    float a = xr[t], c = xr[t + 256];
    float s = a + c;
    #pragma unroll
    for (int off = 1; off < 64; off <<= 1) s += __shfl_xor(s, off, 64);
    if ((t & 63) == 0) sh[t >> 6] = s;
    __syncthreads();
    s = sh[0] + sh[1] + sh[2] + sh[3];
    float mu = s * (1.0f / E_);
    float da = a - mu, dc = c - mu;
    float q = da * da + dc * dc;
    __syncthreads();
    #pragma unroll
    for (int off = 1; off < 64; off <<= 1) q += __shfl_xor(q, off, 64);
    if ((t & 63) == 0) sh[t >> 6] = q;
    __syncthreads();
    q = sh[0] + sh[1] + sh[2] + sh[3];
    float rstd = rsqrtf(q * (1.0f / E_) + 1e-6f);
    float v0 = da * rstd * gamma[t] + beta[t];
    float v1 = dc * rstd * gamma[t + 256] + beta[t + 256];
    if (OUTBF) {
        short* yr = (short*)yout + (size_t)row * E_;
        yr[t] = f2bf(v0);
        yr[t + 256] = f2bf(v1);
    } else {
        float* yr = (float*)yout + (size_t)row * E_;
        yr[t] = v0;
        yr[t + 256] = v1;
    }
}

// ---------------------------------------------------------------------------
// Weight convert + transpose: Wt[n][k] = bf16(W[k][n] * scale), per layer (z)
// ---------------------------------------------------------------------------
__global__ __launch_bounds__(256) void convT_kernel(const float* __restrict__ W,
                                                    short* __restrict__ Wt,
                                                    int K, int N,
                                                    size_t wStride, size_t wtStride,
                                                    float scale) {
    __shared__ float Ts[64][65];
    const float* Wl = W + blockIdx.z * wStride;
    short* Wtl = Wt + blockIdx.z * wtStride;
    int n0 = blockIdx.x * 64, k0 = blockIdx.y * 64;
    int t = threadIdx.x;
    int c = t & 63, r0 = t >> 6;
    #pragma unroll
    for (int i = 0; i < 16; ++i) {
        int r = r0 * 16 + i;
        Ts[r][c] = Wl[(size_t)(k0 + r) * N + n0 + c] * scale;
    }
    __syncthreads();
    #pragma unroll
    for (int i = 0; i < 16; ++i) {
        int r = r0 * 16 + i;
        Wtl[(size_t)(n0 + r) * K + k0 + c] = f2bf(Ts[c][r]);
    }
}

// ---------------------------------------------------------------------------
// MFMA bf16 GEMM: C[M,N] = act(A[M,K] * Bt[N,K]^T + bias) + res
// Tile BM x BN, BK=64, 4 waves arranged WRxWC (wave tile (BM/WR)x(BN/WC)).
// T2 XOR swizzle (rule #21): LDS dest linear (global_load_lds), global
// source chunk pre-swizzled with c = (l&7)^(l>>3), ds_read applies same XOR.
// ---------------------------------------------------------------------------
__device__ __forceinline__ float gelu_tanh(float x) {
    float x3 = x * x * x;
    return 0.5f * x * (1.0f + tanhf(0.7978845608028654f * (x + 0.044715f * x3)));
}

template<int BM, int BN, int WR, int WC, int ACT, int OUTBF>
__global__ __launch_bounds__(256) void mgemm_kernel(const short* __restrict__ A,
                                                    const short* __restrict__ Bt,
                                                    const float* __restrict__ bias,
                                                    const float* __restrict__ res,
                                                    void* __restrict__ Cout,
                                                    int M, int N, int K) {
    constexpr int FM = BM / WR / 16;   // A fragments per wave
    constexpr int FN = BN / WC / 16;   // B fragments per wave
    __shared__ short Als[BM][64];
    __shared__ short Bls[BN][64];
    int t = threadIdx.x;
    int w = t >> 6, l = t & 63;
    int l15 = l & 15, lg = l >> 4;
    int wr = w / WC, wc = w % WC;
    int rowbase = wr * (BM / WR), colbase = wc * (BN / WC);
    int brow = blockIdx.y * BM, bcol = blockIdx.x * BN;
    int swz = ((l & 7) ^ (l >> 3)) * 8;    // pre-swizzled global chunk offset
    f32x4 acc[FM][FN] = {};

    for (int k0 = 0; k0 < K; k0 += 64) {
        __syncthreads();
        #pragma unroll
        for (int it = 0; it < BM / 32; ++it) {
            int row8 = (it * 4 + w) * 8;
            const short* ga = A + (size_t)(brow + row8 + (l >> 3)) * K + k0 + swz;
            __builtin_amdgcn_global_load_lds(
                (const __attribute__((address_space(1))) unsigned int*)ga,
                (__attribute__((address_space(3))) unsigned int*)&Als[row8][0],
                16, 0, 0);
        }
        #pragma unroll
        for (int it = 0; it < BN / 32; ++it) {
            int row8 = (it * 4 + w) * 8;
            const short* gb = Bt + (size_t)(bcol + row8 + (l >> 3)) * K + k0 + swz;
            __builtin_amdgcn_global_load_lds(
                (const __attribute__((address_space(1))) unsigned int*)gb,
                (__attribute__((address_space(3))) unsigned int*)&Bls[row8][0],
                16, 0, 0);
        }
        __syncthreads();
        #pragma unroll
        for (int kk = 0; kk < 64; kk += 32) {
            bf16x8 af[FM], bfr[FN];
            #pragma unroll
            for (int m = 0; m < FM; ++m)
                af[m] = *(const bf16x8*)&Als[rowbase + m * 16 + l15]
                                            [(((kk >> 3) + lg) ^ (l15 & 7)) * 8];
            #pragma unroll
            for (int n = 0; n < FN; ++n)
                bfr[n] = *(const bf16x8*)&Bls[colbase + n * 16 + l15]
                                             [(((kk >> 3) + lg) ^ (l15 & 7)) * 8];
            #pragma unroll
            for (int m = 0; m < FM; ++m)
                #pragma unroll
                for (int n = 0; n < FN; ++n)
                    acc[m][n] = __builtin_amdgcn_mfma_f32_16x16x32_bf16(af[m], bfr[n], acc[m][n], 0, 0, 0);
        }
    }

    #pragma unroll
    for (int m = 0; m < FM; ++m) {
        int row = brow + rowbase + m * 16 + lg * 4;
        #pragma unroll
        for (int n = 0; n < FN; ++n) {
            int col = bcol + colbase + n * 16 + l15;
            float bv = bias ? bias[col] : 0.0f;
            #pragma unroll
            for (int r = 0; r < 4; ++r) {
                float vv = acc[m][n][r] + bv;
                if (ACT == 1) vv = gelu_tanh(vv);
                if (res) vv += res[(size_t)(row + r) * N + col];
                if (OUTBF) ((short*)Cout)[(size_t)(row + r) * N + col] = f2bf(vv);
                else       ((float*)Cout)[(size_t)(row + r) * N + col] = vv;
            }
        }
    }
}

// ---------------------------------------------------------------------------
// Sparse block attention, MFMA bf16, chunked work items + flash-split.
// ---------------------------------------------------------------------------
#define KSTR 72

__global__ __launch_bounds__(256) void attn_kernel(const short* __restrict__ qkv,
                                                   const int* __restrict__ tokens,
                                                   short* __restrict__ o,
                                                   float* __restrict__ pacc,
                                                   float* __restrict__ pm,
                                                   float* __restrict__ pl,
                                                   int lyr) {
    __shared__ __align__(16) short Ks[64][KSTR];
    __shared__ __align__(16) short Vt[64][KSTR];
    __shared__ __align__(16) short Pw[4][16][KSTR];
    __shared__ int padk[64];
    __shared__ int padq[64];

    int item = blockIdx.x, h = blockIdx.y, b = blockIdx.z;
    int qb   = g_wt.itm_qb[lyr][item];
    int j0   = g_wt.itm_j0[lyr][item];
    int jn   = g_wt.itm_jn[lyr][item];
    int slot = g_wt.itm_slot[lyr][item];
    const unsigned char* jl = g_wt.jlist[lyr][qb];

    int t = threadIdx.x;
    int l = t & 63, w = t >> 6;
    int l15 = l & 15, lg = l >> 4;
    int srow = t >> 3, sdb = t & 7;

    if (t < 64) padq[t] = tokens[b * L_ + qb * 64 + t] > 0;

    int qrow = qb * 64 + w * 16 + l15;
    const short* qp = qkv + (size_t)(b * L_ + qrow) * 1536 + h * 64;
    bf16x8 qf0 = *(const bf16x8*)(qp + lg * 8);
    bf16x8 qf1 = *(const bf16x8*)(qp + lg * 8 + 32);

    f32x4 acc[4] = {};
    float m_r[4], l_r[4];
    #pragma unroll
    for (int r = 0; r < 4; ++r) { m_r[r] = -INFINITY; l_r[r] = 0.0f; }

    bf16x8 k0, k1, v0, v1;
    int pn = 0;
    {
        int jb = jl[j0];
        const short* base = qkv + (size_t)(b * L_ + jb * 64 + srow) * 1536 + h * 64;
        k0 = *(const bf16x8*)(base + 512 + sdb * 8);
        k1 = *(const bf16x8*)(base + (size_t)32 * 1536 + 512 + sdb * 8);
        v0 = *(const bf16x8*)(base + 1024 + sdb * 8);
        v1 = *(const bf16x8*)(base + (size_t)32 * 1536 + 1024 + sdb * 8);
        if (t < 64) pn = tokens[b * L_ + jb * 64 + t];
    }

    for (int ci = 0; ci < jn; ++ci) {
        __syncthreads();
        *(bf16x8*)&Ks[srow][sdb * 8] = k0;
        *(bf16x8*)&Ks[srow + 32][sdb * 8] = k1;
        #pragma unroll
        for (int j = 0; j < 8; ++j) {
            Vt[sdb * 8 + j][(srow & 7) + 8 * ((srow >> 3) ^ sdb)] = v0[j];
            Vt[sdb * 8 + j][(srow & 7) + 8 * (((srow >> 3) + 4) ^ sdb)] = v1[j];
        }
        if (t < 64) padk[t] = pn > 0;
        __syncthreads();

        if (ci + 1 < jn) {
            int jb = jl[j0 + ci + 1];
            const short* base = qkv + (size_t)(b * L_ + jb * 64 + srow) * 1536 + h * 64;
            k0 = *(const bf16x8*)(base + 512 + sdb * 8);
            k1 = *(const bf16x8*)(base + (size_t)32 * 1536 + 512 + sdb * 8);
            v0 = *(const bf16x8*)(base + 1024 + sdb * 8);
            v1 = *(const bf16x8*)(base + (size_t)32 * 1536 + 1024 + sdb * 8);
            if (t < 64) pn = tokens[b * L_ + jb * 64 + t];
        }

        f32x4 sacc[4];
        #pragma unroll
        for (int f = 0; f < 4; ++f) {
            bf16x8 kk0 = *(const bf16x8*)&Ks[16 * f + l15][lg * 8];
            bf16x8 kk1 = *(const bf16x8*)&Ks[16 * f + l15][lg * 8 + 32];
            f32x4 z = {};
            z = __builtin_amdgcn_mfma_f32_16x16x32_bf16(qf0, kk0, z, 0, 0, 0);
            z = __builtin_amdgcn_mfma_f32_16x16x32_bf16(qf1, kk1, z, 0, 0, 0);
            sacc[f] = z;
        }

        int mc[4], mrow[4];
        #pragma unroll
        for (int f = 0; f < 4; ++f) mc[f] = padk[16 * f + l15];
        #pragma unroll
        for (int r = 0; r < 4; ++r) mrow[r] = padq[w * 16 + lg * 4 + r];

        float alpha[4];
        #pragma unroll
        for (int r = 0; r < 4; ++r) {
            float mx = -INFINITY;
            #pragma unroll
            for (int f = 0; f < 4; ++f)
                if (mc[f] && mrow[r]) mx = fmaxf(mx, sacc[f][r]);
            mx = fmaxf(mx, __shfl_xor(mx, 1, 64));
            mx = fmaxf(mx, __shfl_xor(mx, 2, 64));
            mx = fmaxf(mx, __shfl_xor(mx, 4, 64));
            mx = fmaxf(mx, __shfl_xor(mx, 8, 64));
            float nm = fmaxf(m_r[r], mx);
            float sum = 0.0f;
            #pragma unroll
            for (int f = 0; f < 4; ++f) {
                float p = (mc[f] && mrow[r]) ? __expf(sacc[f][r] - nm) : 0.0f;
                Pw[w][lg * 4 + r][16 * f + l15] = f2bf(p);
                sum += p;
            }
            sum += __shfl_xor(sum, 1, 64);
            sum += __shfl_xor(sum, 2, 64);
            sum += __shfl_xor(sum, 4, 64);
            sum += __shfl_xor(sum, 8, 64);
            float al = (nm == -INFINITY) ? 1.0f : __expf(m_r[r] - nm);
            m_r[r] = nm;
            l_r[r] = l_r[r] * al + sum;
            alpha[r] = al;
        }
        #pragma unroll
        for (int fd = 0; fd < 4; ++fd)
            #pragma unroll
            for (int r = 0; r < 4; ++r) acc[fd][r] *= alpha[r];

        bf16x8 pa0 = *(const bf16x8*)&Pw[w][l15][lg * 8];
        bf16x8 pa1 = *(const bf16x8*)&Pw[w][l15][lg * 8 + 32];
        #pragma unroll
        for (int fd = 0; fd < 4; ++fd) {
            int dd = 16 * fd + l15;
            bf16x8 vv0 = *(const bf16x8*)&Vt[dd][8 * (lg ^ (dd >> 3))];
            bf16x8 vv1 = *(const bf16x8*)&Vt[dd][8 * ((4 + lg) ^ (dd >> 3))];
            acc[fd] = __builtin_amdgcn_mfma_f32_16x16x32_bf16(pa0, vv0, acc[fd], 0, 0, 0);
            acc[fd] = __builtin_amdgcn_mfma_f32_16x16x32_bf16(pa1, vv1, acc[fd], 0, 0, 0);
        }
    }

    if (slot == 0xFF) {
        #pragma unroll
        for (int r = 0; r < 4; ++r) {
            int rw = lg * 4 + r;
            int gl = qb * 64 + w * 16 + rw;
            size_t ob = (size_t)(b * L_ + gl) * 512 + h * 64 + l15;
            bool ok = (padq[w * 16 + rw] != 0) && (l_r[r] > 0.0f);
            if (ok) {
                float inv = 1.0f / l_r[r];
                #pragma unroll
                for (int fd = 0; fd < 4; ++fd) o[ob + 16 * fd] = f2bf(acc[fd][r] * inv);
            } else {
                #pragma unroll
                for (int fd = 0; fd < 4; ++fd) {
                    float s = 0.0f;
                    for (int m = 0; m < L_; ++m)
                        s += bf2f(qkv[(size_t)(b * L_ + m) * 1536 + 1024 + h * 64 + 16 * fd + l15]);
                    o[ob + 16 * fd] = f2bf(s * (1.0f / L_));
                }
            }
        }
    } else {
        size_t pb = ((size_t)slot * B_ + b) * H_ + h;
        #pragma unroll
        for (int r = 0; r < 4; ++r) {
            int rloc = w * 16 + lg * 4 + r;
            #pragma unroll
            for (int fd = 0; fd < 4; ++fd)
                pacc[pb * 4096 + (size_t)rloc * 64 + 16 * fd + l15] = acc[fd][r];
            if (l15 == 0) {
                pm[pb * 64 + rloc] = m_r[r];
                pl[pb * 64 + rloc] = l_r[r];
            }
        }
    }
}

// ---------------------------------------------------------------------------
// Combine partial flash results for split q-blocks.
// ---------------------------------------------------------------------------
__global__ __launch_bounds__(256) void attn_combine(const short* __restrict__ qkv,
                                                    const int* __restrict__ tokens,
                                                    short* __restrict__ o,
                                                    const float* __restrict__ pacc,
                                                    const float* __restrict__ pm,
                                                    const float* __restrict__ pl,
                                                    int lyr) {
    int ci = blockIdx.x, h = blockIdx.y, b = blockIdx.z;
    int qb  = g_wt.cmb_qb[lyr][ci];
    int s0  = g_wt.cmb_slot0[lyr][ci];
    int nch = g_wt.cmb_nch[lyr][ci];
    int t = threadIdx.x;
    int r = t >> 2, dq = t & 3;
    int grow = qb * 64 + r;
    bool pq = tokens[b * L_ + grow] > 0;
    float M = -INFINITY;
    for (int c = 0; c < nch; ++c)
        M = fmaxf(M, pm[(((size_t)(s0 + c) * B_ + b) * H_ + h) * 64 + r]);
    size_t ob = (size_t)(b * L_ + grow) * 512 + h * 64 + dq * 16;
    if (pq && M > -1e30f) {
        float lsum = 0.0f;
        float accd[16] = {};
        for (int c = 0; c < nch; ++c) {
            size_t pb = ((size_t)(s0 + c) * B_ + b) * H_ + h;
            float wgt = __expf(pm[pb * 64 + r] - M);
            lsum += pl[pb * 64 + r] * wgt;
            const float* pa = pacc + pb * 4096 + (size_t)r * 64 + dq * 16;
            #pragma unroll
            for (int j = 0; j < 16; ++j) accd[j] += pa[j] * wgt;
        }
        float inv = 1.0f / lsum;
        #pragma unroll
        for (int j = 0; j < 16; ++j) o[ob + j] = f2bf(accd[j] * inv);
    } else {
        #pragma unroll
        for (int j = 0; j < 16; ++j) {
            float s = 0.0f;
            for (int m = 0; m < L_; ++m)
                s += bf2f(qkv[(size_t)(b * L_ + m) * 1536 + 1024 + h * 64 + dq * 16 + j]);
            o[ob + j] = f2bf(s * (1.0f / L_));
        }
    }
}

// ---------------------------------------------------------------------------
// Launch
// ---------------------------------------------------------------------------
extern "C" void kernel_launch(void* const* d_in, const int* in_sizes, int n_in,
                              void* d_out, int out_size, void* d_ws, size_t ws_size,
                              hipStream_t stream) {
    (void)in_sizes; (void)n_in; (void)out_size; (void)ws_size;
    const int*   tokens = (const int*)d_in[0];
    const float* embed  = (const float*)d_in[1];
    const float* ln1_s  = (const float*)d_in[2];
    const float* ln1_b  = (const float*)d_in[3];
    const float* wq     = (const float*)d_in[4];
    const float* wk     = (const float*)d_in[5];
    const float* wv     = (const float*)d_in[6];
    const float* wo     = (const float*)d_in[7];
    const float* ln2_s  = (const float*)d_in[8];
    const float* ln2_b  = (const float*)d_in[9];
    const float* w1     = (const float*)d_in[10];
    const float* b1     = (const float*)d_in[11];
    const float* w2     = (const float*)d_in[12];
    const float* b2     = (const float*)d_in[13];
    const float* lnf_s  = (const float*)d_in[14];
    const float* lnf_b  = (const float*)d_in[15];
    float* out = (float*)d_out;

    const size_t BLE = (size_t)B_ * L_ * E_;              // 4,194,304
    char* ws = (char*)d_ws;
    float* x    = (float*)ws;                             // 16 MB
    short* yb   = (short*)(x + BLE);                      //  8 MB
    short* R    = yb + BLE;                               // 32 MB (qkv+ob / hb)
    short* qkv  = R;
    short* ob   = R + 3 * BLE;
    short* hb   = R;
    short* qkvt = R + 4 * BLE;                            // bf16 weights
    short* wot  = qkvt + (size_t)NL_ * 1536 * 512;
    short* w1t  = wot + (size_t)NL_ * 512 * 512;
    short* w2t  = w1t + (size_t)NL_ * 2048 * 512;
    float* pacc = (float*)(w2t + (size_t)NL_ * 512 * 2048);   // 8 slots x B x H x 4096 f32
    float* pm   = pacc + (size_t)8 * B_ * H_ * 4096;
    float* pl   = pm + (size_t)8 * B_ * H_ * 64;

    convT_kernel<<<dim3(8, 8, NL_), 256, 0, stream>>>(wq, qkvt,          512, 512, 262144, 786432, 0.125f);
    convT_kernel<<<dim3(8, 8, NL_), 256, 0, stream>>>(wk, qkvt + 262144, 512, 512, 262144, 786432, 1.0f);
    convT_kernel<<<dim3(8, 8, NL_), 256, 0, stream>>>(wv, qkvt + 524288, 512, 512, 262144, 786432, 1.0f);
    convT_kernel<<<dim3(8, 8, NL_), 256, 0, stream>>>(wo, wot,           512, 512, 262144, 262144, 1.0f);
    convT_kernel<<<dim3(32, 8, NL_), 256, 0, stream>>>(w1, w1t,          512, 2048, 1048576, 1048576, 1.0f);
    convT_kernel<<<dim3(8, 32, NL_), 256, 0, stream>>>(w2, w2t,          2048, 512, 1048576, 1048576, 1.0f);

    embed_kernel<<<(unsigned)(BLE / 256), 256, 0, stream>>>(tokens, embed, x);

    const int MR = B_ * L_;
    for (int lyr = 0; lyr < NL_; ++lyr) {
        ln_kernel<1><<<MR, 256, 0, stream>>>(x, ln1_s + lyr * E_, ln1_b + lyr * E_, yb);
        // QKV: 8192 x 1536 x 512, 128x128 tiles
        mgemm_kernel<128, 128, 2, 2, 0, 1><<<dim3(12, 64), 256, 0, stream>>>(
            yb, qkvt + (size_t)lyr * 786432, nullptr, nullptr, qkv, MR, 1536, 512);
        attn_kernel<<<dim3(WT_HOST.n_items[lyr], H_, B_), 256, 0, stream>>>(
            qkv, tokens, ob, pacc, pm, pl, lyr);
        attn_combine<<<dim3(WT_HOST.n_cmb[lyr], H_, B_), 256, 0, stream>>>(
            qkv, tokens, ob, pacc, pm, pl, lyr);
        // WO: 8192 x 512 x 512, 64x128 tiles -> 512 blocks (2/CU)
        mgemm_kernel<64, 128, 2, 2, 0, 0><<<dim3(4, 128), 256, 0, stream>>>(
            ob, wot + (size_t)lyr * 262144, nullptr, x, x, MR, 512, 512);
        ln_kernel<1><<<MR, 256, 0, stream>>>(x, ln2_s + lyr * E_, ln2_b + lyr * E_, yb);
        // W1: 8192 x 2048 x 512, 128x128 tiles
        mgemm_kernel<128, 128, 2, 2, 1, 1><<<dim3(16, 64), 256, 0, stream>>>(
            yb, w1t + (size_t)lyr * 1048576, b1 + (size_t)lyr * M_, nullptr, hb, MR, 2048, 512);
        // W2: 8192 x 512 x 2048, 64x128 tiles -> 512 blocks (2/CU)
        mgemm_kernel<64, 128, 2, 2, 0, 0><<<dim3(4, 128), 256, 0, stream>>>(
            hb, w2t + (size_t)lyr * 1048576, b2 + (size_t)lyr * E_, x, x, MR, 512, 2048);
    }
    ln_kernel<0><<<MR, 256, 0, stream>>>(x, lnf_s, lnf_b, out);
}

// Round 6
// 768.173 us; speedup vs baseline: 18.8838x; 1.1046x over previous
//
#include <hip/hip_runtime.h>
#include <hip/hip_bf16.h>
#include <cmath>
#include <cstdint>
#include <cstddef>

#define B_   4
#define L_   2048
#define E_   512
#define H_   8
#define DH_  64
#define M_   2048
#define NL_  4
#define NB_  32
#define BS_  64
#define CH_  12   // max jb-blocks per attention work item

typedef short bf16x8 __attribute__((ext_vector_type(8)));
typedef float f32x4 __attribute__((ext_vector_type(4)));

__device__ __forceinline__ short f2bf(float f) {
    union { __hip_bfloat16 h; short s; } u;
    u.h = __float2bfloat16(f);
    return u.s;
}
__device__ __forceinline__ float bf2f(short s) {
    union { short s; __hip_bfloat16 h; } u;
    u.s = s;
    return __bfloat162float(u.h);
}

// ---------------------------------------------------------------------------
// BigBird masks + work partition, all at COMPILE TIME.
// ---------------------------------------------------------------------------
struct MaskTable { unsigned m[NL_][NB_]; };
struct CxMT { unsigned key[624]; int pos; };

constexpr unsigned cx_next(CxMT& st) {
    if (st.pos >= 624) {
        for (int i = 0; i < 624; ++i) {
            unsigned y = (st.key[i] & 0x80000000u) | (st.key[(i + 1) % 624] & 0x7fffffffu);
            st.key[i] = st.key[(i + 397) % 624] ^ (y >> 1) ^ ((y & 1u) ? 0x9908b0dfu : 0u);
        }
        st.pos = 0;
    }
    unsigned y = st.key[st.pos++];
    y ^= y >> 11;
    y ^= (y << 7) & 0x9d2c5680u;
    y ^= (y << 15) & 0xefc60000u;
    y ^= y >> 18;
    return y;
}
constexpr unsigned cx_interval(CxMT& st, unsigned maxv) {
    if (maxv == 0u) return 0u;
    unsigned mask = maxv;
    mask |= mask >> 1; mask |= mask >> 2; mask |= mask >> 4;
    mask |= mask >> 8; mask |= mask >> 16;
    unsigned v = cx_next(st) & mask;
    while (v > maxv) v = cx_next(st) & mask;
    return v;
}
constexpr MaskTable compute_masks() {
    MaskTable T{};
    for (int lyr = 0; lyr < NL_; ++lyr) {
        unsigned m[NB_] = {};
        for (int i = 0; i < NB_; ++i) {
            unsigned w = 1u << i;
            if (i > 0) w |= 1u << (i - 1);
            if (i < NB_ - 1) w |= 1u << (i + 1);
            w |= 1u | (1u << (NB_ - 1));
            m[i] = w;
        }
        m[0] = 0xffffffffu;
        m[NB_ - 1] = 0xffffffffu;
        CxMT st{};
        unsigned s = (unsigned)lyr;
        for (int i = 0; i < 624; ++i) {
            st.key[i] = s;
            s = 1812433253u * (s ^ (s >> 30)) + (unsigned)i + 1u;
        }
        st.pos = 624;
        for (int i = 1; i < NB_ - 1; ++i) {
            int cand[NB_] = {};
            int n = 0;
            for (int j = 0; j < NB_; ++j) {
                if (j == 0 || j == NB_ - 1 || j == i - 1 || j == i || j == i + 1) continue;
                cand[n++] = j;
            }
            for (int kk = n - 1; kk >= 1; --kk) {
                int jj = (int)cx_interval(st, (unsigned)kk);
                int tmp = cand[kk]; cand[kk] = cand[jj]; cand[jj] = tmp;
            }
            m[i] |= (1u << cand[0]) | (1u << cand[1]) | (1u << cand[2]);
        }
        for (int i = 0; i < NB_; ++i) T.m[lyr][i] = m[i];
    }
    return T;
}

struct WorkTable {
    int n_items[NL_];
    int n_cmb[NL_];
    unsigned char itm_qb[NL_][40];
    unsigned char itm_j0[NL_][40];
    unsigned char itm_jn[NL_][40];
    unsigned char itm_slot[NL_][40];   // 0xFF = direct write to o
    unsigned char cmb_qb[NL_][8];
    unsigned char cmb_slot0[NL_][8];
    unsigned char cmb_nch[NL_][8];
    unsigned char jlist[NL_][NB_][NB_];
};

constexpr WorkTable compute_work() {
    WorkTable T{};
    MaskTable M = compute_masks();
    for (int lyr = 0; lyr < NL_; ++lyr) {
        int items = 0, slots = 0, ncmb = 0;
        for (int qb = 0; qb < NB_; ++qb) {
            int cnt = 0;
            for (int j = 0; j < NB_; ++j)
                if ((M.m[lyr][qb] >> j) & 1u)
                    T.jlist[lyr][qb][cnt++] = (unsigned char)j;
            int nch = (cnt + CH_ - 1) / CH_;
            if (nch == 1) {
                T.itm_qb[lyr][items] = (unsigned char)qb;
                T.itm_j0[lyr][items] = 0;
                T.itm_jn[lyr][items] = (unsigned char)cnt;
                T.itm_slot[lyr][items] = 0xFF;
                items++;
            } else {
                T.cmb_qb[lyr][ncmb] = (unsigned char)qb;
                T.cmb_slot0[lyr][ncmb] = (unsigned char)slots;
                T.cmb_nch[lyr][ncmb] = (unsigned char)nch;
                ncmb++;
                int base = cnt / nch, rem = cnt % nch, off = 0;
                for (int c = 0; c < nch; ++c) {
                    int cl = base + (c < rem ? 1 : 0);
                    T.itm_qb[lyr][items] = (unsigned char)qb;
                    T.itm_j0[lyr][items] = (unsigned char)off;
                    T.itm_jn[lyr][items] = (unsigned char)cl;
                    T.itm_slot[lyr][items] = (unsigned char)slots;
                    items++; slots++; off += cl;
                }
            }
        }
        T.n_items[lyr] = items;
        T.n_cmb[lyr] = ncmb;
    }
    return T;
}

static constexpr WorkTable WT_HOST = compute_work();
__constant__ WorkTable g_wt = compute_work();

// ---------------------------------------------------------------------------
// Embedding + sinusoidal PE (fp32 residual stream)
// ---------------------------------------------------------------------------
__global__ __launch_bounds__(256) void embed_kernel(const int* __restrict__ tokens,
                                                    const float* __restrict__ embed,
                                                    float* __restrict__ x) {
    size_t i = (size_t)blockIdx.x * 256 + threadIdx.x;
    int e = (int)(i & (E_ - 1));
    size_t bl = i >> 9;
    int l = (int)(bl & (L_ - 1));
    int tok = tokens[bl];
    int j = e & 255;
    float div = expf((float)j * -0.03597789207717895f);  // -ln(10000)/256
    float arg = (float)l * div;
    float pe = (e < 256) ? sinf(arg) : cosf(arg);
    x[i] = embed[(size_t)tok * E_ + e] + pe;
}

// ---------------------------------------------------------------------------
// LayerNorm: fp32 input, bf16 (OUTBF=1) or fp32 (OUTBF=0) output
// ---------------------------------------------------------------------------
template<int OUTBF>
__global__ __launch_bounds__(256) void ln_kernel(const float* __restrict__ x,
                                                 const float* __restrict__ gamma,
                                                 const float* __restrict__ beta,
                                                 void* __restrict__ yout) {
    __shared__ float sh[4];
    int row = blockIdx.x, t = threadIdx.x;
    const float* xr = x + (size_t)row * E_;
    float a = xr[t], c = xr[t + 256];
    float s = a + c;
    #pragma unroll
    for (int off = 1; off < 64; off <<= 1) s += __shfl_xor(s, off, 64);
    if ((t & 63) == 0) sh[t >> 6] = s;
    __syncthreads();
    s = sh[0] + sh[1] + sh[2] + sh[3];
    float mu = s * (1.0f / E_);
    float da = a - mu, dc = c - mu;
    float q = da * da + dc * dc;
    __syncthreads();
    #pragma unroll
    for (int off = 1; off < 64; off <<= 1) q += __shfl_xor(q, off, 64);
    if ((t & 63) == 0) sh[t >> 6] = q;
    __syncthreads();
    q = sh[0] + sh[1] + sh[2] + sh[3];
    float rstd = rsqrtf(q * (1.0f / E_) + 1e-6f);
    float v0 = da * rstd * gamma[t] + beta[t];
    float v1 = dc * rstd * gamma[t + 256] + beta[t + 256];
    if (OUTBF) {
        short* yr = (short*)yout + (size_t)row * E_;
        yr[t] = f2bf(v0);
        yr[t + 256] = f2bf(v1);
    } else {
        float* yr = (float*)yout + (size_t)row * E_;
        yr[t] = v0;
        yr[t + 256] = v1;
    }
}

// ---------------------------------------------------------------------------
// Weight convert + transpose: Wt[n][k] = bf16(W[k][n] * scale), per layer (z)
// ---------------------------------------------------------------------------
__global__ __launch_bounds__(256) void convT_kernel(const float* __restrict__ W,
                                                    short* __restrict__ Wt,
                                                    int K, int N,
                                                    size_t wStride, size_t wtStride,
                                                    float scale) {
    __shared__ float Ts[64][65];
    const float* Wl = W + blockIdx.z * wStride;
    short* Wtl = Wt + blockIdx.z * wtStride;
    int n0 = blockIdx.x * 64, k0 = blockIdx.y * 64;
    int t = threadIdx.x;
    int c = t & 63, r0 = t >> 6;
    #pragma unroll
    for (int i = 0; i < 16; ++i) {
        int r = r0 * 16 + i;
        Ts[r][c] = Wl[(size_t)(k0 + r) * N + n0 + c] * scale;
    }
    __syncthreads();
    #pragma unroll
    for (int i = 0; i < 16; ++i) {
        int r = r0 * 16 + i;
        Wtl[(size_t)(n0 + r) * K + k0 + c] = f2bf(Ts[c][r]);
    }
}

// ---------------------------------------------------------------------------
// MFMA bf16 GEMM, 2-phase double-buffered (T3-minimum):
//   stage(t+1) issued BEFORE compute(t); single raw s_barrier per K-iter with
//   trailing s_waitcnt vmcnt(0) -> next-tile load latency hides under MFMA.
// C[M,N] = act(A[M,K] * Bt[N,K]^T + bias) + res. T2 XOR swizzle on LDS tiles
// (linear gload_lds dest + pre-swizzled global src + swizzled ds_read).
// Epilogue staged through LDS for coalesced vector stores / res reads.
// ---------------------------------------------------------------------------
__device__ __forceinline__ float gelu_tanh(float x) {
    // x * sigmoid(1.59576912x + 0.07135548x^3)  == 0.5x(1+tanh(0.79788(x+0.044715x^3)))
    float u = x * (1.5957691216057308f + 0.07135480122394604f * x * x);
    return x / (1.0f + __expf(-u));
}

template<int BM, int BN, int WR, int WC, int ACT, int OUTBF>
__global__ __launch_bounds__(256) void mgemm_kernel(const short* __restrict__ A,
                                                    const short* __restrict__ Bt,
                                                    const float* __restrict__ bias,
                                                    const float* __restrict__ res,
                                                    void* __restrict__ Cout,
                                                    int M, int N, int K) {
    constexpr int FM = BM / WR / 16;   // A fragments per wave
    constexpr int FN = BN / WC / 16;   // B fragments per wave
    constexpr int ASZ = BM * 64;       // shorts per A buffer
    constexpr int BSZ = BN * 64;
    constexpr int PAD = 8;
    constexpr int CW = BN + PAD;       // epilogue LDS row stride
    static_assert((size_t)(OUTBF ? BM * CW * 2 : BM * CW * 4) <= (size_t)2 * (ASZ + BSZ) * 2,
                  "epilogue stage must fit in dbuf LDS");
    __shared__ __align__(16) short smem[2 * (ASZ + BSZ)];

    int t = threadIdx.x;
    int w = t >> 6, l = t & 63;
    int l15 = l & 15, lg = l >> 4;
    int wr = w / WC, wc = w % WC;
    int rowbase = wr * (BM / WR), colbase = wc * (BN / WC);
    int brow = blockIdx.y * BM, bcol = blockIdx.x * BN;
    int swz = ((l & 7) ^ (l >> 3)) * 8;    // pre-swizzled global chunk offset
    int lrow = l >> 3;
    f32x4 acc[FM][FN] = {};

    const int nt = K >> 6;

    auto stage = [&](int buf, int k0) {
        short* Ad = smem + buf * ASZ;
        short* Bd = smem + 2 * ASZ + buf * BSZ;
        #pragma unroll
        for (int it = 0; it < BM / 32; ++it) {
            int row8 = (it * 4 + w) * 8;
            const short* ga = A + (size_t)(brow + row8 + lrow) * K + k0 + swz;
            __builtin_amdgcn_global_load_lds(
                (const __attribute__((address_space(1))) unsigned int*)ga,
                (__attribute__((address_space(3))) unsigned int*)(Ad + row8 * 64),
                16, 0, 0);
        }
        #pragma unroll
        for (int it = 0; it < BN / 32; ++it) {
            int row8 = (it * 4 + w) * 8;
            const short* gb = Bt + (size_t)(bcol + row8 + lrow) * K + k0 + swz;
            __builtin_amdgcn_global_load_lds(
                (const __attribute__((address_space(1))) unsigned int*)gb,
                (__attribute__((address_space(3))) unsigned int*)(Bd + row8 * 64),
                16, 0, 0);
        }
    };

    stage(0, 0);
    asm volatile("s_waitcnt vmcnt(0)" ::: "memory");
    __builtin_amdgcn_s_barrier();

    int cur = 0;
    for (int kt = 0; kt < nt; ++kt) {
        if (kt + 1 < nt) stage(cur ^ 1, (kt + 1) << 6);   // prefetch next tile
        const short* Ar = smem + cur * ASZ;
        const short* Br = smem + 2 * ASZ + cur * BSZ;
        #pragma unroll
        for (int kk = 0; kk < 64; kk += 32) {
            bf16x8 af[FM], bfr[FN];
            #pragma unroll
            for (int m = 0; m < FM; ++m)
                af[m] = *(const bf16x8*)(Ar + (rowbase + m * 16 + l15) * 64
                                            + (((kk >> 3) + lg) ^ (l15 & 7)) * 8);
            #pragma unroll
            for (int n = 0; n < FN; ++n)
                bfr[n] = *(const bf16x8*)(Br + (colbase + n * 16 + l15) * 64
                                             + (((kk >> 3) + lg) ^ (l15 & 7)) * 8);
            #pragma unroll
            for (int m = 0; m < FM; ++m)
                #pragma unroll
                for (int n = 0; n < FN; ++n)
                    acc[m][n] = __builtin_amdgcn_mfma_f32_16x16x32_bf16(af[m], bfr[n], acc[m][n], 0, 0, 0);
        }
        asm volatile("s_waitcnt vmcnt(0) lgkmcnt(0)" ::: "memory");
        __builtin_amdgcn_s_barrier();
        cur ^= 1;
    }

    // ---- epilogue: stage C tile in LDS, then coalesced vector stores ----
    if (OUTBF) {
        short* Cs = smem;                       // [BM][CW] bf16
        #pragma unroll
        for (int m = 0; m < FM; ++m) {
            int row = rowbase + m * 16 + lg * 4;
            #pragma unroll
            for (int n = 0; n < FN; ++n) {
                int col = colbase + n * 16 + l15;
                float bv = bias ? bias[bcol + col] : 0.0f;
                #pragma unroll
                for (int r = 0; r < 4; ++r) {
                    float vv = acc[m][n][r] + bv;
                    if (ACT == 1) vv = gelu_tanh(vv);
                    Cs[(row + r) * CW + col] = f2bf(vv);
                }
            }
        }
        __syncthreads();
        #pragma unroll
        for (int it = 0; it < BM * BN / 8 / 256; ++it) {
            int c = it * 256 + t;
            int row = c / (BN / 8), c8 = c % (BN / 8);
            *(bf16x8*)((short*)Cout + (size_t)(brow + row) * N + bcol + c8 * 8) =
                *(const bf16x8*)(Cs + row * CW + c8 * 8);
        }
    } else {
        float* Cs = (float*)smem;               // [BM][CW] f32
        #pragma unroll
        for (int m = 0; m < FM; ++m) {
            int row = rowbase + m * 16 + lg * 4;
            #pragma unroll
            for (int n = 0; n < FN; ++n) {
                int col = colbase + n * 16 + l15;
                float bv = bias ? bias[bcol + col] : 0.0f;
                #pragma unroll
                for (int r = 0; r < 4; ++r)
                    Cs[(row + r) * CW + col] = acc[m][n][r] + bv;
            }
        }
        __syncthreads();
        #pragma unroll
        for (int it = 0; it < BM * BN / 4 / 256; ++it) {
            int c = it * 256 + t;
            int row = c / (BN / 4), c4 = c % (BN / 4);
            f32x4 vv = *(const f32x4*)(Cs + row * CW + c4 * 4);
            size_t gi = (size_t)(brow + row) * N + bcol + c4 * 4;
            if (res) vv += *(const f32x4*)(res + gi);
            *(f32x4*)((float*)Cout + gi) = vv;
        }
    }
}

// ---------------------------------------------------------------------------
// Sparse block attention, MFMA bf16, chunked work items + flash-split.
// ---------------------------------------------------------------------------
#define KSTR 72

__global__ __launch_bounds__(256) void attn_kernel(const short* __restrict__ qkv,
                                                   const int* __restrict__ tokens,
                                                   short* __restrict__ o,
                                                   float* __restrict__ pacc,
                                                   float* __restrict__ pm,
                                                   float* __restrict__ pl,
                                                   int lyr) {
    __shared__ __align__(16) short Ks[64][KSTR];
    __shared__ __align__(16) short Vt[64][KSTR];
    __shared__ __align__(16) short Pw[4][16][KSTR];
    __shared__ int padk[64];
    __shared__ int padq[64];

    int item = blockIdx.x, h = blockIdx.y, b = blockIdx.z;
    int qb   = g_wt.itm_qb[lyr][item];
    int j0   = g_wt.itm_j0[lyr][item];
    int jn   = g_wt.itm_jn[lyr][item];
    int slot = g_wt.itm_slot[lyr][item];
    const unsigned char* jl = g_wt.jlist[lyr][qb];

    int t = threadIdx.x;
    int l = t & 63, w = t >> 6;
    int l15 = l & 15, lg = l >> 4;
    int srow = t >> 3, sdb = t & 7;

    if (t < 64) padq[t] = tokens[b * L_ + qb * 64 + t] > 0;

    int qrow = qb * 64 + w * 16 + l15;
    const short* qp = qkv + (size_t)(b * L_ + qrow) * 1536 + h * 64;
    bf16x8 qf0 = *(const bf16x8*)(qp + lg * 8);
    bf16x8 qf1 = *(const bf16x8*)(qp + lg * 8 + 32);

    f32x4 acc[4] = {};
    float m_r[4], l_r[4];
    #pragma unroll
    for (int r = 0; r < 4; ++r) { m_r[r] = -INFINITY; l_r[r] = 0.0f; }

    bf16x8 k0, k1, v0, v1;
    int pn = 0;
    {
        int jb = jl[j0];
        const short* base = qkv + (size_t)(b * L_ + jb * 64 + srow) * 1536 + h * 64;
        k0 = *(const bf16x8*)(base + 512 + sdb * 8);
        k1 = *(const bf16x8*)(base + (size_t)32 * 1536 + 512 + sdb * 8);
        v0 = *(const bf16x8*)(base + 1024 + sdb * 8);
        v1 = *(const bf16x8*)(base + (size_t)32 * 1536 + 1024 + sdb * 8);
        if (t < 64) pn = tokens[b * L_ + jb * 64 + t];
    }

    for (int ci = 0; ci < jn; ++ci) {
        __syncthreads();
        *(bf16x8*)&Ks[srow][sdb * 8] = k0;
        *(bf16x8*)&Ks[srow + 32][sdb * 8] = k1;
        #pragma unroll
        for (int j = 0; j < 8; ++j) {
            Vt[sdb * 8 + j][(srow & 7) + 8 * ((srow >> 3) ^ sdb)] = v0[j];
            Vt[sdb * 8 + j][(srow & 7) + 8 * (((srow >> 3) + 4) ^ sdb)] = v1[j];
        }
        if (t < 64) padk[t] = pn > 0;
        __syncthreads();

        if (ci + 1 < jn) {
            int jb = jl[j0 + ci + 1];
            const short* base = qkv + (size_t)(b * L_ + jb * 64 + srow) * 1536 + h * 64;
            k0 = *(const bf16x8*)(base + 512 + sdb * 8);
            k1 = *(const bf16x8*)(base + (size_t)32 * 1536 + 512 + sdb * 8);
            v0 = *(const bf16x8*)(base + 1024 + sdb * 8);
            v1 = *(const bf16x8*)(base + (size_t)32 * 1536 + 1024 + sdb * 8);
            if (t < 64) pn = tokens[b * L_ + jb * 64 + t];
        }

        f32x4 sacc[4];
        #pragma unroll
        for (int f = 0; f < 4; ++f) {
            bf16x8 kk0 = *(const bf16x8*)&Ks[16 * f + l15][lg * 8];
            bf16x8 kk1 = *(const bf16x8*)&Ks[16 * f + l15][lg * 8 + 32];
            f32x4 z = {};
            z = __builtin_amdgcn_mfma_f32_16x16x32_bf16(qf0, kk0, z, 0, 0, 0);
            z = __builtin_amdgcn_mfma_f32_16x16x32_bf16(qf1, kk1, z, 0, 0, 0);
            sacc[f] = z;
        }

        int mc[4], mrow[4];
        #pragma unroll
        for (int f = 0; f < 4; ++f) mc[f] = padk[16 * f + l15];
        #pragma unroll
        for (int r = 0; r < 4; ++r) mrow[r] = padq[w * 16 + lg * 4 + r];

        float alpha[4];
        #pragma unroll
        for (int r = 0; r < 4; ++r) {
            float mx = -INFINITY;
            #pragma unroll
            for (int f = 0; f < 4; ++f)
                if (mc[f] && mrow[r]) mx = fmaxf(mx, sacc[f][r]);
            mx = fmaxf(mx, __shfl_xor(mx, 1, 64));
            mx = fmaxf(mx, __shfl_xor(mx, 2, 64));
            mx = fmaxf(mx, __shfl_xor(mx, 4, 64));
            mx = fmaxf(mx, __shfl_xor(mx, 8, 64));
            float nm = fmaxf(m_r[r], mx);
            float sum = 0.0f;
            #pragma unroll
            for (int f = 0; f < 4; ++f) {
                float p = (mc[f] && mrow[r]) ? __expf(sacc[f][r] - nm) : 0.0f;
                Pw[w][lg * 4 + r][16 * f + l15] = f2bf(p);
                sum += p;
            }
            sum += __shfl_xor(sum, 1, 64);
            sum += __shfl_xor(sum, 2, 64);
            sum += __shfl_xor(sum, 4, 64);
            sum += __shfl_xor(sum, 8, 64);
            float al = (nm == -INFINITY) ? 1.0f : __expf(m_r[r] - nm);
            m_r[r] = nm;
            l_r[r] = l_r[r] * al + sum;
            alpha[r] = al;
        }
        #pragma unroll
        for (int fd = 0; fd < 4; ++fd)
            #pragma unroll
            for (int r = 0; r < 4; ++r) acc[fd][r] *= alpha[r];

        bf16x8 pa0 = *(const bf16x8*)&Pw[w][l15][lg * 8];
        bf16x8 pa1 = *(const bf16x8*)&Pw[w][l15][lg * 8 + 32];
        #pragma unroll
        for (int fd = 0; fd < 4; ++fd) {
            int dd = 16 * fd + l15;
            bf16x8 vv0 = *(const bf16x8*)&Vt[dd][8 * (lg ^ (dd >> 3))];
            bf16x8 vv1 = *(const bf16x8*)&Vt[dd][8 * ((4 + lg) ^ (dd >> 3))];
            acc[fd] = __builtin_amdgcn_mfma_f32_16x16x32_bf16(pa0, vv0, acc[fd], 0, 0, 0);
            acc[fd] = __builtin_amdgcn_mfma_f32_16x16x32_bf16(pa1, vv1, acc[fd], 0, 0, 0);
        }
    }

    if (slot == 0xFF) {
        #pragma unroll
        for (int r = 0; r < 4; ++r) {
            int rw = lg * 4 + r;
            int gl = qb * 64 + w * 16 + rw;
            size_t ob = (size_t)(b * L_ + gl) * 512 + h * 64 + l15;
            bool ok = (padq[w * 16 + rw] != 0) && (l_r[r] > 0.0f);
            if (ok) {
                float inv = 1.0f / l_r[r];
                #pragma unroll
                for (int fd = 0; fd < 4; ++fd) o[ob + 16 * fd] = f2bf(acc[fd][r] * inv);
            } else {
                #pragma unroll
                for (int fd = 0; fd < 4; ++fd) {
                    float s = 0.0f;
                    for (int m = 0; m < L_; ++m)
                        s += bf2f(qkv[(size_t)(b * L_ + m) * 1536 + 1024 + h * 64 + 16 * fd + l15]);
                    o[ob + 16 * fd] = f2bf(s * (1.0f / L_));
                }
            }
        }
    } else {
        size_t pb = ((size_t)slot * B_ + b) * H_ + h;
        #pragma unroll
        for (int r = 0; r < 4; ++r) {
            int rloc = w * 16 + lg * 4 + r;
            #pragma unroll
            for (int fd = 0; fd < 4; ++fd)
                pacc[pb * 4096 + (size_t)rloc * 64 + 16 * fd + l15] = acc[fd][r];
            if (l15 == 0) {
                pm[pb * 64 + rloc] = m_r[r];
                pl[pb * 64 + rloc] = l_r[r];
            }
        }
    }
}

// ---------------------------------------------------------------------------
// Combine partial flash results for split q-blocks.
// ---------------------------------------------------------------------------
__global__ __launch_bounds__(256) void attn_combine(const short* __restrict__ qkv,
                                                    const int* __restrict__ tokens,
                                                    short* __restrict__ o,
                                                    const float* __restrict__ pacc,
                                                    const float* __restrict__ pm,
                                                    const float* __restrict__ pl,
                                                    int lyr) {
    int ci = blockIdx.x, h = blockIdx.y, b = blockIdx.z;
    int qb  = g_wt.cmb_qb[lyr][ci];
    int s0  = g_wt.cmb_slot0[lyr][ci];
    int nch = g_wt.cmb_nch[lyr][ci];
    int t = threadIdx.x;
    int r = t >> 2, dq = t & 3;
    int grow = qb * 64 + r;
    bool pq = tokens[b * L_ + grow] > 0;
    float M = -INFINITY;
    for (int c = 0; c < nch; ++c)
        M = fmaxf(M, pm[(((size_t)(s0 + c) * B_ + b) * H_ + h) * 64 + r]);
    size_t ob = (size_t)(b * L_ + grow) * 512 + h * 64 + dq * 16;
    if (pq && M > -1e30f) {
        float lsum = 0.0f;
        float accd[16] = {};
        for (int c = 0; c < nch; ++c) {
            size_t pb = ((size_t)(s0 + c) * B_ + b) * H_ + h;
            float wgt = __expf(pm[pb * 64 + r] - M);
            lsum += pl[pb * 64 + r] * wgt;
            const float* pa = pacc + pb * 4096 + (size_t)r * 64 + dq * 16;
            #pragma unroll
            for (int j = 0; j < 16; ++j) accd[j] += pa[j] * wgt;
        }
        float inv = 1.0f / lsum;
        #pragma unroll
        for (int j = 0; j < 16; ++j) o[ob + j] = f2bf(accd[j] * inv);
    } else {
        #pragma unroll
        for (int j = 0; j < 16; ++j) {
            float s = 0.0f;
            for (int m = 0; m < L_; ++m)
                s += bf2f(qkv[(size_t)(b * L_ + m) * 1536 + 1024 + h * 64 + dq * 16 + j]);
            o[ob + j] = f2bf(s * (1.0f / L_));
        }
    }
}

// ---------------------------------------------------------------------------
// Launch
// ---------------------------------------------------------------------------
extern "C" void kernel_launch(void* const* d_in, const int* in_sizes, int n_in,
                              void* d_out, int out_size, void* d_ws, size_t ws_size,
                              hipStream_t stream) {
    (void)in_sizes; (void)n_in; (void)out_size; (void)ws_size;
    const int*   tokens = (const int*)d_in[0];
    const float* embed  = (const float*)d_in[1];
    const float* ln1_s  = (const float*)d_in[2];
    const float* ln1_b  = (const float*)d_in[3];
    const float* wq     = (const float*)d_in[4];
    const float* wk     = (const float*)d_in[5];
    const float* wv     = (const float*)d_in[6];
    const float* wo     = (const float*)d_in[7];
    const float* ln2_s  = (const float*)d_in[8];
    const float* ln2_b  = (const float*)d_in[9];
    const float* w1     = (const float*)d_in[10];
    const float* b1     = (const float*)d_in[11];
    const float* w2     = (const float*)d_in[12];
    const float* b2     = (const float*)d_in[13];
    const float* lnf_s  = (const float*)d_in[14];
    const float* lnf_b  = (const float*)d_in[15];
    float* out = (float*)d_out;

    const size_t BLE = (size_t)B_ * L_ * E_;              // 4,194,304
    char* ws = (char*)d_ws;
    float* x    = (float*)ws;                             // 16 MB
    short* yb   = (short*)(x + BLE);                      //  8 MB
    short* R    = yb + BLE;                               // 32 MB (qkv+ob / hb)
    short* qkv  = R;
    short* ob   = R + 3 * BLE;
    short* hb   = R;
    short* qkvt = R + 4 * BLE;                            // bf16 weights
    short* wot  = qkvt + (size_t)NL_ * 1536 * 512;
    short* w1t  = wot + (size_t)NL_ * 512 * 512;
    short* w2t  = w1t + (size_t)NL_ * 2048 * 512;
    float* pacc = (float*)(w2t + (size_t)NL_ * 512 * 2048);   // 8 slots x B x H x 4096 f32
    float* pm   = pacc + (size_t)8 * B_ * H_ * 4096;
    float* pl   = pm + (size_t)8 * B_ * H_ * 64;

    convT_kernel<<<dim3(8, 8, NL_), 256, 0, stream>>>(wq, qkvt,          512, 512, 262144, 786432, 0.125f);
    convT_kernel<<<dim3(8, 8, NL_), 256, 0, stream>>>(wk, qkvt + 262144, 512, 512, 262144, 786432, 1.0f);
    convT_kernel<<<dim3(8, 8, NL_), 256, 0, stream>>>(wv, qkvt + 524288, 512, 512, 262144, 786432, 1.0f);
    convT_kernel<<<dim3(8, 8, NL_), 256, 0, stream>>>(wo, wot,           512, 512, 262144, 262144, 1.0f);
    convT_kernel<<<dim3(32, 8, NL_), 256, 0, stream>>>(w1, w1t,          512, 2048, 1048576, 1048576, 1.0f);
    convT_kernel<<<dim3(8, 32, NL_), 256, 0, stream>>>(w2, w2t,          2048, 512, 1048576, 1048576, 1.0f);

    embed_kernel<<<(unsigned)(BLE / 256), 256, 0, stream>>>(tokens, embed, x);

    const int MR = B_ * L_;
    for (int lyr = 0; lyr < NL_; ++lyr) {
        ln_kernel<1><<<MR, 256, 0, stream>>>(x, ln1_s + lyr * E_, ln1_b + lyr * E_, yb);
        // QKV: 8192 x 1536 x 512, 128x128 tiles
        mgemm_kernel<128, 128, 2, 2, 0, 1><<<dim3(12, 64), 256, 0, stream>>>(
            yb, qkvt + (size_t)lyr * 786432, nullptr, nullptr, qkv, MR, 1536, 512);
        attn_kernel<<<dim3(WT_HOST.n_items[lyr], H_, B_), 256, 0, stream>>>(
            qkv, tokens, ob, pacc, pm, pl, lyr);
        attn_combine<<<dim3(WT_HOST.n_cmb[lyr], H_, B_), 256, 0, stream>>>(
            qkv, tokens, ob, pacc, pm, pl, lyr);
        // WO: 8192 x 512 x 512, 64x128 tiles -> 512 blocks
        mgemm_kernel<64, 128, 2, 2, 0, 0><<<dim3(4, 128), 256, 0, stream>>>(
            ob, wot + (size_t)lyr * 262144, nullptr, x, x, MR, 512, 512);
        ln_kernel<1><<<MR, 256, 0, stream>>>(x, ln2_s + lyr * E_, ln2_b + lyr * E_, yb);
        // W1: 8192 x 2048 x 512, 128x128 tiles
        mgemm_kernel<128, 128, 2, 2, 1, 1><<<dim3(16, 64), 256, 0, stream>>>(
            yb, w1t + (size_t)lyr * 1048576, b1 + (size_t)lyr * M_, nullptr, hb, MR, 2048, 512);
        // W2: 8192 x 512 x 2048, 64x128 tiles -> 512 blocks
        mgemm_kernel<64, 128, 2, 2, 0, 0><<<dim3(4, 128), 256, 0, stream>>>(
            hb, w2t + (size_t)lyr * 1048576, b2 + (size_t)lyr * E_, x, x, MR, 512, 2048);
    }
    ln_kernel<0><<<MR, 256, 0, stream>>>(x, lnf_s, lnf_b, out);
}

// Round 7
// 746.302 us; speedup vs baseline: 19.4372x; 1.0293x over previous
//
#include <hip/hip_runtime.h>
#include <hip/hip_bf16.h>
#include <cmath>
#include <cstdint>
#include <cstddef>

#define B_   4
#define L_   2048
#define E_   512
#define H_   8
#define DH_  64
#define M_   2048
#define NL_  4
#define NB_  32
#define BS_  64
#define CH_  12   // max 64-key jb-blocks per attention work item

typedef short bf16x8 __attribute__((ext_vector_type(8)));
typedef float f32x4 __attribute__((ext_vector_type(4)));

__device__ __forceinline__ short f2bf(float f) {
    union { __hip_bfloat16 h; short s; } u;
    u.h = __float2bfloat16(f);
    return u.s;
}
__device__ __forceinline__ float bf2f(short s) {
    union { short s; __hip_bfloat16 h; } u;
    u.s = s;
    return __bfloat162float(u.h);
}

// ---------------------------------------------------------------------------
// BigBird masks + work partition, all at COMPILE TIME.
// ---------------------------------------------------------------------------
struct MaskTable { unsigned m[NL_][NB_]; };
struct CxMT { unsigned key[624]; int pos; };

constexpr unsigned cx_next(CxMT& st) {
    if (st.pos >= 624) {
        for (int i = 0; i < 624; ++i) {
            unsigned y = (st.key[i] & 0x80000000u) | (st.key[(i + 1) % 624] & 0x7fffffffu);
            st.key[i] = st.key[(i + 397) % 624] ^ (y >> 1) ^ ((y & 1u) ? 0x9908b0dfu : 0u);
        }
        st.pos = 0;
    }
    unsigned y = st.key[st.pos++];
    y ^= y >> 11;
    y ^= (y << 7) & 0x9d2c5680u;
    y ^= (y << 15) & 0xefc60000u;
    y ^= y >> 18;
    return y;
}
constexpr unsigned cx_interval(CxMT& st, unsigned maxv) {
    if (maxv == 0u) return 0u;
    unsigned mask = maxv;
    mask |= mask >> 1; mask |= mask >> 2; mask |= mask >> 4;
    mask |= mask >> 8; mask |= mask >> 16;
    unsigned v = cx_next(st) & mask;
    while (v > maxv) v = cx_next(st) & mask;
    return v;
}
constexpr MaskTable compute_masks() {
    MaskTable T{};
    for (int lyr = 0; lyr < NL_; ++lyr) {
        unsigned m[NB_] = {};
        for (int i = 0; i < NB_; ++i) {
            unsigned w = 1u << i;
            if (i > 0) w |= 1u << (i - 1);
            if (i < NB_ - 1) w |= 1u << (i + 1);
            w |= 1u | (1u << (NB_ - 1));
            m[i] = w;
        }
        m[0] = 0xffffffffu;
        m[NB_ - 1] = 0xffffffffu;
        CxMT st{};
        unsigned s = (unsigned)lyr;
        for (int i = 0; i < 624; ++i) {
            st.key[i] = s;
            s = 1812433253u * (s ^ (s >> 30)) + (unsigned)i + 1u;
        }
        st.pos = 624;
        for (int i = 1; i < NB_ - 1; ++i) {
            int cand[NB_] = {};
            int n = 0;
            for (int j = 0; j < NB_; ++j) {
                if (j == 0 || j == NB_ - 1 || j == i - 1 || j == i || j == i + 1) continue;
                cand[n++] = j;
            }
            for (int kk = n - 1; kk >= 1; --kk) {
                int jj = (int)cx_interval(st, (unsigned)kk);
                int tmp = cand[kk]; cand[kk] = cand[jj]; cand[jj] = tmp;
            }
            m[i] |= (1u << cand[0]) | (1u << cand[1]) | (1u << cand[2]);
        }
        for (int i = 0; i < NB_; ++i) T.m[lyr][i] = m[i];
    }
    return T;
}

struct WorkTable {
    int n_items[NL_];
    int n_cmb[NL_];
    unsigned char itm_qb[NL_][40];
    unsigned char itm_j0[NL_][40];
    unsigned char itm_jn[NL_][40];
    unsigned char itm_slot[NL_][40];   // 0xFF = direct write to o
    unsigned char cmb_qb[NL_][8];
    unsigned char cmb_slot0[NL_][8];
    unsigned char cmb_nch[NL_][8];
    unsigned char jlist[NL_][NB_][NB_];
};

constexpr WorkTable compute_work() {
    WorkTable T{};
    MaskTable M = compute_masks();
    for (int lyr = 0; lyr < NL_; ++lyr) {
        int items = 0, slots = 0, ncmb = 0;
        for (int qb = 0; qb < NB_; ++qb) {
            int cnt = 0;
            for (int j = 0; j < NB_; ++j)
                if ((M.m[lyr][qb] >> j) & 1u)
                    T.jlist[lyr][qb][cnt++] = (unsigned char)j;
            int nch = (cnt + CH_ - 1) / CH_;
            if (nch == 1) {
                T.itm_qb[lyr][items] = (unsigned char)qb;
                T.itm_j0[lyr][items] = 0;
                T.itm_jn[lyr][items] = (unsigned char)cnt;
                T.itm_slot[lyr][items] = 0xFF;
                items++;
            } else {
                T.cmb_qb[lyr][ncmb] = (unsigned char)qb;
                T.cmb_slot0[lyr][ncmb] = (unsigned char)slots;
                T.cmb_nch[lyr][ncmb] = (unsigned char)nch;
                ncmb++;
                int base = cnt / nch, rem = cnt % nch, off = 0;
                for (int c = 0; c < nch; ++c) {
                    int cl = base + (c < rem ? 1 : 0);
                    T.itm_qb[lyr][items] = (unsigned char)qb;
                    T.itm_j0[lyr][items] = (unsigned char)off;
                    T.itm_jn[lyr][items] = (unsigned char)cl;
                    T.itm_slot[lyr][items] = (unsigned char)slots;
                    items++; slots++; off += cl;
                }
            }
        }
        T.n_items[lyr] = items;
        T.n_cmb[lyr] = ncmb;
    }
    return T;
}

static constexpr WorkTable WT_HOST = compute_work();
__constant__ WorkTable g_wt = compute_work();

// ---------------------------------------------------------------------------
// Embedding + sinusoidal PE. One thread per (l, 8-wide e chunk); PE computed
// once and reused across the 4 batches (4x fewer sinf/expf).
// ---------------------------------------------------------------------------
__global__ __launch_bounds__(256) void embed_kernel(const int* __restrict__ tokens,
                                                    const float* __restrict__ embed,
                                                    float* __restrict__ x) {
    int idx = blockIdx.x * 256 + threadIdx.x;      // < L_*E_/8 = 131072
    int l = idx >> 6;
    int e0 = (idx & 63) * 8;
    float pe[8];
    #pragma unroll
    for (int j = 0; j < 8; ++j) {
        int e = e0 + j;
        int jj = e & 255;
        float div = expf((float)jj * -0.03597789207717895f);  // -ln(10000)/256
        float arg = (float)l * div;
        pe[j] = (e < 256) ? sinf(arg) : cosf(arg);
    }
    #pragma unroll
    for (int b = 0; b < B_; ++b) {
        int tok = tokens[b * L_ + l];
        const float* em = embed + (size_t)tok * E_ + e0;
        f32x4 v0 = *(const f32x4*)em;
        f32x4 v1 = *(const f32x4*)(em + 4);
        #pragma unroll
        for (int j = 0; j < 4; ++j) { v0[j] += pe[j]; v1[j] += pe[4 + j]; }
        float* xo = x + ((size_t)(b * L_ + l)) * E_ + e0;
        *(f32x4*)xo = v0;
        *(f32x4*)(xo + 4) = v1;
    }
}

// ---------------------------------------------------------------------------
// LayerNorm: wave-per-row (4 rows per 256-thread block, no barriers).
// fp32 input, bf16 (OUTBF=1) or fp32 (OUTBF=0) output.
// ---------------------------------------------------------------------------
template<int OUTBF>
__global__ __launch_bounds__(256) void ln_kernel(const float* __restrict__ x,
                                                 const float* __restrict__ gamma,
                                                 const float* __restrict__ beta,
                                                 void* __restrict__ yout) {
    int t = threadIdx.x;
    int lane = t & 63;
    int row = blockIdx.x * 4 + (t >> 6);
    const float* xr = x + (size_t)row * E_ + lane * 8;
    f32x4 a0 = *(const f32x4*)xr;
    f32x4 a1 = *(const f32x4*)(xr + 4);
    float s = a0[0] + a0[1] + a0[2] + a0[3] + a1[0] + a1[1] + a1[2] + a1[3];
    #pragma unroll
    for (int off = 1; off < 64; off <<= 1) s += __shfl_xor(s, off, 64);
    float mu = s * (1.0f / E_);
    float q = 0.0f;
    #pragma unroll
    for (int j = 0; j < 4; ++j) { float d = a0[j] - mu; q += d * d; }
    #pragma unroll
    for (int j = 0; j < 4; ++j) { float d = a1[j] - mu; q += d * d; }
    #pragma unroll
    for (int off = 1; off < 64; off <<= 1) q += __shfl_xor(q, off, 64);
    float rstd = rsqrtf(q * (1.0f / E_) + 1e-6f);
    f32x4 g0 = *(const f32x4*)(gamma + lane * 8);
    f32x4 g1 = *(const f32x4*)(gamma + lane * 8 + 4);
    f32x4 b0 = *(const f32x4*)(beta + lane * 8);
    f32x4 b1 = *(const f32x4*)(beta + lane * 8 + 4);
    float o[8];
    #pragma unroll
    for (int j = 0; j < 4; ++j) o[j] = (a0[j] - mu) * rstd * g0[j] + b0[j];
    #pragma unroll
    for (int j = 0; j < 4; ++j) o[4 + j] = (a1[j] - mu) * rstd * g1[j] + b1[j];
    if (OUTBF) {
        bf16x8 pk;
        #pragma unroll
        for (int j = 0; j < 8; ++j) pk[j] = f2bf(o[j]);
        *(bf16x8*)((short*)yout + (size_t)row * E_ + lane * 8) = pk;
    } else {
        float* yr = (float*)yout + (size_t)row * E_ + lane * 8;
        *(f32x4*)yr = f32x4{o[0], o[1], o[2], o[3]};
        *(f32x4*)(yr + 4) = f32x4{o[4], o[5], o[6], o[7]};
    }
}

// ---------------------------------------------------------------------------
// Weight convert + transpose: Wt[n][k] = bf16(W[k][n] * scale), per layer (z)
// ---------------------------------------------------------------------------
__global__ __launch_bounds__(256) void convT_kernel(const float* __restrict__ W,
                                                    short* __restrict__ Wt,
                                                    int K, int N,
                                                    size_t wStride, size_t wtStride,
                                                    float scale) {
    __shared__ float Ts[64][65];
    const float* Wl = W + blockIdx.z * wStride;
    short* Wtl = Wt + blockIdx.z * wtStride;
    int n0 = blockIdx.x * 64, k0 = blockIdx.y * 64;
    int t = threadIdx.x;
    int c = t & 63, r0 = t >> 6;
    #pragma unroll
    for (int i = 0; i < 16; ++i) {
        int r = r0 * 16 + i;
        Ts[r][c] = Wl[(size_t)(k0 + r) * N + n0 + c] * scale;
    }
    __syncthreads();
    #pragma unroll
    for (int i = 0; i < 16; ++i) {
        int r = r0 * 16 + i;
        Wtl[(size_t)(n0 + r) * K + k0 + c] = f2bf(Ts[c][r]);
    }
}

// ---------------------------------------------------------------------------
// MFMA bf16 GEMM, 2-phase double-buffered (unchanged from round 6).
// ---------------------------------------------------------------------------
__device__ __forceinline__ float gelu_tanh(float x) {
    float u = x * (1.5957691216057308f + 0.07135480122394604f * x * x);
    return x / (1.0f + __expf(-u));
}

template<int BM, int BN, int WR, int WC, int ACT, int OUTBF>
__global__ __launch_bounds__(256) void mgemm_kernel(const short* __restrict__ A,
                                                    const short* __restrict__ Bt,
                                                    const float* __restrict__ bias,
                                                    const float* __restrict__ res,
                                                    void* __restrict__ Cout,
                                                    int M, int N, int K) {
    constexpr int FM = BM / WR / 16;
    constexpr int FN = BN / WC / 16;
    constexpr int ASZ = BM * 64;
    constexpr int BSZ = BN * 64;
    constexpr int PAD = 8;
    constexpr int CW = BN + PAD;
    static_assert((size_t)(OUTBF ? BM * CW * 2 : BM * CW * 4) <= (size_t)2 * (ASZ + BSZ) * 2,
                  "epilogue stage must fit in dbuf LDS");
    __shared__ __align__(16) short smem[2 * (ASZ + BSZ)];

    int t = threadIdx.x;
    int w = t >> 6, l = t & 63;
    int l15 = l & 15, lg = l >> 4;
    int wr = w / WC, wc = w % WC;
    int rowbase = wr * (BM / WR), colbase = wc * (BN / WC);
    int brow = blockIdx.y * BM, bcol = blockIdx.x * BN;
    int swz = ((l & 7) ^ (l >> 3)) * 8;
    int lrow = l >> 3;
    f32x4 acc[FM][FN] = {};

    const int nt = K >> 6;

    auto stage = [&](int buf, int k0) {
        short* Ad = smem + buf * ASZ;
        short* Bd = smem + 2 * ASZ + buf * BSZ;
        #pragma unroll
        for (int it = 0; it < BM / 32; ++it) {
            int row8 = (it * 4 + w) * 8;
            const short* ga = A + (size_t)(brow + row8 + lrow) * K + k0 + swz;
            __builtin_amdgcn_global_load_lds(
                (const __attribute__((address_space(1))) unsigned int*)ga,
                (__attribute__((address_space(3))) unsigned int*)(Ad + row8 * 64),
                16, 0, 0);
        }
        #pragma unroll
        for (int it = 0; it < BN / 32; ++it) {
            int row8 = (it * 4 + w) * 8;
            const short* gb = Bt + (size_t)(bcol + row8 + lrow) * K + k0 + swz;
            __builtin_amdgcn_global_load_lds(
                (const __attribute__((address_space(1))) unsigned int*)gb,
                (__attribute__((address_space(3))) unsigned int*)(Bd + row8 * 64),
                16, 0, 0);
        }
    };

    stage(0, 0);
    asm volatile("s_waitcnt vmcnt(0)" ::: "memory");
    __builtin_amdgcn_s_barrier();

    int cur = 0;
    for (int kt = 0; kt < nt; ++kt) {
        if (kt + 1 < nt) stage(cur ^ 1, (kt + 1) << 6);
        const short* Ar = smem + cur * ASZ;
        const short* Br = smem + 2 * ASZ + cur * BSZ;
        #pragma unroll
        for (int kk = 0; kk < 64; kk += 32) {
            bf16x8 af[FM], bfr[FN];
            #pragma unroll
            for (int m = 0; m < FM; ++m)
                af[m] = *(const bf16x8*)(Ar + (rowbase + m * 16 + l15) * 64
                                            + (((kk >> 3) + lg) ^ (l15 & 7)) * 8);
            #pragma unroll
            for (int n = 0; n < FN; ++n)
                bfr[n] = *(const bf16x8*)(Br + (colbase + n * 16 + l15) * 64
                                             + (((kk >> 3) + lg) ^ (l15 & 7)) * 8);
            #pragma unroll
            for (int m = 0; m < FM; ++m)
                #pragma unroll
                for (int n = 0; n < FN; ++n)
                    acc[m][n] = __builtin_amdgcn_mfma_f32_16x16x32_bf16(af[m], bfr[n], acc[m][n], 0, 0, 0);
        }
        asm volatile("s_waitcnt vmcnt(0) lgkmcnt(0)" ::: "memory");
        __builtin_amdgcn_s_barrier();
        cur ^= 1;
    }

    if (OUTBF) {
        short* Cs = smem;
        #pragma unroll
        for (int m = 0; m < FM; ++m) {
            int row = rowbase + m * 16 + lg * 4;
            #pragma unroll
            for (int n = 0; n < FN; ++n) {
                int col = colbase + n * 16 + l15;
                float bv = bias ? bias[bcol + col] : 0.0f;
                #pragma unroll
                for (int r = 0; r < 4; ++r) {
                    float vv = acc[m][n][r] + bv;
                    if (ACT == 1) vv = gelu_tanh(vv);
                    Cs[(row + r) * CW + col] = f2bf(vv);
                }
            }
        }
        __syncthreads();
        #pragma unroll
        for (int it = 0; it < BM * BN / 8 / 256; ++it) {
            int c = it * 256 + t;
            int row = c / (BN / 8), c8 = c % (BN / 8);
            *(bf16x8*)((short*)Cout + (size_t)(brow + row) * N + bcol + c8 * 8) =
                *(const bf16x8*)(Cs + row * CW + c8 * 8);
        }
    } else {
        float* Cs = (float*)smem;
        #pragma unroll
        for (int m = 0; m < FM; ++m) {
            int row = rowbase + m * 16 + lg * 4;
            #pragma unroll
            for (int n = 0; n < FN; ++n) {
                int col = colbase + n * 16 + l15;
                float bv = bias ? bias[bcol + col] : 0.0f;
                #pragma unroll
                for (int r = 0; r < 4; ++r)
                    Cs[(row + r) * CW + col] = acc[m][n][r] + bv;
            }
        }
        __syncthreads();
        #pragma unroll
        for (int it = 0; it < BM * BN / 4 / 256; ++it) {
            int c = it * 256 + t;
            int row = c / (BN / 4), c4 = c % (BN / 4);
            f32x4 vv = *(const f32x4*)(Cs + row * CW + c4 * 4);
            size_t gi = (size_t)(brow + row) * N + bcol + c4 * 4;
            if (res) vv += *(const f32x4*)(res + gi);
            *(f32x4*)((float*)Cout + gi) = vv;
        }
    }
}

// ---------------------------------------------------------------------------
// Sparse block attention, MFMA bf16, KVBLK=128 (two 64-key blocks per iter),
// chunked work items + flash-split, setprio around MFMA clusters.
// Odd tails: second block duplicated from first with padk=0 (masked out).
// ---------------------------------------------------------------------------
#define KSTR 72
#define VSTR 136

__global__ __launch_bounds__(256) void attn_kernel(const short* __restrict__ qkv,
                                                   const int* __restrict__ tokens,
                                                   short* __restrict__ o,
                                                   float* __restrict__ pacc,
                                                   float* __restrict__ pm,
                                                   float* __restrict__ pl,
                                                   int lyr) {
    __shared__ __align__(16) short Ks[128][KSTR];
    __shared__ __align__(16) short Vt[64][VSTR];      // Vt[d][key'] swizzled
    __shared__ __align__(16) short Pw[4][16][VSTR];   // per-wave P tile [q][128 keys]
    __shared__ int padk[128];
    __shared__ int padq[64];

    int item = blockIdx.x, h = blockIdx.y, b = blockIdx.z;
    int qb   = g_wt.itm_qb[lyr][item];
    int j0   = g_wt.itm_j0[lyr][item];
    int jn   = g_wt.itm_jn[lyr][item];
    int slot = g_wt.itm_slot[lyr][item];
    const unsigned char* jl = g_wt.jlist[lyr][qb];
    int npair = (jn + 1) >> 1;

    int t = threadIdx.x;
    int l = t & 63, w = t >> 6;
    int l15 = l & 15, lg = l >> 4;
    int srow = t >> 3, sdb = t & 7;

    if (t < 64) padq[t] = tokens[b * L_ + qb * 64 + t] > 0;

    int qrow = qb * 64 + w * 16 + l15;
    const short* qp = qkv + (size_t)(b * L_ + qrow) * 1536 + h * 64;
    bf16x8 qf0 = *(const bf16x8*)(qp + lg * 8);
    bf16x8 qf1 = *(const bf16x8*)(qp + lg * 8 + 32);

    f32x4 acc[4] = {};
    float m_r[4], l_r[4];
    #pragma unroll
    for (int r = 0; r < 4; ++r) { m_r[r] = -INFINITY; l_r[r] = 0.0f; }

    bf16x8 kr0, kr1, kr2, kr3, vr0, vr1, vr2, vr3;
    int pn = 0;
    auto LOAD = [&](int pi) {
        int jb1 = jl[j0 + 2 * pi];
        int jj2 = 2 * pi + 1;
        int jb2 = (jj2 < jn) ? jl[j0 + jj2] : jb1;    // sentinel: repeat jb1, masked
        const short* p1 = qkv + (size_t)(b * L_ + jb1 * 64 + srow) * 1536 + h * 64;
        const short* p2 = qkv + (size_t)(b * L_ + jb2 * 64 + srow) * 1536 + h * 64;
        kr0 = *(const bf16x8*)(p1 + 512 + sdb * 8);
        kr1 = *(const bf16x8*)(p1 + (size_t)32 * 1536 + 512 + sdb * 8);
        kr2 = *(const bf16x8*)(p2 + 512 + sdb * 8);
        kr3 = *(const bf16x8*)(p2 + (size_t)32 * 1536 + 512 + sdb * 8);
        vr0 = *(const bf16x8*)(p1 + 1024 + sdb * 8);
        vr1 = *(const bf16x8*)(p1 + (size_t)32 * 1536 + 1024 + sdb * 8);
        vr2 = *(const bf16x8*)(p2 + 1024 + sdb * 8);
        vr3 = *(const bf16x8*)(p2 + (size_t)32 * 1536 + 1024 + sdb * 8);
        pn = 0;
        if (t < 128) {
            int jj = 2 * pi + (t >> 6);
            if (jj < jn) pn = tokens[b * L_ + jl[j0 + jj] * 64 + (t & 63)];
        }
    };
    LOAD(0);

    for (int pi = 0; pi < npair; ++pi) {
        __syncthreads();   // previous iteration done reading LDS
        *(bf16x8*)&Ks[srow][sdb * 8]      = kr0;
        *(bf16x8*)&Ks[srow + 32][sdb * 8] = kr1;
        *(bf16x8*)&Ks[srow + 64][sdb * 8] = kr2;
        *(bf16x8*)&Ks[srow + 96][sdb * 8] = kr3;
        int c0 = srow >> 3;
        #pragma unroll
        for (int j = 0; j < 8; ++j) {
            int d = sdb * 8 + j;
            Vt[d][(srow & 7) + 8 * ((c0 ^ sdb))]             = vr0[j];
            Vt[d][(srow & 7) + 8 * (((c0 + 4) ^ sdb))]       = vr1[j];
            Vt[d][(srow & 7) + 8 * (8 | (c0 ^ sdb))]         = vr2[j];
            Vt[d][(srow & 7) + 8 * (8 | ((c0 + 4) ^ sdb))]   = vr3[j];
        }
        if (t < 128) padk[t] = pn > 0;
        __syncthreads();

        if (pi + 1 < npair) LOAD(pi + 1);

        // S = Q K^T over 128 keys: 8 col-fragments x 2 k-steps
        f32x4 sacc[8];
        __builtin_amdgcn_s_setprio(1);
        #pragma unroll
        for (int f = 0; f < 8; ++f) {
            bf16x8 kk0 = *(const bf16x8*)&Ks[16 * f + l15][lg * 8];
            bf16x8 kk1 = *(const bf16x8*)&Ks[16 * f + l15][lg * 8 + 32];
            f32x4 z = {};
            z = __builtin_amdgcn_mfma_f32_16x16x32_bf16(qf0, kk0, z, 0, 0, 0);
            z = __builtin_amdgcn_mfma_f32_16x16x32_bf16(qf1, kk1, z, 0, 0, 0);
            sacc[f] = z;
        }
        __builtin_amdgcn_s_setprio(0);

        int mc[8], mrow[4];
        #pragma unroll
        for (int f = 0; f < 8; ++f) mc[f] = padk[16 * f + l15];
        #pragma unroll
        for (int r = 0; r < 4; ++r) mrow[r] = padq[w * 16 + lg * 4 + r];

        float alpha[4];
        #pragma unroll
        for (int r = 0; r < 4; ++r) {
            float mx = -INFINITY;
            #pragma unroll
            for (int f = 0; f < 8; ++f)
                if (mc[f] && mrow[r]) mx = fmaxf(mx, sacc[f][r]);
            mx = fmaxf(mx, __shfl_xor(mx, 1, 64));
            mx = fmaxf(mx, __shfl_xor(mx, 2, 64));
            mx = fmaxf(mx, __shfl_xor(mx, 4, 64));
            mx = fmaxf(mx, __shfl_xor(mx, 8, 64));
            float nm = fmaxf(m_r[r], mx);
            float sum = 0.0f;
            #pragma unroll
            for (int f = 0; f < 8; ++f) {
                float p = (mc[f] && mrow[r]) ? __expf(sacc[f][r] - nm) : 0.0f;
                Pw[w][lg * 4 + r][16 * f + l15] = f2bf(p);
                sum += p;
            }
            sum += __shfl_xor(sum, 1, 64);
            sum += __shfl_xor(sum, 2, 64);
            sum += __shfl_xor(sum, 4, 64);
            sum += __shfl_xor(sum, 8, 64);
            float al = (nm == -INFINITY) ? 1.0f : __expf(m_r[r] - nm);
            m_r[r] = nm;
            l_r[r] = l_r[r] * al + sum;
            alpha[r] = al;
        }
        #pragma unroll
        for (int fd = 0; fd < 4; ++fd)
            #pragma unroll
            for (int r = 0; r < 4; ++r) acc[fd][r] *= alpha[r];

        // P (A-layout, same-wave LDS RAW) and PV over 128 keys
        bf16x8 pa[4];
        #pragma unroll
        for (int s = 0; s < 4; ++s)
            pa[s] = *(const bf16x8*)&Pw[w][l15][32 * s + lg * 8];
        __builtin_amdgcn_s_setprio(1);
        #pragma unroll
        for (int fd = 0; fd < 4; ++fd) {
            int d = 16 * fd + l15, sd = d >> 3;
            #pragma unroll
            for (int s = 0; s < 4; ++s) {
                int cb = 4 * s + lg;
                int cbp = (cb & 8) | ((cb & 7) ^ sd);
                bf16x8 vv = *(const bf16x8*)&Vt[d][8 * cbp];
                acc[fd] = __builtin_amdgcn_mfma_f32_16x16x32_bf16(pa[s], vv, acc[fd], 0, 0, 0);
            }
        }
        __builtin_amdgcn_s_setprio(0);
    }

    if (slot == 0xFF) {
        #pragma unroll
        for (int r = 0; r < 4; ++r) {
            int rw = lg * 4 + r;
            int gl = qb * 64 + w * 16 + rw;
            size_t ob = (size_t)(b * L_ + gl) * 512 + h * 64 + l15;
            bool ok = (padq[w * 16 + rw] != 0) && (l_r[r] > 0.0f);
            if (ok) {
                float inv = 1.0f / l_r[r];
                #pragma unroll
                for (int fd = 0; fd < 4; ++fd) o[ob + 16 * fd] = f2bf(acc[fd][r] * inv);
            } else {
                #pragma unroll
                for (int fd = 0; fd < 4; ++fd) {
                    float s = 0.0f;
                    for (int m = 0; m < L_; ++m)
                        s += bf2f(qkv[(size_t)(b * L_ + m) * 1536 + 1024 + h * 64 + 16 * fd + l15]);
                    o[ob + 16 * fd] = f2bf(s * (1.0f / L_));
                }
            }
        }
    } else {
        size_t pb = ((size_t)slot * B_ + b) * H_ + h;
        #pragma unroll
        for (int r = 0; r < 4; ++r) {
            int rloc = w * 16 + lg * 4 + r;
            #pragma unroll
            for (int fd = 0; fd < 4; ++fd)
                pacc[pb * 4096 + (size_t)rloc * 64 + 16 * fd + l15] = acc[fd][r];
            if (l15 == 0) {
                pm[pb * 64 + rloc] = m_r[r];
                pl[pb * 64 + rloc] = l_r[r];
            }
        }
    }
}

// ---------------------------------------------------------------------------
// Combine partial flash results for split q-blocks.
// ---------------------------------------------------------------------------
__global__ __launch_bounds__(256) void attn_combine(const short* __restrict__ qkv,
                                                    const int* __restrict__ tokens,
                                                    short* __restrict__ o,
                                                    const float* __restrict__ pacc,
                                                    const float* __restrict__ pm,
                                                    const float* __restrict__ pl,
                                                    int lyr) {
    int ci = blockIdx.x, h = blockIdx.y, b = blockIdx.z;
    int qb  = g_wt.cmb_qb[lyr][ci];
    int s0  = g_wt.cmb_slot0[lyr][ci];
    int nch = g_wt.cmb_nch[lyr][ci];
    int t = threadIdx.x;
    int r = t >> 2, dq = t & 3;
    int grow = qb * 64 + r;
    bool pq = tokens[b * L_ + grow] > 0;
    float M = -INFINITY;
    for (int c = 0; c < nch; ++c)
        M = fmaxf(M, pm[(((size_t)(s0 + c) * B_ + b) * H_ + h) * 64 + r]);
    size_t ob = (size_t)(b * L_ + grow) * 512 + h * 64 + dq * 16;
    if (pq && M > -1e30f) {
        float lsum = 0.0f;
        float accd[16] = {};
        for (int c = 0; c < nch; ++c) {
            size_t pb = ((size_t)(s0 + c) * B_ + b) * H_ + h;
            float wgt = __expf(pm[pb * 64 + r] - M);
            lsum += pl[pb * 64 + r] * wgt;
            const float* pa = pacc + pb * 4096 + (size_t)r * 64 + dq * 16;
            #pragma unroll
            for (int j = 0; j < 16; ++j) accd[j] += pa[j] * wgt;
        }
        float inv = 1.0f / lsum;
        #pragma unroll
        for (int j = 0; j < 16; ++j) o[ob + j] = f2bf(accd[j] * inv);
    } else {
        #pragma unroll
        for (int j = 0; j < 16; ++j) {
            float s = 0.0f;
            for (int m = 0; m < L_; ++m)
                s += bf2f(qkv[(size_t)(b * L_ + m) * 1536 + 1024 + h * 64 + dq * 16 + j]);
            o[ob + j] = f2bf(s * (1.0f / L_));
        }
    }
}

// ---------------------------------------------------------------------------
// Launch
// ---------------------------------------------------------------------------
extern "C" void kernel_launch(void* const* d_in, const int* in_sizes, int n_in,
                              void* d_out, int out_size, void* d_ws, size_t ws_size,
                              hipStream_t stream) {
    (void)in_sizes; (void)n_in; (void)out_size; (void)ws_size;
    const int*   tokens = (const int*)d_in[0];
    const float* embed  = (const float*)d_in[1];
    const float* ln1_s  = (const float*)d_in[2];
    const float* ln1_b  = (const float*)d_in[3];
    const float* wq     = (const float*)d_in[4];
    const float* wk     = (const float*)d_in[5];
    const float* wv     = (const float*)d_in[6];
    const float* wo     = (const float*)d_in[7];
    const float* ln2_s  = (const float*)d_in[8];
    const float* ln2_b  = (const float*)d_in[9];
    const float* w1     = (const float*)d_in[10];
    const float* b1     = (const float*)d_in[11];
    const float* w2     = (const float*)d_in[12];
    const float* b2     = (const float*)d_in[13];
    const float* lnf_s  = (const float*)d_in[14];
    const float* lnf_b  = (const float*)d_in[15];
    float* out = (float*)d_out;

    const size_t BLE = (size_t)B_ * L_ * E_;              // 4,194,304
    char* ws = (char*)d_ws;
    float* x    = (float*)ws;                             // 16 MB
    short* yb   = (short*)(x + BLE);                      //  8 MB
    short* R    = yb + BLE;                               // 32 MB (qkv+ob / hb)
    short* qkv  = R;
    short* ob   = R + 3 * BLE;
    short* hb   = R;
    short* qkvt = R + 4 * BLE;                            // bf16 weights
    short* wot  = qkvt + (size_t)NL_ * 1536 * 512;
    short* w1t  = wot + (size_t)NL_ * 512 * 512;
    short* w2t  = w1t + (size_t)NL_ * 2048 * 512;
    float* pacc = (float*)(w2t + (size_t)NL_ * 512 * 2048);   // 8 slots x B x H x 4096 f32
    float* pm   = pacc + (size_t)8 * B_ * H_ * 4096;
    float* pl   = pm + (size_t)8 * B_ * H_ * 64;

    convT_kernel<<<dim3(8, 8, NL_), 256, 0, stream>>>(wq, qkvt,          512, 512, 262144, 786432, 0.125f);
    convT_kernel<<<dim3(8, 8, NL_), 256, 0, stream>>>(wk, qkvt + 262144, 512, 512, 262144, 786432, 1.0f);
    convT_kernel<<<dim3(8, 8, NL_), 256, 0, stream>>>(wv, qkvt + 524288, 512, 512, 262144, 786432, 1.0f);
    convT_kernel<<<dim3(8, 8, NL_), 256, 0, stream>>>(wo, wot,           512, 512, 262144, 262144, 1.0f);
    convT_kernel<<<dim3(32, 8, NL_), 256, 0, stream>>>(w1, w1t,          512, 2048, 1048576, 1048576, 1.0f);
    convT_kernel<<<dim3(8, 32, NL_), 256, 0, stream>>>(w2, w2t,          2048, 512, 1048576, 1048576, 1.0f);

    embed_kernel<<<(L_ * E_ / 8) / 256, 256, 0, stream>>>(tokens, embed, x);

    const int MR = B_ * L_;
    const int LNG = MR / 4;                                // 2048 blocks
    for (int lyr = 0; lyr < NL_; ++lyr) {
        ln_kernel<1><<<LNG, 256, 0, stream>>>(x, ln1_s + lyr * E_, ln1_b + lyr * E_, yb);
        mgemm_kernel<128, 128, 2, 2, 0, 1><<<dim3(12, 64), 256, 0, stream>>>(
            yb, qkvt + (size_t)lyr * 786432, nullptr, nullptr, qkv, MR, 1536, 512);
        attn_kernel<<<dim3(WT_HOST.n_items[lyr], H_, B_), 256, 0, stream>>>(
            qkv, tokens, ob, pacc, pm, pl, lyr);
        attn_combine<<<dim3(WT_HOST.n_cmb[lyr], H_, B_), 256, 0, stream>>>(
            qkv, tokens, ob, pacc, pm, pl, lyr);
        mgemm_kernel<64, 128, 2, 2, 0, 0><<<dim3(4, 128), 256, 0, stream>>>(
            ob, wot + (size_t)lyr * 262144, nullptr, x, x, MR, 512, 512);
        ln_kernel<1><<<LNG, 256, 0, stream>>>(x, ln2_s + lyr * E_, ln2_b + lyr * E_, yb);
        mgemm_kernel<128, 128, 2, 2, 1, 1><<<dim3(16, 64), 256, 0, stream>>>(
            yb, w1t + (size_t)lyr * 1048576, b1 + (size_t)lyr * M_, nullptr, hb, MR, 2048, 512);
        mgemm_kernel<64, 128, 2, 2, 0, 0><<<dim3(4, 128), 256, 0, stream>>>(
            hb, w2t + (size_t)lyr * 1048576, b2 + (size_t)lyr * E_, x, x, MR, 512, 2048);
    }
    ln_kernel<0><<<LNG, 256, 0, stream>>>(x, lnf_s, lnf_b, out);
}

// Round 8
// 684.912 us; speedup vs baseline: 21.1794x; 1.0896x over previous
//
#include <hip/hip_runtime.h>
#include <hip/hip_bf16.h>
#include <cmath>
#include <cstdint>
#include <cstddef>

#define B_   4
#define L_   2048
#define E_   512
#define H_   8
#define DH_  64
#define M_   2048
#define NL_  4
#define NB_  32
#define BS_  64
#define CH_  12   // max 64-key jb-blocks per attention work item

typedef short bf16x8 __attribute__((ext_vector_type(8)));
typedef short bf16x4 __attribute__((ext_vector_type(4)));
typedef float f32x4 __attribute__((ext_vector_type(4)));

__device__ __forceinline__ short f2bf(float f) {
    union { __hip_bfloat16 h; short s; } u;
    u.h = __float2bfloat16(f);
    return u.s;
}
__device__ __forceinline__ float bf2f(short s) {
    union { short s; __hip_bfloat16 h; } u;
    u.s = s;
    return __bfloat162float(u.h);
}

// ---------------------------------------------------------------------------
// BigBird masks + work partition, all at COMPILE TIME.
// ---------------------------------------------------------------------------
struct MaskTable { unsigned m[NL_][NB_]; };
struct CxMT { unsigned key[624]; int pos; };

constexpr unsigned cx_next(CxMT& st) {
    if (st.pos >= 624) {
        for (int i = 0; i < 624; ++i) {
            unsigned y = (st.key[i] & 0x80000000u) | (st.key[(i + 1) % 624] & 0x7fffffffu);
            st.key[i] = st.key[(i + 397) % 624] ^ (y >> 1) ^ ((y & 1u) ? 0x9908b0dfu : 0u);
        }
        st.pos = 0;
    }
    unsigned y = st.key[st.pos++];
    y ^= y >> 11;
    y ^= (y << 7) & 0x9d2c5680u;
    y ^= (y << 15) & 0xefc60000u;
    y ^= y >> 18;
    return y;
}
constexpr unsigned cx_interval(CxMT& st, unsigned maxv) {
    if (maxv == 0u) return 0u;
    unsigned mask = maxv;
    mask |= mask >> 1; mask |= mask >> 2; mask |= mask >> 4;
    mask |= mask >> 8; mask |= mask >> 16;
    unsigned v = cx_next(st) & mask;
    while (v > maxv) v = cx_next(st) & mask;
    return v;
}
constexpr MaskTable compute_masks() {
    MaskTable T{};
    for (int lyr = 0; lyr < NL_; ++lyr) {
        unsigned m[NB_] = {};
        for (int i = 0; i < NB_; ++i) {
            unsigned w = 1u << i;
            if (i > 0) w |= 1u << (i - 1);
            if (i < NB_ - 1) w |= 1u << (i + 1);
            w |= 1u | (1u << (NB_ - 1));
            m[i] = w;
        }
        m[0] = 0xffffffffu;
        m[NB_ - 1] = 0xffffffffu;
        CxMT st{};
        unsigned s = (unsigned)lyr;
        for (int i = 0; i < 624; ++i) {
            st.key[i] = s;
            s = 1812433253u * (s ^ (s >> 30)) + (unsigned)i + 1u;
        }
        st.pos = 624;
        for (int i = 1; i < NB_ - 1; ++i) {
            int cand[NB_] = {};
            int n = 0;
            for (int j = 0; j < NB_; ++j) {
                if (j == 0 || j == NB_ - 1 || j == i - 1 || j == i || j == i + 1) continue;
                cand[n++] = j;
            }
            for (int kk = n - 1; kk >= 1; --kk) {
                int jj = (int)cx_interval(st, (unsigned)kk);
                int tmp = cand[kk]; cand[kk] = cand[jj]; cand[jj] = tmp;
            }
            m[i] |= (1u << cand[0]) | (1u << cand[1]) | (1u << cand[2]);
        }
        for (int i = 0; i < NB_; ++i) T.m[lyr][i] = m[i];
    }
    return T;
}

struct WorkTable {
    int n_items[NL_];
    int n_cmb[NL_];
    unsigned char itm_qb[NL_][40];
    unsigned char itm_j0[NL_][40];
    unsigned char itm_jn[NL_][40];
    unsigned char itm_slot[NL_][40];   // 0xFF = direct write to o
    unsigned char cmb_qb[NL_][8];
    unsigned char cmb_slot0[NL_][8];
    unsigned char cmb_nch[NL_][8];
    unsigned char jlist[NL_][NB_][NB_];
};

constexpr WorkTable compute_work() {
    WorkTable T{};
    MaskTable M = compute_masks();
    for (int lyr = 0; lyr < NL_; ++lyr) {
        int items = 0, slots = 0, ncmb = 0;
        for (int qb = 0; qb < NB_; ++qb) {
            int cnt = 0;
            for (int j = 0; j < NB_; ++j)
                if ((M.m[lyr][qb] >> j) & 1u)
                    T.jlist[lyr][qb][cnt++] = (unsigned char)j;
            int nch = (cnt + CH_ - 1) / CH_;
            if (nch == 1) {
                T.itm_qb[lyr][items] = (unsigned char)qb;
                T.itm_j0[lyr][items] = 0;
                T.itm_jn[lyr][items] = (unsigned char)cnt;
                T.itm_slot[lyr][items] = 0xFF;
                items++;
            } else {
                T.cmb_qb[lyr][ncmb] = (unsigned char)qb;
                T.cmb_slot0[lyr][ncmb] = (unsigned char)slots;
                T.cmb_nch[lyr][ncmb] = (unsigned char)nch;
                ncmb++;
                int base = cnt / nch, rem = cnt % nch, off = 0;
                for (int c = 0; c < nch; ++c) {
                    int cl = base + (c < rem ? 1 : 0);
                    T.itm_qb[lyr][items] = (unsigned char)qb;
                    T.itm_j0[lyr][items] = (unsigned char)off;
                    T.itm_jn[lyr][items] = (unsigned char)cl;
                    T.itm_slot[lyr][items] = (unsigned char)slots;
                    items++; slots++; off += cl;
                }
            }
        }
        T.n_items[lyr] = items;
        T.n_cmb[lyr] = ncmb;
    }
    return T;
}

static constexpr WorkTable WT_HOST = compute_work();
__constant__ WorkTable g_wt = compute_work();

// ---------------------------------------------------------------------------
// Embedding + sinusoidal PE (PE reused across the 4 batches)
// ---------------------------------------------------------------------------
__global__ __launch_bounds__(256) void embed_kernel(const int* __restrict__ tokens,
                                                    const float* __restrict__ embed,
                                                    float* __restrict__ x) {
    int idx = blockIdx.x * 256 + threadIdx.x;      // < L_*E_/8 = 131072
    int l = idx >> 6;
    int e0 = (idx & 63) * 8;
    float pe[8];
    #pragma unroll
    for (int j = 0; j < 8; ++j) {
        int e = e0 + j;
        int jj = e & 255;
        float div = expf((float)jj * -0.03597789207717895f);  // -ln(10000)/256
        float arg = (float)l * div;
        pe[j] = (e < 256) ? sinf(arg) : cosf(arg);
    }
    #pragma unroll
    for (int b = 0; b < B_; ++b) {
        int tok = tokens[b * L_ + l];
        const float* em = embed + (size_t)tok * E_ + e0;
        f32x4 v0 = *(const f32x4*)em;
        f32x4 v1 = *(const f32x4*)(em + 4);
        #pragma unroll
        for (int j = 0; j < 4; ++j) { v0[j] += pe[j]; v1[j] += pe[4 + j]; }
        float* xo = x + ((size_t)(b * L_ + l)) * E_ + e0;
        *(f32x4*)xo = v0;
        *(f32x4*)(xo + 4) = v1;
    }
}

// ---------------------------------------------------------------------------
// LayerNorm: wave-per-row (4 rows per 256-thread block, no barriers).
// ---------------------------------------------------------------------------
template<int OUTBF>
__global__ __launch_bounds__(256) void ln_kernel(const float* __restrict__ x,
                                                 const float* __restrict__ gamma,
                                                 const float* __restrict__ beta,
                                                 void* __restrict__ yout) {
    int t = threadIdx.x;
    int lane = t & 63;
    int row = blockIdx.x * 4 + (t >> 6);
    const float* xr = x + (size_t)row * E_ + lane * 8;
    f32x4 a0 = *(const f32x4*)xr;
    f32x4 a1 = *(const f32x4*)(xr + 4);
    float s = a0[0] + a0[1] + a0[2] + a0[3] + a1[0] + a1[1] + a1[2] + a1[3];
    #pragma unroll
    for (int off = 1; off < 64; off <<= 1) s += __shfl_xor(s, off, 64);
    float mu = s * (1.0f / E_);
    float q = 0.0f;
    #pragma unroll
    for (int j = 0; j < 4; ++j) { float d = a0[j] - mu; q += d * d; }
    #pragma unroll
    for (int j = 0; j < 4; ++j) { float d = a1[j] - mu; q += d * d; }
    #pragma unroll
    for (int off = 1; off < 64; off <<= 1) q += __shfl_xor(q, off, 64);
    float rstd = rsqrtf(q * (1.0f / E_) + 1e-6f);
    f32x4 g0 = *(const f32x4*)(gamma + lane * 8);
    f32x4 g1 = *(const f32x4*)(gamma + lane * 8 + 4);
    f32x4 b0 = *(const f32x4*)(beta + lane * 8);
    f32x4 b1 = *(const f32x4*)(beta + lane * 8 + 4);
    float o[8];
    #pragma unroll
    for (int j = 0; j < 4; ++j) o[j] = (a0[j] - mu) * rstd * g0[j] + b0[j];
    #pragma unroll
    for (int j = 0; j < 4; ++j) o[4 + j] = (a1[j] - mu) * rstd * g1[j] + b1[j];
    if (OUTBF) {
        bf16x8 pk;
        #pragma unroll
        for (int j = 0; j < 8; ++j) pk[j] = f2bf(o[j]);
        *(bf16x8*)((short*)yout + (size_t)row * E_ + lane * 8) = pk;
    } else {
        float* yr = (float*)yout + (size_t)row * E_ + lane * 8;
        *(f32x4*)yr = f32x4{o[0], o[1], o[2], o[3]};
        *(f32x4*)(yr + 4) = f32x4{o[4], o[5], o[6], o[7]};
    }
}

// ---------------------------------------------------------------------------
// Weight convert + transpose: Wt[n][k] = bf16(W[k][n] * scale), per layer (z)
// ---------------------------------------------------------------------------
__global__ __launch_bounds__(256) void convT_kernel(const float* __restrict__ W,
                                                    short* __restrict__ Wt,
                                                    int K, int N,
                                                    size_t wStride, size_t wtStride,
                                                    float scale) {
    __shared__ float Ts[64][65];
    const float* Wl = W + blockIdx.z * wStride;
    short* Wtl = Wt + blockIdx.z * wtStride;
    int n0 = blockIdx.x * 64, k0 = blockIdx.y * 64;
    int t = threadIdx.x;
    int c = t & 63, r0 = t >> 6;
    #pragma unroll
    for (int i = 0; i < 16; ++i) {
        int r = r0 * 16 + i;
        Ts[r][c] = Wl[(size_t)(k0 + r) * N + n0 + c] * scale;
    }
    __syncthreads();
    #pragma unroll
    for (int i = 0; i < 16; ++i) {
        int r = r0 * 16 + i;
        Wtl[(size_t)(n0 + r) * K + k0 + c] = f2bf(Ts[c][r]);
    }
}

// ---------------------------------------------------------------------------
// MFMA bf16 GEMM, 2-phase double-buffered (unchanged from round 6).
// ---------------------------------------------------------------------------
__device__ __forceinline__ float gelu_tanh(float x) {
    float u = x * (1.5957691216057308f + 0.07135480122394604f * x * x);
    return x / (1.0f + __expf(-u));
}

template<int BM, int BN, int WR, int WC, int ACT, int OUTBF>
__global__ __launch_bounds__(256) void mgemm_kernel(const short* __restrict__ A,
                                                    const short* __restrict__ Bt,
                                                    const float* __restrict__ bias,
                                                    const float* __restrict__ res,
                                                    void* __restrict__ Cout,
                                                    int M, int N, int K) {
    constexpr int FM = BM / WR / 16;
    constexpr int FN = BN / WC / 16;
    constexpr int ASZ = BM * 64;
    constexpr int BSZ = BN * 64;
    constexpr int PAD = 8;
    constexpr int CW = BN + PAD;
    static_assert((size_t)(OUTBF ? BM * CW * 2 : BM * CW * 4) <= (size_t)2 * (ASZ + BSZ) * 2,
                  "epilogue stage must fit in dbuf LDS");
    __shared__ __align__(16) short smem[2 * (ASZ + BSZ)];

    int t = threadIdx.x;
    int w = t >> 6, l = t & 63;
    int l15 = l & 15, lg = l >> 4;
    int wr = w / WC, wc = w % WC;
    int rowbase = wr * (BM / WR), colbase = wc * (BN / WC);
    int brow = blockIdx.y * BM, bcol = blockIdx.x * BN;
    int swz = ((l & 7) ^ (l >> 3)) * 8;
    int lrow = l >> 3;
    f32x4 acc[FM][FN] = {};

    const int nt = K >> 6;

    auto stage = [&](int buf, int k0) {
        short* Ad = smem + buf * ASZ;
        short* Bd = smem + 2 * ASZ + buf * BSZ;
        #pragma unroll
        for (int it = 0; it < BM / 32; ++it) {
            int row8 = (it * 4 + w) * 8;
            const short* ga = A + (size_t)(brow + row8 + lrow) * K + k0 + swz;
            __builtin_amdgcn_global_load_lds(
                (const __attribute__((address_space(1))) unsigned int*)ga,
                (__attribute__((address_space(3))) unsigned int*)(Ad + row8 * 64),
                16, 0, 0);
        }
        #pragma unroll
        for (int it = 0; it < BN / 32; ++it) {
            int row8 = (it * 4 + w) * 8;
            const short* gb = Bt + (size_t)(bcol + row8 + lrow) * K + k0 + swz;
            __builtin_amdgcn_global_load_lds(
                (const __attribute__((address_space(1))) unsigned int*)gb,
                (__attribute__((address_space(3))) unsigned int*)(Bd + row8 * 64),
                16, 0, 0);
        }
    };

    stage(0, 0);
    asm volatile("s_waitcnt vmcnt(0)" ::: "memory");
    __builtin_amdgcn_s_barrier();

    int cur = 0;
    for (int kt = 0; kt < nt; ++kt) {
        if (kt + 1 < nt) stage(cur ^ 1, (kt + 1) << 6);
        const short* Ar = smem + cur * ASZ;
        const short* Br = smem + 2 * ASZ + cur * BSZ;
        #pragma unroll
        for (int kk = 0; kk < 64; kk += 32) {
            bf16x8 af[FM], bfr[FN];
            #pragma unroll
            for (int m = 0; m < FM; ++m)
                af[m] = *(const bf16x8*)(Ar + (rowbase + m * 16 + l15) * 64
                                            + (((kk >> 3) + lg) ^ (l15 & 7)) * 8);
            #pragma unroll
            for (int n = 0; n < FN; ++n)
                bfr[n] = *(const bf16x8*)(Br + (colbase + n * 16 + l15) * 64
                                             + (((kk >> 3) + lg) ^ (l15 & 7)) * 8);
            #pragma unroll
            for (int m = 0; m < FM; ++m)
                #pragma unroll
                for (int n = 0; n < FN; ++n)
                    acc[m][n] = __builtin_amdgcn_mfma_f32_16x16x32_bf16(af[m], bfr[n], acc[m][n], 0, 0, 0);
        }
        asm volatile("s_waitcnt vmcnt(0) lgkmcnt(0)" ::: "memory");
        __builtin_amdgcn_s_barrier();
        cur ^= 1;
    }

    if (OUTBF) {
        short* Cs = smem;
        #pragma unroll
        for (int m = 0; m < FM; ++m) {
            int row = rowbase + m * 16 + lg * 4;
            #pragma unroll
            for (int n = 0; n < FN; ++n) {
                int col = colbase + n * 16 + l15;
                float bv = bias ? bias[bcol + col] : 0.0f;
                #pragma unroll
                for (int r = 0; r < 4; ++r) {
                    float vv = acc[m][n][r] + bv;
                    if (ACT == 1) vv = gelu_tanh(vv);
                    Cs[(row + r) * CW + col] = f2bf(vv);
                }
            }
        }
        __syncthreads();
        #pragma unroll
        for (int it = 0; it < BM * BN / 8 / 256; ++it) {
            int c = it * 256 + t;
            int row = c / (BN / 8), c8 = c % (BN / 8);
            *(bf16x8*)((short*)Cout + (size_t)(brow + row) * N + bcol + c8 * 8) =
                *(const bf16x8*)(Cs + row * CW + c8 * 8);
        }
    } else {
        float* Cs = (float*)smem;
        #pragma unroll
        for (int m = 0; m < FM; ++m) {
            int row = rowbase + m * 16 + lg * 4;
            #pragma unroll
            for (int n = 0; n < FN; ++n) {
                int col = colbase + n * 16 + l15;
                float bv = bias ? bias[bcol + col] : 0.0f;
                #pragma unroll
                for (int r = 0; r < 4; ++r)
                    Cs[(row + r) * CW + col] = acc[m][n][r] + bv;
            }
        }
        __syncthreads();
        #pragma unroll
        for (int it = 0; it < BM * BN / 4 / 256; ++it) {
            int c = it * 256 + t;
            int row = c / (BN / 4), c4 = c % (BN / 4);
            f32x4 vv = *(const f32x4*)(Cs + row * CW + c4 * 4);
            size_t gi = (size_t)(brow + row) * N + bcol + c4 * 4;
            if (res) vv += *(const f32x4*)(res + gi);
            *(f32x4*)((float*)Cout + gi) = vv;
        }
    }
}

// ---------------------------------------------------------------------------
// Sparse block attention, MFMA bf16, KVBLK=64, SWAPPED QK^T:
//   sacc = mfma(K, Q) -> lane (lg,l15) holds S[key=16f+4lg+r][qrow=l15].
//   Row-softmax: 15 in-register fmax + 2 shfl_xor (16,32). State (m,l) is one
//   scalar per lane; alpha/l redistributed to D-layout rows via 4 shfl.
//   padq/padk as __ballot bitmasks. P written packed (ds_write_b64).
// ---------------------------------------------------------------------------
#define KSTR 72

__global__ __launch_bounds__(256) void attn_kernel(const short* __restrict__ qkv,
                                                   const int* __restrict__ tokens,
                                                   short* __restrict__ o,
                                                   float* __restrict__ pacc,
                                                   float* __restrict__ pm,
                                                   float* __restrict__ pl,
                                                   int lyr) {
    __shared__ __align__(16) short Ks[64][KSTR];
    __shared__ __align__(16) short Vt[64][KSTR];
    __shared__ __align__(16) short Pw[4][16][KSTR];
    __shared__ unsigned long long qbits_s;
    __shared__ unsigned long long kbits_s;

    int item = blockIdx.x, h = blockIdx.y, b = blockIdx.z;
    int qb   = g_wt.itm_qb[lyr][item];
    int j0   = g_wt.itm_j0[lyr][item];
    int jn   = g_wt.itm_jn[lyr][item];
    int slot = g_wt.itm_slot[lyr][item];
    const unsigned char* jl = g_wt.jlist[lyr][qb];

    int t = threadIdx.x;
    int l = t & 63, w = t >> 6;
    int l15 = l & 15, lg = l >> 4;
    int srow = t >> 3, sdb = t & 7;

    if (t < 64) {
        unsigned long long qm = __ballot(tokens[b * L_ + qb * 64 + t] > 0);
        if (t == 0) qbits_s = qm;
    }

    int qrow = qb * 64 + w * 16 + l15;
    const short* qp = qkv + (size_t)(b * L_ + qrow) * 1536 + h * 64;
    bf16x8 qf0 = *(const bf16x8*)(qp + lg * 8);
    bf16x8 qf1 = *(const bf16x8*)(qp + lg * 8 + 32);

    f32x4 acc[4] = {};
    float m_r = -INFINITY, l_r = 0.0f;

    bf16x8 kr0, kr1, vr0, vr1;
    int pn = 0;
    auto LOAD = [&](int ci) {
        int jb = jl[j0 + ci];
        const short* base = qkv + (size_t)(b * L_ + jb * 64 + srow) * 1536 + h * 64;
        kr0 = *(const bf16x8*)(base + 512 + sdb * 8);
        kr1 = *(const bf16x8*)(base + (size_t)32 * 1536 + 512 + sdb * 8);
        vr0 = *(const bf16x8*)(base + 1024 + sdb * 8);
        vr1 = *(const bf16x8*)(base + (size_t)32 * 1536 + 1024 + sdb * 8);
        if (t < 64) pn = tokens[b * L_ + jb * 64 + t];
    };
    LOAD(0);

    for (int ci = 0; ci < jn; ++ci) {
        __syncthreads();   // previous iteration done reading LDS
        *(bf16x8*)&Ks[srow][sdb * 8] = kr0;
        *(bf16x8*)&Ks[srow + 32][sdb * 8] = kr1;
        #pragma unroll
        for (int j = 0; j < 8; ++j) {
            Vt[sdb * 8 + j][(srow & 7) + 8 * ((srow >> 3) ^ sdb)] = vr0[j];
            Vt[sdb * 8 + j][(srow & 7) + 8 * (((srow >> 3) + 4) ^ sdb)] = vr1[j];
        }
        if (t < 64) {
            unsigned long long km = __ballot(pn > 0);
            if (t == 0) kbits_s = km;
        }
        __syncthreads();

        if (ci + 1 < jn) LOAD(ci + 1);

        // S^T = K Q^T (swapped operands; same fragment reads as before)
        f32x4 sacc[4];
        __builtin_amdgcn_s_setprio(1);
        #pragma unroll
        for (int f = 0; f < 4; ++f) {
            bf16x8 kk0 = *(const bf16x8*)&Ks[16 * f + l15][lg * 8];
            bf16x8 kk1 = *(const bf16x8*)&Ks[16 * f + l15][lg * 8 + 32];
            f32x4 z = {};
            z = __builtin_amdgcn_mfma_f32_16x16x32_bf16(kk0, qf0, z, 0, 0, 0);
            z = __builtin_amdgcn_mfma_f32_16x16x32_bf16(kk1, qf1, z, 0, 0, 0);
            sacc[f] = z;
        }
        __builtin_amdgcn_s_setprio(0);

        unsigned long long kb = kbits_s;
        bool pq = (qbits_s >> (w * 16 + l15)) & 1ull;
        unsigned vm = 0;
        #pragma unroll
        for (int f = 0; f < 4; ++f)
            vm |= ((unsigned)(kb >> (16 * f + 4 * lg)) & 0xFu) << (4 * f);
        if (!pq) vm = 0;

        float mx = -INFINITY;
        #pragma unroll
        for (int f = 0; f < 4; ++f)
            #pragma unroll
            for (int r = 0; r < 4; ++r)
                if ((vm >> (4 * f + r)) & 1u) mx = fmaxf(mx, sacc[f][r]);
        mx = fmaxf(mx, __shfl_xor(mx, 16, 64));
        mx = fmaxf(mx, __shfl_xor(mx, 32, 64));
        float nm = fmaxf(m_r, mx);

        float pv[16];
        float sum = 0.0f;
        #pragma unroll
        for (int f = 0; f < 4; ++f)
            #pragma unroll
            for (int r = 0; r < 4; ++r) {
                float p = ((vm >> (4 * f + r)) & 1u) ? __expf(sacc[f][r] - nm) : 0.0f;
                pv[4 * f + r] = p;
                sum += p;
            }
        sum += __shfl_xor(sum, 16, 64);
        sum += __shfl_xor(sum, 32, 64);
        float al = (nm == -INFINITY) ? 1.0f : __expf(m_r - nm);
        m_r = nm;
        l_r = l_r * al + sum;

        // P -> LDS (packed 4x bf16 = 8B per write), same-wave RAW
        #pragma unroll
        for (int f = 0; f < 4; ++f) {
            bf16x4 pk;
            #pragma unroll
            for (int r = 0; r < 4; ++r) pk[r] = f2bf(pv[4 * f + r]);
            *(bf16x4*)&Pw[w][l15][16 * f + 4 * lg] = pk;
        }

        // alpha to D-layout rows (qrow = lg*4+r)
        float alr[4];
        #pragma unroll
        for (int r = 0; r < 4; ++r) alr[r] = __shfl(al, lg * 4 + r, 64);
        #pragma unroll
        for (int fd = 0; fd < 4; ++fd)
            #pragma unroll
            for (int r = 0; r < 4; ++r) acc[fd][r] *= alr[r];

        bf16x8 pa0 = *(const bf16x8*)&Pw[w][l15][lg * 8];
        bf16x8 pa1 = *(const bf16x8*)&Pw[w][l15][lg * 8 + 32];
        __builtin_amdgcn_s_setprio(1);
        #pragma unroll
        for (int fd = 0; fd < 4; ++fd) {
            int dd = 16 * fd + l15;
            bf16x8 vv0 = *(const bf16x8*)&Vt[dd][8 * (lg ^ (dd >> 3))];
            bf16x8 vv1 = *(const bf16x8*)&Vt[dd][8 * ((4 + lg) ^ (dd >> 3))];
            acc[fd] = __builtin_amdgcn_mfma_f32_16x16x32_bf16(pa0, vv0, acc[fd], 0, 0, 0);
            acc[fd] = __builtin_amdgcn_mfma_f32_16x16x32_bf16(pa1, vv1, acc[fd], 0, 0, 0);
        }
        __builtin_amdgcn_s_setprio(0);
    }

    // redistribute (m,l) from per-l15 lanes to D-layout rows
    float lrr[4], mrr[4];
    #pragma unroll
    for (int r = 0; r < 4; ++r) {
        lrr[r] = __shfl(l_r, lg * 4 + r, 64);
        mrr[r] = __shfl(m_r, lg * 4 + r, 64);
    }
    unsigned long long qbits = qbits_s;

    if (slot == 0xFF) {
        #pragma unroll
        for (int r = 0; r < 4; ++r) {
            int rw = lg * 4 + r;
            int gl = qb * 64 + w * 16 + rw;
            size_t ob = (size_t)(b * L_ + gl) * 512 + h * 64 + l15;
            bool ok = ((qbits >> (w * 16 + rw)) & 1ull) && (lrr[r] > 0.0f);
            if (ok) {
                float inv = 1.0f / lrr[r];
                #pragma unroll
                for (int fd = 0; fd < 4; ++fd) o[ob + 16 * fd] = f2bf(acc[fd][r] * inv);
            } else {
                #pragma unroll
                for (int fd = 0; fd < 4; ++fd) {
                    float s = 0.0f;
                    for (int m = 0; m < L_; ++m)
                        s += bf2f(qkv[(size_t)(b * L_ + m) * 1536 + 1024 + h * 64 + 16 * fd + l15]);
                    o[ob + 16 * fd] = f2bf(s * (1.0f / L_));
                }
            }
        }
    } else {
        size_t pb = ((size_t)slot * B_ + b) * H_ + h;
        #pragma unroll
        for (int r = 0; r < 4; ++r) {
            int rloc = w * 16 + lg * 4 + r;
            #pragma unroll
            for (int fd = 0; fd < 4; ++fd)
                pacc[pb * 4096 + (size_t)rloc * 64 + 16 * fd + l15] = acc[fd][r];
            if (l15 == 0) {
                pm[pb * 64 + rloc] = mrr[r];
                pl[pb * 64 + rloc] = lrr[r];
            }
        }
    }
}

// ---------------------------------------------------------------------------
// Combine partial flash results for split q-blocks.
// ---------------------------------------------------------------------------
__global__ __launch_bounds__(256) void attn_combine(const short* __restrict__ qkv,
                                                    const int* __restrict__ tokens,
                                                    short* __restrict__ o,
                                                    const float* __restrict__ pacc,
                                                    const float* __restrict__ pm,
                                                    const float* __restrict__ pl,
                                                    int lyr) {
    int ci = blockIdx.x, h = blockIdx.y, b = blockIdx.z;
    int qb  = g_wt.cmb_qb[lyr][ci];
    int s0  = g_wt.cmb_slot0[lyr][ci];
    int nch = g_wt.cmb_nch[lyr][ci];
    int t = threadIdx.x;
    int r = t >> 2, dq = t & 3;
    int grow = qb * 64 + r;
    bool pq = tokens[b * L_ + grow] > 0;
    float M = -INFINITY;
    for (int c = 0; c < nch; ++c)
        M = fmaxf(M, pm[(((size_t)(s0 + c) * B_ + b) * H_ + h) * 64 + r]);
    size_t ob = (size_t)(b * L_ + grow) * 512 + h * 64 + dq * 16;
    if (pq && M > -1e30f) {
        float lsum = 0.0f;
        float accd[16] = {};
        for (int c = 0; c < nch; ++c) {
            size_t pb = ((size_t)(s0 + c) * B_ + b) * H_ + h;
            float wgt = __expf(pm[pb * 64 + r] - M);
            lsum += pl[pb * 64 + r] * wgt;
            const float* pa = pacc + pb * 4096 + (size_t)r * 64 + dq * 16;
            #pragma unroll
            for (int j = 0; j < 16; ++j) accd[j] += pa[j] * wgt;
        }
        float inv = 1.0f / lsum;
        #pragma unroll
        for (int j = 0; j < 16; ++j) o[ob + j] = f2bf(accd[j] * inv);
    } else {
        #pragma unroll
        for (int j = 0; j < 16; ++j) {
            float s = 0.0f;
            for (int m = 0; m < L_; ++m)
                s += bf2f(qkv[(size_t)(b * L_ + m) * 1536 + 1024 + h * 64 + dq * 16 + j]);
            o[ob + j] = f2bf(s * (1.0f / L_));
        }
    }
}

// ---------------------------------------------------------------------------
// Launch
// ---------------------------------------------------------------------------
extern "C" void kernel_launch(void* const* d_in, const int* in_sizes, int n_in,
                              void* d_out, int out_size, void* d_ws, size_t ws_size,
                              hipStream_t stream) {
    (void)in_sizes; (void)n_in; (void)out_size; (void)ws_size;
    const int*   tokens = (const int*)d_in[0];
    const float* embed  = (const float*)d_in[1];
    const float* ln1_s  = (const float*)d_in[2];
    const float* ln1_b  = (const float*)d_in[3];
    const float* wq     = (const float*)d_in[4];
    const float* wk     = (const float*)d_in[5];
    const float* wv     = (const float*)d_in[6];
    const float* wo     = (const float*)d_in[7];
    const float* ln2_s  = (const float*)d_in[8];
    const float* ln2_b  = (const float*)d_in[9];
    const float* w1     = (const float*)d_in[10];
    const float* b1     = (const float*)d_in[11];
    const float* w2     = (const float*)d_in[12];
    const float* b2     = (const float*)d_in[13];
    const float* lnf_s  = (const float*)d_in[14];
    const float* lnf_b  = (const float*)d_in[15];
    float* out = (float*)d_out;

    const size_t BLE = (size_t)B_ * L_ * E_;              // 4,194,304
    char* ws = (char*)d_ws;
    float* x    = (float*)ws;                             // 16 MB
    short* yb   = (short*)(x + BLE);                      //  8 MB
    short* R    = yb + BLE;                               // 32 MB (qkv+ob / hb)
    short* qkv  = R;
    short* ob   = R + 3 * BLE;
    short* hb   = R;
    short* qkvt = R + 4 * BLE;                            // bf16 weights
    short* wot  = qkvt + (size_t)NL_ * 1536 * 512;
    short* w1t  = wot + (size_t)NL_ * 512 * 512;
    short* w2t  = w1t + (size_t)NL_ * 2048 * 512;
    float* pacc = (float*)(w2t + (size_t)NL_ * 512 * 2048);   // 8 slots x B x H x 4096 f32
    float* pm   = pacc + (size_t)8 * B_ * H_ * 4096;
    float* pl   = pm + (size_t)8 * B_ * H_ * 64;

    convT_kernel<<<dim3(8, 8, NL_), 256, 0, stream>>>(wq, qkvt,          512, 512, 262144, 786432, 0.125f);
    convT_kernel<<<dim3(8, 8, NL_), 256, 0, stream>>>(wk, qkvt + 262144, 512, 512, 262144, 786432, 1.0f);
    convT_kernel<<<dim3(8, 8, NL_), 256, 0, stream>>>(wv, qkvt + 524288, 512, 512, 262144, 786432, 1.0f);
    convT_kernel<<<dim3(8, 8, NL_), 256, 0, stream>>>(wo, wot,           512, 512, 262144, 262144, 1.0f);
    convT_kernel<<<dim3(32, 8, NL_), 256, 0, stream>>>(w1, w1t,          512, 2048, 1048576, 1048576, 1.0f);
    convT_kernel<<<dim3(8, 32, NL_), 256, 0, stream>>>(w2, w2t,          2048, 512, 1048576, 1048576, 1.0f);

    embed_kernel<<<(L_ * E_ / 8) / 256, 256, 0, stream>>>(tokens, embed, x);

    const int MR = B_ * L_;
    const int LNG = MR / 4;                                // 2048 blocks
    for (int lyr = 0; lyr < NL_; ++lyr) {
        ln_kernel<1><<<LNG, 256, 0, stream>>>(x, ln1_s + lyr * E_, ln1_b + lyr * E_, yb);
        mgemm_kernel<128, 128, 2, 2, 0, 1><<<dim3(12, 64), 256, 0, stream>>>(
            yb, qkvt + (size_t)lyr * 786432, nullptr, nullptr, qkv, MR, 1536, 512);
        attn_kernel<<<dim3(WT_HOST.n_items[lyr], H_, B_), 256, 0, stream>>>(
            qkv, tokens, ob, pacc, pm, pl, lyr);
        attn_combine<<<dim3(WT_HOST.n_cmb[lyr], H_, B_), 256, 0, stream>>>(
            qkv, tokens, ob, pacc, pm, pl, lyr);
        mgemm_kernel<64, 128, 2, 2, 0, 0><<<dim3(4, 128), 256, 0, stream>>>(
            ob, wot + (size_t)lyr * 262144, nullptr, x, x, MR, 512, 512);
        ln_kernel<1><<<LNG, 256, 0, stream>>>(x, ln2_s + lyr * E_, ln2_b + lyr * E_, yb);
        mgemm_kernel<128, 128, 2, 2, 1, 1><<<dim3(16, 64), 256, 0, stream>>>(
            yb, w1t + (size_t)lyr * 1048576, b1 + (size_t)lyr * M_, nullptr, hb, MR, 2048, 512);
        mgemm_kernel<64, 128, 2, 2, 0, 0><<<dim3(4, 128), 256, 0, stream>>>(
            hb, w2t + (size_t)lyr * 1048576, b2 + (size_t)lyr * E_, x, x, MR, 512, 2048);
    }
    ln_kernel<0><<<LNG, 256, 0, stream>>>(x, lnf_s, lnf_b, out);
}

// Round 9
// 602.293 us; speedup vs baseline: 24.0847x; 1.1372x over previous
//
#include <hip/hip_runtime.h>
#include <hip/hip_bf16.h>
#include <cmath>
#include <cstdint>
#include <cstddef>

#define B_   4
#define L_   2048
#define E_   512
#define H_   8
#define DH_  64
#define M_   2048
#define NL_  4
#define NB_  32
#define BS_  64
#define CH_  12   // max 64-key jb-blocks per attention work item

typedef short bf16x8 __attribute__((ext_vector_type(8)));
typedef short bf16x4 __attribute__((ext_vector_type(4)));
typedef float f32x4 __attribute__((ext_vector_type(4)));

__device__ __forceinline__ short f2bf(float f) {
    union { __hip_bfloat16 h; short s; } u;
    u.h = __float2bfloat16(f);
    return u.s;
}
__device__ __forceinline__ float bf2f(short s) {
    union { short s; __hip_bfloat16 h; } u;
    u.s = s;
    return __bfloat162float(u.h);
}

// ---------------------------------------------------------------------------
// BigBird masks + work partition, all at COMPILE TIME.
// ---------------------------------------------------------------------------
struct MaskTable { unsigned m[NL_][NB_]; };
struct CxMT { unsigned key[624]; int pos; };

constexpr unsigned cx_next(CxMT& st) {
    if (st.pos >= 624) {
        for (int i = 0; i < 624; ++i) {
            unsigned y = (st.key[i] & 0x80000000u) | (st.key[(i + 1) % 624] & 0x7fffffffu);
            st.key[i] = st.key[(i + 397) % 624] ^ (y >> 1) ^ ((y & 1u) ? 0x9908b0dfu : 0u);
        }
        st.pos = 0;
    }
    unsigned y = st.key[st.pos++];
    y ^= y >> 11;
    y ^= (y << 7) & 0x9d2c5680u;
    y ^= (y << 15) & 0xefc60000u;
    y ^= y >> 18;
    return y;
}
constexpr unsigned cx_interval(CxMT& st, unsigned maxv) {
    if (maxv == 0u) return 0u;
    unsigned mask = maxv;
    mask |= mask >> 1; mask |= mask >> 2; mask |= mask >> 4;
    mask |= mask >> 8; mask |= mask >> 16;
    unsigned v = cx_next(st) & mask;
    while (v > maxv) v = cx_next(st) & mask;
    return v;
}
constexpr MaskTable compute_masks() {
    MaskTable T{};
    for (int lyr = 0; lyr < NL_; ++lyr) {
        unsigned m[NB_] = {};
        for (int i = 0; i < NB_; ++i) {
            unsigned w = 1u << i;
            if (i > 0) w |= 1u << (i - 1);
            if (i < NB_ - 1) w |= 1u << (i + 1);
            w |= 1u | (1u << (NB_ - 1));
            m[i] = w;
        }
        m[0] = 0xffffffffu;
        m[NB_ - 1] = 0xffffffffu;
        CxMT st{};
        unsigned s = (unsigned)lyr;
        for (int i = 0; i < 624; ++i) {
            st.key[i] = s;
            s = 1812433253u * (s ^ (s >> 30)) + (unsigned)i + 1u;
        }
        st.pos = 624;
        for (int i = 1; i < NB_ - 1; ++i) {
            int cand[NB_] = {};
            int n = 0;
            for (int j = 0; j < NB_; ++j) {
                if (j == 0 || j == NB_ - 1 || j == i - 1 || j == i || j == i + 1) continue;
                cand[n++] = j;
            }
            for (int kk = n - 1; kk >= 1; --kk) {
                int jj = (int)cx_interval(st, (unsigned)kk);
                int tmp = cand[kk]; cand[kk] = cand[jj]; cand[jj] = tmp;
            }
            m[i] |= (1u << cand[0]) | (1u << cand[1]) | (1u << cand[2]);
        }
        for (int i = 0; i < NB_; ++i) T.m[lyr][i] = m[i];
    }
    return T;
}

struct WorkTable {
    int n_items[NL_];
    int n_cmb[NL_];
    unsigned char itm_qb[NL_][40];
    unsigned char itm_j0[NL_][40];
    unsigned char itm_jn[NL_][40];
    unsigned char itm_slot[NL_][40];   // 0xFF = direct write to o
    unsigned char cmb_qb[NL_][8];
    unsigned char cmb_slot0[NL_][8];
    unsigned char cmb_nch[NL_][8];
    unsigned char jlist[NL_][NB_][NB_];
};

constexpr WorkTable compute_work() {
    WorkTable T{};
    MaskTable M = compute_masks();
    for (int lyr = 0; lyr < NL_; ++lyr) {
        int items = 0, slots = 0, ncmb = 0;
        for (int qb = 0; qb < NB_; ++qb) {
            int cnt = 0;
            for (int j = 0; j < NB_; ++j)
                if ((M.m[lyr][qb] >> j) & 1u)
                    T.jlist[lyr][qb][cnt++] = (unsigned char)j;
            int nch = (cnt + CH_ - 1) / CH_;
            if (nch == 1) {
                T.itm_qb[lyr][items] = (unsigned char)qb;
                T.itm_j0[lyr][items] = 0;
                T.itm_jn[lyr][items] = (unsigned char)cnt;
                T.itm_slot[lyr][items] = 0xFF;
                items++;
            } else {
                T.cmb_qb[lyr][ncmb] = (unsigned char)qb;
                T.cmb_slot0[lyr][ncmb] = (unsigned char)slots;
                T.cmb_nch[lyr][ncmb] = (unsigned char)nch;
                ncmb++;
                int base = cnt / nch, rem = cnt % nch, off = 0;
                for (int c = 0; c < nch; ++c) {
                    int cl = base + (c < rem ? 1 : 0);
                    T.itm_qb[lyr][items] = (unsigned char)qb;
                    T.itm_j0[lyr][items] = (unsigned char)off;
                    T.itm_jn[lyr][items] = (unsigned char)cl;
                    T.itm_slot[lyr][items] = (unsigned char)slots;
                    items++; slots++; off += cl;
                }
            }
        }
        T.n_items[lyr] = items;
        T.n_cmb[lyr] = ncmb;
    }
    return T;
}

static constexpr WorkTable WT_HOST = compute_work();
__constant__ WorkTable g_wt = compute_work();

// ---------------------------------------------------------------------------
// Embedding + sinusoidal PE (PE reused across the 4 batches)
// ---------------------------------------------------------------------------
__global__ __launch_bounds__(256) void embed_kernel(const int* __restrict__ tokens,
                                                    const float* __restrict__ embed,
                                                    float* __restrict__ x) {
    int idx = blockIdx.x * 256 + threadIdx.x;      // < L_*E_/8 = 131072
    int l = idx >> 6;
    int e0 = (idx & 63) * 8;
    float pe[8];
    #pragma unroll
    for (int j = 0; j < 8; ++j) {
        int e = e0 + j;
        int jj = e & 255;
        float div = expf((float)jj * -0.03597789207717895f);  // -ln(10000)/256
        float arg = (float)l * div;
        pe[j] = (e < 256) ? sinf(arg) : cosf(arg);
    }
    #pragma unroll
    for (int b = 0; b < B_; ++b) {
        int tok = tokens[b * L_ + l];
        const float* em = embed + (size_t)tok * E_ + e0;
        f32x4 v0 = *(const f32x4*)em;
        f32x4 v1 = *(const f32x4*)(em + 4);
        #pragma unroll
        for (int j = 0; j < 4; ++j) { v0[j] += pe[j]; v1[j] += pe[4 + j]; }
        float* xo = x + ((size_t)(b * L_ + l)) * E_ + e0;
        *(f32x4*)xo = v0;
        *(f32x4*)(xo + 4) = v1;
    }
}

// ---------------------------------------------------------------------------
// LayerNorm: wave-per-row (4 rows per 256-thread block, no barriers).
// ---------------------------------------------------------------------------
template<int OUTBF>
__global__ __launch_bounds__(256) void ln_kernel(const float* __restrict__ x,
                                                 const float* __restrict__ gamma,
                                                 const float* __restrict__ beta,
                                                 void* __restrict__ yout) {
    int t = threadIdx.x;
    int lane = t & 63;
    int row = blockIdx.x * 4 + (t >> 6);
    const float* xr = x + (size_t)row * E_ + lane * 8;
    f32x4 a0 = *(const f32x4*)xr;
    f32x4 a1 = *(const f32x4*)(xr + 4);
    float s = a0[0] + a0[1] + a0[2] + a0[3] + a1[0] + a1[1] + a1[2] + a1[3];
    #pragma unroll
    for (int off = 1; off < 64; off <<= 1) s += __shfl_xor(s, off, 64);
    float mu = s * (1.0f / E_);
    float q = 0.0f;
    #pragma unroll
    for (int j = 0; j < 4; ++j) { float d = a0[j] - mu; q += d * d; }
    #pragma unroll
    for (int j = 0; j < 4; ++j) { float d = a1[j] - mu; q += d * d; }
    #pragma unroll
    for (int off = 1; off < 64; off <<= 1) q += __shfl_xor(q, off, 64);
    float rstd = rsqrtf(q * (1.0f / E_) + 1e-6f);
    f32x4 g0 = *(const f32x4*)(gamma + lane * 8);
    f32x4 g1 = *(const f32x4*)(gamma + lane * 8 + 4);
    f32x4 b0 = *(const f32x4*)(beta + lane * 8);
    f32x4 b1 = *(const f32x4*)(beta + lane * 8 + 4);
    float o[8];
    #pragma unroll
    for (int j = 0; j < 4; ++j) o[j] = (a0[j] - mu) * rstd * g0[j] + b0[j];
    #pragma unroll
    for (int j = 0; j < 4; ++j) o[4 + j] = (a1[j] - mu) * rstd * g1[j] + b1[j];
    if (OUTBF) {
        bf16x8 pk;
        #pragma unroll
        for (int j = 0; j < 8; ++j) pk[j] = f2bf(o[j]);
        *(bf16x8*)((short*)yout + (size_t)row * E_ + lane * 8) = pk;
    } else {
        float* yr = (float*)yout + (size_t)row * E_ + lane * 8;
        *(f32x4*)yr = f32x4{o[0], o[1], o[2], o[3]};
        *(f32x4*)(yr + 4) = f32x4{o[4], o[5], o[6], o[7]};
    }
}

// ---------------------------------------------------------------------------
// Weight convert + transpose: Wt[n][k] = bf16(W[k][n] * scale), per layer (z)
// ---------------------------------------------------------------------------
__global__ __launch_bounds__(256) void convT_kernel(const float* __restrict__ W,
                                                    short* __restrict__ Wt,
                                                    int K, int N,
                                                    size_t wStride, size_t wtStride,
                                                    float scale) {
    __shared__ float Ts[64][65];
    const float* Wl = W + blockIdx.z * wStride;
    short* Wtl = Wt + blockIdx.z * wtStride;
    int n0 = blockIdx.x * 64, k0 = blockIdx.y * 64;
    int t = threadIdx.x;
    int c = t & 63, r0 = t >> 6;
    #pragma unroll
    for (int i = 0; i < 16; ++i) {
        int r = r0 * 16 + i;
        Ts[r][c] = Wl[(size_t)(k0 + r) * N + n0 + c] * scale;
    }
    __syncthreads();
    #pragma unroll
    for (int i = 0; i < 16; ++i) {
        int r = r0 * 16 + i;
        Wtl[(size_t)(n0 + r) * K + k0 + c] = f2bf(Ts[c][r]);
    }
}

// ---------------------------------------------------------------------------
// MFMA bf16 GEMM, 2-phase double-buffered, 512 threads = 8 waves (2x4),
// XCD-aware bijective block swizzle (T1) for L2 A-panel locality.
// C[M,N] = act(A[M,K] * Bt[N,K]^T + bias) + res. T2 XOR swizzle on LDS.
// ---------------------------------------------------------------------------
__device__ __forceinline__ float gelu_tanh(float x) {
    float u = x * (1.5957691216057308f + 0.07135480122394604f * x * x);
    return x / (1.0f + __expf(-u));
}

template<int BM, int BN, int ACT, int OUTBF>
__global__ __launch_bounds__(512) void mgemm_kernel(const short* __restrict__ A,
                                                    const short* __restrict__ Bt,
                                                    const float* __restrict__ bias,
                                                    const float* __restrict__ res,
                                                    void* __restrict__ Cout,
                                                    int M, int N, int K) {
    constexpr int WR = 2, WC = 4;      // 8 waves
    constexpr int FM = BM / WR / 16;
    constexpr int FN = BN / WC / 16;
    constexpr int ASZ = BM * 64;
    constexpr int BSZ = BN * 64;
    constexpr int PAD = 8;
    constexpr int CW = BN + PAD;
    static_assert((size_t)(OUTBF ? BM * CW * 2 : BM * CW * 4) <= (size_t)2 * (ASZ + BSZ) * 2,
                  "epilogue stage must fit in dbuf LDS");
    __shared__ __align__(16) short smem[2 * (ASZ + BSZ)];

    int t = threadIdx.x;
    int w = t >> 6, l = t & 63;
    int l15 = l & 15, lg = l >> 4;
    int wr = w >> 2, wc = w & 3;
    int rowbase = wr * (BM / WR), colbase = wc * (BN / WC);

    // XCD-aware bijective swizzle (all grids have nwg % 8 == 0)
    int nwg = (int)(gridDim.x * gridDim.y);
    int orig = (int)(blockIdx.y * gridDim.x + blockIdx.x);
    int sid = (orig & 7) * (nwg >> 3) + (orig >> 3);
    int bx = sid % (int)gridDim.x, by = sid / (int)gridDim.x;
    int brow = by * BM, bcol = bx * BN;

    int swz = ((t & 7) ^ ((t >> 3) & 7)) * 8;   // pre-swizzled global chunk
    f32x4 acc[FM][FN] = {};

    const int nt = K >> 6;

    auto stage = [&](int buf, int k0) {
        short* Ad = smem + buf * ASZ;
        short* Bd = smem + 2 * ASZ + buf * BSZ;
        #pragma unroll
        for (int it = 0; it < BM / 64; ++it) {
            int row = it * 64 + (t >> 3);
            const short* ga = A + (size_t)(brow + row) * K + k0 + swz;
            __builtin_amdgcn_global_load_lds(
                (const __attribute__((address_space(1))) unsigned int*)ga,
                (__attribute__((address_space(3))) unsigned int*)(Ad + (it * 64 + w * 8) * 64),
                16, 0, 0);
        }
        #pragma unroll
        for (int it = 0; it < BN / 64; ++it) {
            int row = it * 64 + (t >> 3);
            const short* gb = Bt + (size_t)(bcol + row) * K + k0 + swz;
            __builtin_amdgcn_global_load_lds(
                (const __attribute__((address_space(1))) unsigned int*)gb,
                (__attribute__((address_space(3))) unsigned int*)(Bd + (it * 64 + w * 8) * 64),
                16, 0, 0);
        }
    };

    stage(0, 0);
    asm volatile("s_waitcnt vmcnt(0)" ::: "memory");
    __builtin_amdgcn_s_barrier();

    int cur = 0;
    for (int kt = 0; kt < nt; ++kt) {
        if (kt + 1 < nt) stage(cur ^ 1, (kt + 1) << 6);
        const short* Ar = smem + cur * ASZ;
        const short* Br = smem + 2 * ASZ + cur * BSZ;
        #pragma unroll
        for (int kk = 0; kk < 64; kk += 32) {
            bf16x8 af[FM], bfr[FN];
            #pragma unroll
            for (int m = 0; m < FM; ++m)
                af[m] = *(const bf16x8*)(Ar + (rowbase + m * 16 + l15) * 64
                                            + (((kk >> 3) + lg) ^ (l15 & 7)) * 8);
            #pragma unroll
            for (int n = 0; n < FN; ++n)
                bfr[n] = *(const bf16x8*)(Br + (colbase + n * 16 + l15) * 64
                                             + (((kk >> 3) + lg) ^ (l15 & 7)) * 8);
            #pragma unroll
            for (int m = 0; m < FM; ++m)
                #pragma unroll
                for (int n = 0; n < FN; ++n)
                    acc[m][n] = __builtin_amdgcn_mfma_f32_16x16x32_bf16(af[m], bfr[n], acc[m][n], 0, 0, 0);
        }
        asm volatile("s_waitcnt vmcnt(0) lgkmcnt(0)" ::: "memory");
        __builtin_amdgcn_s_barrier();
        cur ^= 1;
    }

    if (OUTBF) {
        short* Cs = smem;
        #pragma unroll
        for (int m = 0; m < FM; ++m) {
            int row = rowbase + m * 16 + lg * 4;
            #pragma unroll
            for (int n = 0; n < FN; ++n) {
                int col = colbase + n * 16 + l15;
                float bv = bias ? bias[bcol + col] : 0.0f;
                #pragma unroll
                for (int r = 0; r < 4; ++r) {
                    float vv = acc[m][n][r] + bv;
                    if (ACT == 1) vv = gelu_tanh(vv);
                    Cs[(row + r) * CW + col] = f2bf(vv);
                }
            }
        }
        __syncthreads();
        #pragma unroll
        for (int it = 0; it < BM * BN / 8 / 512; ++it) {
            int c = it * 512 + t;
            int row = c / (BN / 8), c8 = c % (BN / 8);
            *(bf16x8*)((short*)Cout + (size_t)(brow + row) * N + bcol + c8 * 8) =
                *(const bf16x8*)(Cs + row * CW + c8 * 8);
        }
    } else {
        float* Cs = (float*)smem;
        #pragma unroll
        for (int m = 0; m < FM; ++m) {
            int row = rowbase + m * 16 + lg * 4;
            #pragma unroll
            for (int n = 0; n < FN; ++n) {
                int col = colbase + n * 16 + l15;
                float bv = bias ? bias[bcol + col] : 0.0f;
                #pragma unroll
                for (int r = 0; r < 4; ++r)
                    Cs[(row + r) * CW + col] = acc[m][n][r] + bv;
            }
        }
        __syncthreads();
        #pragma unroll
        for (int it = 0; it < BM * BN / 4 / 512; ++it) {
            int c = it * 512 + t;
            int row = c / (BN / 4), c4 = c % (BN / 4);
            f32x4 vv = *(const f32x4*)(Cs + row * CW + c4 * 4);
            size_t gi = (size_t)(brow + row) * N + bcol + c4 * 4;
            if (res) vv += *(const f32x4*)(res + gi);
            *(f32x4*)((float*)Cout + gi) = vv;
        }
    }
}

// ---------------------------------------------------------------------------
// Sparse block attention, MFMA bf16, KVBLK=64, swapped QK^T (unchanged r8).
// ---------------------------------------------------------------------------
#define KSTR 72

__global__ __launch_bounds__(256) void attn_kernel(const short* __restrict__ qkv,
                                                   const int* __restrict__ tokens,
                                                   short* __restrict__ o,
                                                   float* __restrict__ pacc,
                                                   float* __restrict__ pm,
                                                   float* __restrict__ pl,
                                                   int lyr) {
    __shared__ __align__(16) short Ks[64][KSTR];
    __shared__ __align__(16) short Vt[64][KSTR];
    __shared__ __align__(16) short Pw[4][16][KSTR];
    __shared__ unsigned long long qbits_s;
    __shared__ unsigned long long kbits_s;

    int item = blockIdx.x, h = blockIdx.y, b = blockIdx.z;
    int qb   = g_wt.itm_qb[lyr][item];
    int j0   = g_wt.itm_j0[lyr][item];
    int jn   = g_wt.itm_jn[lyr][item];
    int slot = g_wt.itm_slot[lyr][item];
    const unsigned char* jl = g_wt.jlist[lyr][qb];

    int t = threadIdx.x;
    int l = t & 63, w = t >> 6;
    int l15 = l & 15, lg = l >> 4;
    int srow = t >> 3, sdb = t & 7;

    if (t < 64) {
        unsigned long long qm = __ballot(tokens[b * L_ + qb * 64 + t] > 0);
        if (t == 0) qbits_s = qm;
    }

    int qrow = qb * 64 + w * 16 + l15;
    const short* qp = qkv + (size_t)(b * L_ + qrow) * 1536 + h * 64;
    bf16x8 qf0 = *(const bf16x8*)(qp + lg * 8);
    bf16x8 qf1 = *(const bf16x8*)(qp + lg * 8 + 32);

    f32x4 acc[4] = {};
    float m_r = -INFINITY, l_r = 0.0f;

    bf16x8 kr0, kr1, vr0, vr1;
    int pn = 0;
    auto LOAD = [&](int ci) {
        int jb = jl[j0 + ci];
        const short* base = qkv + (size_t)(b * L_ + jb * 64 + srow) * 1536 + h * 64;
        kr0 = *(const bf16x8*)(base + 512 + sdb * 8);
        kr1 = *(const bf16x8*)(base + (size_t)32 * 1536 + 512 + sdb * 8);
        vr0 = *(const bf16x8*)(base + 1024 + sdb * 8);
        vr1 = *(const bf16x8*)(base + (size_t)32 * 1536 + 1024 + sdb * 8);
        if (t < 64) pn = tokens[b * L_ + jb * 64 + t];
    };
    LOAD(0);

    for (int ci = 0; ci < jn; ++ci) {
        __syncthreads();
        *(bf16x8*)&Ks[srow][sdb * 8] = kr0;
        *(bf16x8*)&Ks[srow + 32][sdb * 8] = kr1;
        #pragma unroll
        for (int j = 0; j < 8; ++j) {
            Vt[sdb * 8 + j][(srow & 7) + 8 * ((srow >> 3) ^ sdb)] = vr0[j];
            Vt[sdb * 8 + j][(srow & 7) + 8 * (((srow >> 3) + 4) ^ sdb)] = vr1[j];
        }
        if (t < 64) {
            unsigned long long km = __ballot(pn > 0);
            if (t == 0) kbits_s = km;
        }
        __syncthreads();

        if (ci + 1 < jn) LOAD(ci + 1);

        f32x4 sacc[4];
        __builtin_amdgcn_s_setprio(1);
        #pragma unroll
        for (int f = 0; f < 4; ++f) {
            bf16x8 kk0 = *(const bf16x8*)&Ks[16 * f + l15][lg * 8];
            bf16x8 kk1 = *(const bf16x8*)&Ks[16 * f + l15][lg * 8 + 32];
            f32x4 z = {};
            z = __builtin_amdgcn_mfma_f32_16x16x32_bf16(kk0, qf0, z, 0, 0, 0);
            z = __builtin_amdgcn_mfma_f32_16x16x32_bf16(kk1, qf1, z, 0, 0, 0);
            sacc[f] = z;
        }
        __builtin_amdgcn_s_setprio(0);

        unsigned long long kb = kbits_s;
        bool pq = (qbits_s >> (w * 16 + l15)) & 1ull;
        unsigned vm = 0;
        #pragma unroll
        for (int f = 0; f < 4; ++f)
            vm |= ((unsigned)(kb >> (16 * f + 4 * lg)) & 0xFu) << (4 * f);
        if (!pq) vm = 0;

        float mx = -INFINITY;
        #pragma unroll
        for (int f = 0; f < 4; ++f)
            #pragma unroll
            for (int r = 0; r < 4; ++r)
                if ((vm >> (4 * f + r)) & 1u) mx = fmaxf(mx, sacc[f][r]);
        mx = fmaxf(mx, __shfl_xor(mx, 16, 64));
        mx = fmaxf(mx, __shfl_xor(mx, 32, 64));
        float nm = fmaxf(m_r, mx);

        float pv[16];
        float sum = 0.0f;
        #pragma unroll
        for (int f = 0; f < 4; ++f)
            #pragma unroll
            for (int r = 0; r < 4; ++r) {
                float p = ((vm >> (4 * f + r)) & 1u) ? __expf(sacc[f][r] - nm) : 0.0f;
                pv[4 * f + r] = p;
                sum += p;
            }
        sum += __shfl_xor(sum, 16, 64);
        sum += __shfl_xor(sum, 32, 64);
        float al = (nm == -INFINITY) ? 1.0f : __expf(m_r - nm);
        m_r = nm;
        l_r = l_r * al + sum;

        #pragma unroll
        for (int f = 0; f < 4; ++f) {
            bf16x4 pk;
            #pragma unroll
            for (int r = 0; r < 4; ++r) pk[r] = f2bf(pv[4 * f + r]);
            *(bf16x4*)&Pw[w][l15][16 * f + 4 * lg] = pk;
        }

        float alr[4];
        #pragma unroll
        for (int r = 0; r < 4; ++r) alr[r] = __shfl(al, lg * 4 + r, 64);
        #pragma unroll
        for (int fd = 0; fd < 4; ++fd)
            #pragma unroll
            for (int r = 0; r < 4; ++r) acc[fd][r] *= alr[r];

        bf16x8 pa0 = *(const bf16x8*)&Pw[w][l15][lg * 8];
        bf16x8 pa1 = *(const bf16x8*)&Pw[w][l15][lg * 8 + 32];
        __builtin_amdgcn_s_setprio(1);
        #pragma unroll
        for (int fd = 0; fd < 4; ++fd) {
            int dd = 16 * fd + l15;
            bf16x8 vv0 = *(const bf16x8*)&Vt[dd][8 * (lg ^ (dd >> 3))];
            bf16x8 vv1 = *(const bf16x8*)&Vt[dd][8 * ((4 + lg) ^ (dd >> 3))];
            acc[fd] = __builtin_amdgcn_mfma_f32_16x16x32_bf16(pa0, vv0, acc[fd], 0, 0, 0);
            acc[fd] = __builtin_amdgcn_mfma_f32_16x16x32_bf16(pa1, vv1, acc[fd], 0, 0, 0);
        }
        __builtin_amdgcn_s_setprio(0);
    }

    float lrr[4], mrr[4];
    #pragma unroll
    for (int r = 0; r < 4; ++r) {
        lrr[r] = __shfl(l_r, lg * 4 + r, 64);
        mrr[r] = __shfl(m_r, lg * 4 + r, 64);
    }
    unsigned long long qbits = qbits_s;

    if (slot == 0xFF) {
        #pragma unroll
        for (int r = 0; r < 4; ++r) {
            int rw = lg * 4 + r;
            int gl = qb * 64 + w * 16 + rw;
            size_t ob = (size_t)(b * L_ + gl) * 512 + h * 64 + l15;
            bool ok = ((qbits >> (w * 16 + rw)) & 1ull) && (lrr[r] > 0.0f);
            if (ok) {
                float inv = 1.0f / lrr[r];
                #pragma unroll
                for (int fd = 0; fd < 4; ++fd) o[ob + 16 * fd] = f2bf(acc[fd][r] * inv);
            } else {
                #pragma unroll
                for (int fd = 0; fd < 4; ++fd) {
                    float s = 0.0f;
                    for (int m = 0; m < L_; ++m)
                        s += bf2f(qkv[(size_t)(b * L_ + m) * 1536 + 1024 + h * 64 + 16 * fd + l15]);
                    o[ob + 16 * fd] = f2bf(s * (1.0f / L_));
                }
            }
        }
    } else {
        size_t pb = ((size_t)slot * B_ + b) * H_ + h;
        #pragma unroll
        for (int r = 0; r < 4; ++r) {
            int rloc = w * 16 + lg * 4 + r;
            #pragma unroll
            for (int fd = 0; fd < 4; ++fd)
                pacc[pb * 4096 + (size_t)rloc * 64 + 16 * fd + l15] = acc[fd][r];
            if (l15 == 0) {
                pm[pb * 64 + rloc] = mrr[r];
                pl[pb * 64 + rloc] = lrr[r];
            }
        }
    }
}

// ---------------------------------------------------------------------------
// Combine partial flash results for split q-blocks.
// ---------------------------------------------------------------------------
__global__ __launch_bounds__(256) void attn_combine(const short* __restrict__ qkv,
                                                    const int* __restrict__ tokens,
                                                    short* __restrict__ o,
                                                    const float* __restrict__ pacc,
                                                    const float* __restrict__ pm,
                                                    const float* __restrict__ pl,
                                                    int lyr) {
    int ci = blockIdx.x, h = blockIdx.y, b = blockIdx.z;
    int qb  = g_wt.cmb_qb[lyr][ci];
    int s0  = g_wt.cmb_slot0[lyr][ci];
    int nch = g_wt.cmb_nch[lyr][ci];
    int t = threadIdx.x;
    int r = t >> 2, dq = t & 3;
    int grow = qb * 64 + r;
    bool pq = tokens[b * L_ + grow] > 0;
    float M = -INFINITY;
    for (int c = 0; c < nch; ++c)
        M = fmaxf(M, pm[(((size_t)(s0 + c) * B_ + b) * H_ + h) * 64 + r]);
    size_t ob = (size_t)(b * L_ + grow) * 512 + h * 64 + dq * 16;
    if (pq && M > -1e30f) {
        float lsum = 0.0f;
        float accd[16] = {};
        for (int c = 0; c < nch; ++c) {
            size_t pb = ((size_t)(s0 + c) * B_ + b) * H_ + h;
            float wgt = __expf(pm[pb * 64 + r] - M);
            lsum += pl[pb * 64 + r] * wgt;
            const float* pa = pacc + pb * 4096 + (size_t)r * 64 + dq * 16;
            #pragma unroll
            for (int j = 0; j < 16; ++j) accd[j] += pa[j] * wgt;
        }
        float inv = 1.0f / lsum;
        #pragma unroll
        for (int j = 0; j < 16; ++j) o[ob + j] = f2bf(accd[j] * inv);
    } else {
        #pragma unroll
        for (int j = 0; j < 16; ++j) {
            float s = 0.0f;
            for (int m = 0; m < L_; ++m)
                s += bf2f(qkv[(size_t)(b * L_ + m) * 1536 + 1024 + h * 64 + dq * 16 + j]);
            o[ob + j] = f2bf(s * (1.0f / L_));
        }
    }
}

// ---------------------------------------------------------------------------
// Launch
// ---------------------------------------------------------------------------
extern "C" void kernel_launch(void* const* d_in, const int* in_sizes, int n_in,
                              void* d_out, int out_size, void* d_ws, size_t ws_size,
                              hipStream_t stream) {
    (void)in_sizes; (void)n_in; (void)out_size; (void)ws_size;
    const int*   tokens = (const int*)d_in[0];
    const float* embed  = (const float*)d_in[1];
    const float* ln1_s  = (const float*)d_in[2];
    const float* ln1_b  = (const float*)d_in[3];
    const float* wq     = (const float*)d_in[4];
    const float* wk     = (const float*)d_in[5];
    const float* wv     = (const float*)d_in[6];
    const float* wo     = (const float*)d_in[7];
    const float* ln2_s  = (const float*)d_in[8];
    const float* ln2_b  = (const float*)d_in[9];
    const float* w1     = (const float*)d_in[10];
    const float* b1     = (const float*)d_in[11];
    const float* w2     = (const float*)d_in[12];
    const float* b2     = (const float*)d_in[13];
    const float* lnf_s  = (const float*)d_in[14];
    const float* lnf_b  = (const float*)d_in[15];
    float* out = (float*)d_out;

    const size_t BLE = (size_t)B_ * L_ * E_;              // 4,194,304
    char* ws = (char*)d_ws;
    float* x    = (float*)ws;                             // 16 MB
    short* yb   = (short*)(x + BLE);                      //  8 MB
    short* R    = yb + BLE;                               // 32 MB (qkv+ob / hb)
    short* qkv  = R;
    short* ob   = R + 3 * BLE;
    short* hb   = R;
    short* qkvt = R + 4 * BLE;                            // bf16 weights
    short* wot  = qkvt + (size_t)NL_ * 1536 * 512;
    short* w1t  = wot + (size_t)NL_ * 512 * 512;
    short* w2t  = w1t + (size_t)NL_ * 2048 * 512;
    float* pacc = (float*)(w2t + (size_t)NL_ * 512 * 2048);   // 8 slots x B x H x 4096 f32
    float* pm   = pacc + (size_t)8 * B_ * H_ * 4096;
    float* pl   = pm + (size_t)8 * B_ * H_ * 64;

    convT_kernel<<<dim3(8, 8, NL_), 256, 0, stream>>>(wq, qkvt,          512, 512, 262144, 786432, 0.125f);
    convT_kernel<<<dim3(8, 8, NL_), 256, 0, stream>>>(wk, qkvt + 262144, 512, 512, 262144, 786432, 1.0f);
    convT_kernel<<<dim3(8, 8, NL_), 256, 0, stream>>>(wv, qkvt + 524288, 512, 512, 262144, 786432, 1.0f);
    convT_kernel<<<dim3(8, 8, NL_), 256, 0, stream>>>(wo, wot,           512, 512, 262144, 262144, 1.0f);
    convT_kernel<<<dim3(32, 8, NL_), 256, 0, stream>>>(w1, w1t,          512, 2048, 1048576, 1048576, 1.0f);
    convT_kernel<<<dim3(8, 32, NL_), 256, 0, stream>>>(w2, w2t,          2048, 512, 1048576, 1048576, 1.0f);

    embed_kernel<<<(L_ * E_ / 8) / 256, 256, 0, stream>>>(tokens, embed, x);

    const int MR = B_ * L_;
    const int LNG = MR / 4;                                // 2048 blocks
    for (int lyr = 0; lyr < NL_; ++lyr) {
        ln_kernel<1><<<LNG, 256, 0, stream>>>(x, ln1_s + lyr * E_, ln1_b + lyr * E_, yb);
        // QKV: 8192 x 1536 x 512, 128x128 tiles, 768 wg
        mgemm_kernel<128, 128, 0, 1><<<dim3(12, 64), 512, 0, stream>>>(
            yb, qkvt + (size_t)lyr * 786432, nullptr, nullptr, qkv, MR, 1536, 512);
        attn_kernel<<<dim3(WT_HOST.n_items[lyr], H_, B_), 256, 0, stream>>>(
            qkv, tokens, ob, pacc, pm, pl, lyr);
        attn_combine<<<dim3(WT_HOST.n_cmb[lyr], H_, B_), 256, 0, stream>>>(
            qkv, tokens, ob, pacc, pm, pl, lyr);
        // WO: 8192 x 512 x 512, 64x128 tiles, 512 wg
        mgemm_kernel<64, 128, 0, 0><<<dim3(4, 128), 512, 0, stream>>>(
            ob, wot + (size_t)lyr * 262144, nullptr, x, x, MR, 512, 512);
        ln_kernel<1><<<LNG, 256, 0, stream>>>(x, ln2_s + lyr * E_, ln2_b + lyr * E_, yb);
        // W1: 8192 x 2048 x 512, 128x128 tiles, 1024 wg
        mgemm_kernel<128, 128, 1, 1><<<dim3(16, 64), 512, 0, stream>>>(
            yb, w1t + (size_t)lyr * 1048576, b1 + (size_t)lyr * M_, nullptr, hb, MR, 2048, 512);
        // W2: 8192 x 512 x 2048, 64x128 tiles, 512 wg
        mgemm_kernel<64, 128, 0, 0><<<dim3(4, 128), 512, 0, stream>>>(
            hb, w2t + (size_t)lyr * 1048576, b2 + (size_t)lyr * E_, x, x, MR, 512, 2048);
    }
    ln_kernel<0><<<LNG, 256, 0, stream>>>(x, lnf_s, lnf_b, out);
}

// Round 10
// 594.539 us; speedup vs baseline: 24.3988x; 1.0130x over previous
//
#include <hip/hip_runtime.h>
#include <hip/hip_bf16.h>
#include <cmath>
#include <cstdint>
#include <cstddef>

#define B_   4
#define L_   2048
#define E_   512
#define H_   8
#define DH_  64
#define M_   2048
#define NL_  4
#define NB_  32
#define BS_  64
#define CH_  8    // max 64-key jb-blocks per attention work item

typedef short bf16x8 __attribute__((ext_vector_type(8)));
typedef short bf16x4 __attribute__((ext_vector_type(4)));
typedef float f32x4 __attribute__((ext_vector_type(4)));

__device__ __forceinline__ short f2bf(float f) {
    union { __hip_bfloat16 h; short s; } u;
    u.h = __float2bfloat16(f);
    return u.s;
}
__device__ __forceinline__ float bf2f(short s) {
    union { short s; __hip_bfloat16 h; } u;
    u.s = s;
    return __bfloat162float(u.h);
}

// ---------------------------------------------------------------------------
// BigBird masks + work partition, all at COMPILE TIME.
// ---------------------------------------------------------------------------
struct MaskTable { unsigned m[NL_][NB_]; };
struct CxMT { unsigned key[624]; int pos; };

constexpr unsigned cx_next(CxMT& st) {
    if (st.pos >= 624) {
        for (int i = 0; i < 624; ++i) {
            unsigned y = (st.key[i] & 0x80000000u) | (st.key[(i + 1) % 624] & 0x7fffffffu);
            st.key[i] = st.key[(i + 397) % 624] ^ (y >> 1) ^ ((y & 1u) ? 0x9908b0dfu : 0u);
        }
        st.pos = 0;
    }
    unsigned y = st.key[st.pos++];
    y ^= y >> 11;
    y ^= (y << 7) & 0x9d2c5680u;
    y ^= (y << 15) & 0xefc60000u;
    y ^= y >> 18;
    return y;
}
constexpr unsigned cx_interval(CxMT& st, unsigned maxv) {
    if (maxv == 0u) return 0u;
    unsigned mask = maxv;
    mask |= mask >> 1; mask |= mask >> 2; mask |= mask >> 4;
    mask |= mask >> 8; mask |= mask >> 16;
    unsigned v = cx_next(st) & mask;
    while (v > maxv) v = cx_next(st) & mask;
    return v;
}
constexpr MaskTable compute_masks() {
    MaskTable T{};
    for (int lyr = 0; lyr < NL_; ++lyr) {
        unsigned m[NB_] = {};
        for (int i = 0; i < NB_; ++i) {
            unsigned w = 1u << i;
            if (i > 0) w |= 1u << (i - 1);
            if (i < NB_ - 1) w |= 1u << (i + 1);
            w |= 1u | (1u << (NB_ - 1));
            m[i] = w;
        }
        m[0] = 0xffffffffu;
        m[NB_ - 1] = 0xffffffffu;
        CxMT st{};
        unsigned s = (unsigned)lyr;
        for (int i = 0; i < 624; ++i) {
            st.key[i] = s;
            s = 1812433253u * (s ^ (s >> 30)) + (unsigned)i + 1u;
        }
        st.pos = 624;
        for (int i = 1; i < NB_ - 1; ++i) {
            int cand[NB_] = {};
            int n = 0;
            for (int j = 0; j < NB_; ++j) {
                if (j == 0 || j == NB_ - 1 || j == i - 1 || j == i || j == i + 1) continue;
                cand[n++] = j;
            }
            for (int kk = n - 1; kk >= 1; --kk) {
                int jj = (int)cx_interval(st, (unsigned)kk);
                int tmp = cand[kk]; cand[kk] = cand[jj]; cand[jj] = tmp;
            }
            m[i] |= (1u << cand[0]) | (1u << cand[1]) | (1u << cand[2]);
        }
        for (int i = 0; i < NB_; ++i) T.m[lyr][i] = m[i];
    }
    return T;
}

struct WorkTable {
    int n_items[NL_];
    int n_cmb[NL_];
    unsigned char itm_qb[NL_][48];
    unsigned char itm_j0[NL_][48];
    unsigned char itm_jn[NL_][48];
    unsigned char itm_slot[NL_][48];   // 0xFF = direct write to o
    unsigned char cmb_qb[NL_][8];
    unsigned char cmb_slot0[NL_][8];
    unsigned char cmb_nch[NL_][8];
    unsigned char jlist[NL_][NB_][NB_];
};

constexpr WorkTable compute_work() {
    WorkTable T{};
    MaskTable M = compute_masks();
    for (int lyr = 0; lyr < NL_; ++lyr) {
        int items = 0, slots = 0, ncmb = 0;
        for (int qb = 0; qb < NB_; ++qb) {
            int cnt = 0;
            for (int j = 0; j < NB_; ++j)
                if ((M.m[lyr][qb] >> j) & 1u)
                    T.jlist[lyr][qb][cnt++] = (unsigned char)j;
            int nch = (cnt + CH_ - 1) / CH_;
            if (nch == 1) {
                T.itm_qb[lyr][items] = (unsigned char)qb;
                T.itm_j0[lyr][items] = 0;
                T.itm_jn[lyr][items] = (unsigned char)cnt;
                T.itm_slot[lyr][items] = 0xFF;
                items++;
            } else {
                T.cmb_qb[lyr][ncmb] = (unsigned char)qb;
                T.cmb_slot0[lyr][ncmb] = (unsigned char)slots;
                T.cmb_nch[lyr][ncmb] = (unsigned char)nch;
                ncmb++;
                int base = cnt / nch, rem = cnt % nch, off = 0;
                for (int c = 0; c < nch; ++c) {
                    int cl = base + (c < rem ? 1 : 0);
                    T.itm_qb[lyr][items] = (unsigned char)qb;
                    T.itm_j0[lyr][items] = (unsigned char)off;
                    T.itm_jn[lyr][items] = (unsigned char)cl;
                    T.itm_slot[lyr][items] = (unsigned char)slots;
                    items++; slots++; off += cl;
                }
            }
        }
        T.n_items[lyr] = items;
        T.n_cmb[lyr] = ncmb;
    }
    return T;
}

static constexpr WorkTable WT_HOST = compute_work();
__constant__ WorkTable g_wt = compute_work();

// ---------------------------------------------------------------------------
// Embedding + sinusoidal PE (PE reused across the 4 batches)
// ---------------------------------------------------------------------------
__global__ __launch_bounds__(256) void embed_kernel(const int* __restrict__ tokens,
                                                    const float* __restrict__ embed,
                                                    float* __restrict__ x) {
    int idx = blockIdx.x * 256 + threadIdx.x;      // < L_*E_/8 = 131072
    int l = idx >> 6;
    int e0 = (idx & 63) * 8;
    float pe[8];
    #pragma unroll
    for (int j = 0; j < 8; ++j) {
        int e = e0 + j;
        int jj = e & 255;
        float div = expf((float)jj * -0.03597789207717895f);  // -ln(10000)/256
        float arg = (float)l * div;
        pe[j] = (e < 256) ? sinf(arg) : cosf(arg);
    }
    #pragma unroll
    for (int b = 0; b < B_; ++b) {
        int tok = tokens[b * L_ + l];
        const float* em = embed + (size_t)tok * E_ + e0;
        f32x4 v0 = *(const f32x4*)em;
        f32x4 v1 = *(const f32x4*)(em + 4);
        #pragma unroll
        for (int j = 0; j < 4; ++j) { v0[j] += pe[j]; v1[j] += pe[4 + j]; }
        float* xo = x + ((size_t)(b * L_ + l)) * E_ + e0;
        *(f32x4*)xo = v0;
        *(f32x4*)(xo + 4) = v1;
    }
}

// ---------------------------------------------------------------------------
// LayerNorm: wave-per-row (4 rows per 256-thread block, no barriers).
// ---------------------------------------------------------------------------
template<int OUTBF>
__global__ __launch_bounds__(256) void ln_kernel(const float* __restrict__ x,
                                                 const float* __restrict__ gamma,
                                                 const float* __restrict__ beta,
                                                 void* __restrict__ yout) {
    int t = threadIdx.x;
    int lane = t & 63;
    int row = blockIdx.x * 4 + (t >> 6);
    const float* xr = x + (size_t)row * E_ + lane * 8;
    f32x4 a0 = *(const f32x4*)xr;
    f32x4 a1 = *(const f32x4*)(xr + 4);
    float s = a0[0] + a0[1] + a0[2] + a0[3] + a1[0] + a1[1] + a1[2] + a1[3];
    #pragma unroll
    for (int off = 1; off < 64; off <<= 1) s += __shfl_xor(s, off, 64);
    float mu = s * (1.0f / E_);
    float q = 0.0f;
    #pragma unroll
    for (int j = 0; j < 4; ++j) { float d = a0[j] - mu; q += d * d; }
    #pragma unroll
    for (int j = 0; j < 4; ++j) { float d = a1[j] - mu; q += d * d; }
    #pragma unroll
    for (int off = 1; off < 64; off <<= 1) q += __shfl_xor(q, off, 64);
    float rstd = rsqrtf(q * (1.0f / E_) + 1e-6f);
    f32x4 g0 = *(const f32x4*)(gamma + lane * 8);
    f32x4 g1 = *(const f32x4*)(gamma + lane * 8 + 4);
    f32x4 b0 = *(const f32x4*)(beta + lane * 8);
    f32x4 b1 = *(const f32x4*)(beta + lane * 8 + 4);
    float o[8];
    #pragma unroll
    for (int j = 0; j < 4; ++j) o[j] = (a0[j] - mu) * rstd * g0[j] + b0[j];
    #pragma unroll
    for (int j = 0; j < 4; ++j) o[4 + j] = (a1[j] - mu) * rstd * g1[j] + b1[j];
    if (OUTBF) {
        bf16x8 pk;
        #pragma unroll
        for (int j = 0; j < 8; ++j) pk[j] = f2bf(o[j]);
        *(bf16x8*)((short*)yout + (size_t)row * E_ + lane * 8) = pk;
    } else {
        float* yr = (float*)yout + (size_t)row * E_ + lane * 8;
        *(f32x4*)yr = f32x4{o[0], o[1], o[2], o[3]};
        *(f32x4*)(yr + 4) = f32x4{o[4], o[5], o[6], o[7]};
    }
}

// ---------------------------------------------------------------------------
// Weight convert + transpose: Wt[n][k] = bf16(W[k][n] * scale), per layer (z)
// ---------------------------------------------------------------------------
__global__ __launch_bounds__(256) void convT_kernel(const float* __restrict__ W,
                                                    short* __restrict__ Wt,
                                                    int K, int N,
                                                    size_t wStride, size_t wtStride,
                                                    float scale) {
    __shared__ float Ts[64][65];
    const float* Wl = W + blockIdx.z * wStride;
    short* Wtl = Wt + blockIdx.z * wtStride;
    int n0 = blockIdx.x * 64, k0 = blockIdx.y * 64;
    int t = threadIdx.x;
    int c = t & 63, r0 = t >> 6;
    #pragma unroll
    for (int i = 0; i < 16; ++i) {
        int r = r0 * 16 + i;
        Ts[r][c] = Wl[(size_t)(k0 + r) * N + n0 + c] * scale;
    }
    __syncthreads();
    #pragma unroll
    for (int i = 0; i < 16; ++i) {
        int r = r0 * 16 + i;
        Wtl[(size_t)(n0 + r) * K + k0 + c] = f2bf(Ts[c][r]);
    }
}

// ---------------------------------------------------------------------------
// MFMA bf16 GEMM, 2-phase double-buffered, 512 threads = 8 waves (2x4),
// XCD-aware bijective block swizzle (T1) for L2 A-panel locality.
// ---------------------------------------------------------------------------
__device__ __forceinline__ float gelu_tanh(float x) {
    float u = x * (1.5957691216057308f + 0.07135480122394604f * x * x);
    return x / (1.0f + __expf(-u));
}

template<int BM, int BN, int ACT, int OUTBF>
__global__ __launch_bounds__(512) void mgemm_kernel(const short* __restrict__ A,
                                                    const short* __restrict__ Bt,
                                                    const float* __restrict__ bias,
                                                    const float* __restrict__ res,
                                                    void* __restrict__ Cout,
                                                    int M, int N, int K) {
    constexpr int WR = 2, WC = 4;      // 8 waves
    constexpr int FM = BM / WR / 16;
    constexpr int FN = BN / WC / 16;
    constexpr int ASZ = BM * 64;
    constexpr int BSZ = BN * 64;
    constexpr int PAD = 8;
    constexpr int CW = BN + PAD;
    static_assert((size_t)(OUTBF ? BM * CW * 2 : BM * CW * 4) <= (size_t)2 * (ASZ + BSZ) * 2,
                  "epilogue stage must fit in dbuf LDS");
    __shared__ __align__(16) short smem[2 * (ASZ + BSZ)];

    int t = threadIdx.x;
    int w = t >> 6, l = t & 63;
    int l15 = l & 15, lg = l >> 4;
    int wr = w >> 2, wc = w & 3;
    int rowbase = wr * (BM / WR), colbase = wc * (BN / WC);

    int nwg = (int)(gridDim.x * gridDim.y);
    int orig = (int)(blockIdx.y * gridDim.x + blockIdx.x);
    int sid = (orig & 7) * (nwg >> 3) + (orig >> 3);
    int bx = sid % (int)gridDim.x, by = sid / (int)gridDim.x;
    int brow = by * BM, bcol = bx * BN;

    int swz = ((t & 7) ^ ((t >> 3) & 7)) * 8;
    f32x4 acc[FM][FN] = {};

    const int nt = K >> 6;

    auto stage = [&](int buf, int k0) {
        short* Ad = smem + buf * ASZ;
        short* Bd = smem + 2 * ASZ + buf * BSZ;
        #pragma unroll
        for (int it = 0; it < BM / 64; ++it) {
            int row = it * 64 + (t >> 3);
            const short* ga = A + (size_t)(brow + row) * K + k0 + swz;
            __builtin_amdgcn_global_load_lds(
                (const __attribute__((address_space(1))) unsigned int*)ga,
                (__attribute__((address_space(3))) unsigned int*)(Ad + (it * 64 + w * 8) * 64),
                16, 0, 0);
        }
        #pragma unroll
        for (int it = 0; it < BN / 64; ++it) {
            int row = it * 64 + (t >> 3);
            const short* gb = Bt + (size_t)(bcol + row) * K + k0 + swz;
            __builtin_amdgcn_global_load_lds(
                (const __attribute__((address_space(1))) unsigned int*)gb,
                (__attribute__((address_space(3))) unsigned int*)(Bd + (it * 64 + w * 8) * 64),
                16, 0, 0);
        }
    };

    stage(0, 0);
    asm volatile("s_waitcnt vmcnt(0)" ::: "memory");
    __builtin_amdgcn_s_barrier();

    int cur = 0;
    for (int kt = 0; kt < nt; ++kt) {
        if (kt + 1 < nt) stage(cur ^ 1, (kt + 1) << 6);
        const short* Ar = smem + cur * ASZ;
        const short* Br = smem + 2 * ASZ + cur * BSZ;
        #pragma unroll
        for (int kk = 0; kk < 64; kk += 32) {
            bf16x8 af[FM], bfr[FN];
            #pragma unroll
            for (int m = 0; m < FM; ++m)
                af[m] = *(const bf16x8*)(Ar + (rowbase + m * 16 + l15) * 64
                                            + (((kk >> 3) + lg) ^ (l15 & 7)) * 8);
            #pragma unroll
            for (int n = 0; n < FN; ++n)
                bfr[n] = *(const bf16x8*)(Br + (colbase + n * 16 + l15) * 64
                                             + (((kk >> 3) + lg) ^ (l15 & 7)) * 8);
            #pragma unroll
            for (int m = 0; m < FM; ++m)
                #pragma unroll
                for (int n = 0; n < FN; ++n)
                    acc[m][n] = __builtin_amdgcn_mfma_f32_16x16x32_bf16(af[m], bfr[n], acc[m][n], 0, 0, 0);
        }
        asm volatile("s_waitcnt vmcnt(0) lgkmcnt(0)" ::: "memory");
        __builtin_amdgcn_s_barrier();
        cur ^= 1;
    }

    if (OUTBF) {
        short* Cs = smem;
        #pragma unroll
        for (int m = 0; m < FM; ++m) {
            int row = rowbase + m * 16 + lg * 4;
            #pragma unroll
            for (int n = 0; n < FN; ++n) {
                int col = colbase + n * 16 + l15;
                float bv = bias ? bias[bcol + col] : 0.0f;
                #pragma unroll
                for (int r = 0; r < 4; ++r) {
                    float vv = acc[m][n][r] + bv;
                    if (ACT == 1) vv = gelu_tanh(vv);
                    Cs[(row + r) * CW + col] = f2bf(vv);
                }
            }
        }
        __syncthreads();
        #pragma unroll
        for (int it = 0; it < BM * BN / 8 / 512; ++it) {
            int c = it * 512 + t;
            int row = c / (BN / 8), c8 = c % (BN / 8);
            *(bf16x8*)((short*)Cout + (size_t)(brow + row) * N + bcol + c8 * 8) =
                *(const bf16x8*)(Cs + row * CW + c8 * 8);
        }
    } else {
        float* Cs = (float*)smem;
        #pragma unroll
        for (int m = 0; m < FM; ++m) {
            int row = rowbase + m * 16 + lg * 4;
            #pragma unroll
            for (int n = 0; n < FN; ++n) {
                int col = colbase + n * 16 + l15;
                float bv = bias ? bias[bcol + col] : 0.0f;
                #pragma unroll
                for (int r = 0; r < 4; ++r)
                    Cs[(row + r) * CW + col] = acc[m][n][r] + bv;
            }
        }
        __syncthreads();
        #pragma unroll
        for (int it = 0; it < BM * BN / 4 / 512; ++it) {
            int c = it * 512 + t;
            int row = c / (BN / 4), c4 = c % (BN / 4);
            f32x4 vv = *(const f32x4*)(Cs + row * CW + c4 * 4);
            size_t gi = (size_t)(brow + row) * N + bcol + c4 * 4;
            if (res) vv += *(const f32x4*)(res + gi);
            *(f32x4*)((float*)Cout + gi) = vv;
        }
    }
}

// ---------------------------------------------------------------------------
// Sparse block attention, MFMA bf16, KVBLK=64, swapped QK^T,
// DOUBLE-BUFFERED K/V LDS with ONE barrier per iteration:
//   iter ci: compute from buf[cur]; store regs(ci+1)->buf[cur^1];
//            issue loads(ci+2)->regs; barrier; cur^=1.
// Loads get a full iteration of latency cover; barrier count halves.
// ---------------------------------------------------------------------------
#define KSTR 72

__global__ __launch_bounds__(256) void attn_kernel(const short* __restrict__ qkv,
                                                   const int* __restrict__ tokens,
                                                   short* __restrict__ o,
                                                   float* __restrict__ pacc,
                                                   float* __restrict__ pm,
                                                   float* __restrict__ pl,
                                                   int lyr) {
    __shared__ __align__(16) short Ks[2][64][KSTR];
    __shared__ __align__(16) short Vt[2][64][KSTR];
    __shared__ __align__(16) short Pw[4][16][KSTR];
    __shared__ unsigned long long qbits_s;
    __shared__ unsigned long long kbits_s[2];

    int item = blockIdx.x, h = blockIdx.y, b = blockIdx.z;
    int qb   = g_wt.itm_qb[lyr][item];
    int j0   = g_wt.itm_j0[lyr][item];
    int jn   = g_wt.itm_jn[lyr][item];
    int slot = g_wt.itm_slot[lyr][item];
    const unsigned char* jl = g_wt.jlist[lyr][qb];

    int t = threadIdx.x;
    int l = t & 63, w = t >> 6;
    int l15 = l & 15, lg = l >> 4;
    int srow = t >> 3, sdb = t & 7;

    if (t < 64) {
        unsigned long long qm = __ballot(tokens[b * L_ + qb * 64 + t] > 0);
        if (t == 0) qbits_s = qm;
    }

    int qrow = qb * 64 + w * 16 + l15;
    const short* qp = qkv + (size_t)(b * L_ + qrow) * 1536 + h * 64;
    bf16x8 qf0 = *(const bf16x8*)(qp + lg * 8);
    bf16x8 qf1 = *(const bf16x8*)(qp + lg * 8 + 32);

    f32x4 acc[4] = {};
    float m_r = -INFINITY, l_r = 0.0f;

    bf16x8 kr0, kr1, vr0, vr1;
    int pn = 0;
    auto LOAD = [&](int ci) {
        int jb = jl[j0 + ci];
        const short* base = qkv + (size_t)(b * L_ + jb * 64 + srow) * 1536 + h * 64;
        kr0 = *(const bf16x8*)(base + 512 + sdb * 8);
        kr1 = *(const bf16x8*)(base + (size_t)32 * 1536 + 512 + sdb * 8);
        vr0 = *(const bf16x8*)(base + 1024 + sdb * 8);
        vr1 = *(const bf16x8*)(base + (size_t)32 * 1536 + 1024 + sdb * 8);
        if (t < 64) pn = tokens[b * L_ + jb * 64 + t];
    };
    auto STORE = [&](int buf) {
        *(bf16x8*)&Ks[buf][srow][sdb * 8] = kr0;
        *(bf16x8*)&Ks[buf][srow + 32][sdb * 8] = kr1;
        #pragma unroll
        for (int j = 0; j < 8; ++j) {
            Vt[buf][sdb * 8 + j][(srow & 7) + 8 * ((srow >> 3) ^ sdb)] = vr0[j];
            Vt[buf][sdb * 8 + j][(srow & 7) + 8 * (((srow >> 3) + 4) ^ sdb)] = vr1[j];
        }
        if (t < 64) {
            unsigned long long km = __ballot(pn > 0);
            if (t == 0) kbits_s[buf] = km;
        }
    };

    // prologue: fill buf0, prefetch iter 1 into regs
    LOAD(0);
    STORE(0);
    if (jn > 1) LOAD(1);
    __syncthreads();

    int cur = 0;
    for (int ci = 0; ci < jn; ++ci) {
        // ---- compute from buf[cur] ----
        f32x4 sacc[4];
        __builtin_amdgcn_s_setprio(1);
        #pragma unroll
        for (int f = 0; f < 4; ++f) {
            bf16x8 kk0 = *(const bf16x8*)&Ks[cur][16 * f + l15][lg * 8];
            bf16x8 kk1 = *(const bf16x8*)&Ks[cur][16 * f + l15][lg * 8 + 32];
            f32x4 z = {};
            z = __builtin_amdgcn_mfma_f32_16x16x32_bf16(kk0, qf0, z, 0, 0, 0);
            z = __builtin_amdgcn_mfma_f32_16x16x32_bf16(kk1, qf1, z, 0, 0, 0);
            sacc[f] = z;
        }
        __builtin_amdgcn_s_setprio(0);

        unsigned long long kb = kbits_s[cur];
        bool pq = (qbits_s >> (w * 16 + l15)) & 1ull;
        unsigned vm = 0;
        #pragma unroll
        for (int f = 0; f < 4; ++f)
            vm |= ((unsigned)(kb >> (16 * f + 4 * lg)) & 0xFu) << (4 * f);
        if (!pq) vm = 0;

        float mx = -INFINITY;
        #pragma unroll
        for (int f = 0; f < 4; ++f)
            #pragma unroll
            for (int r = 0; r < 4; ++r)
                if ((vm >> (4 * f + r)) & 1u) mx = fmaxf(mx, sacc[f][r]);
        mx = fmaxf(mx, __shfl_xor(mx, 16, 64));
        mx = fmaxf(mx, __shfl_xor(mx, 32, 64));
        float nm = fmaxf(m_r, mx);

        float pv[16];
        float sum = 0.0f;
        #pragma unroll
        for (int f = 0; f < 4; ++f)
            #pragma unroll
            for (int r = 0; r < 4; ++r) {
                float p = ((vm >> (4 * f + r)) & 1u) ? __expf(sacc[f][r] - nm) : 0.0f;
                pv[4 * f + r] = p;
                sum += p;
            }
        sum += __shfl_xor(sum, 16, 64);
        sum += __shfl_xor(sum, 32, 64);
        float al = (nm == -INFINITY) ? 1.0f : __expf(m_r - nm);
        m_r = nm;
        l_r = l_r * al + sum;

        #pragma unroll
        for (int f = 0; f < 4; ++f) {
            bf16x4 pk;
            #pragma unroll
            for (int r = 0; r < 4; ++r) pk[r] = f2bf(pv[4 * f + r]);
            *(bf16x4*)&Pw[w][l15][16 * f + 4 * lg] = pk;
        }

        float alr[4];
        #pragma unroll
        for (int r = 0; r < 4; ++r) alr[r] = __shfl(al, lg * 4 + r, 64);
        #pragma unroll
        for (int fd = 0; fd < 4; ++fd)
            #pragma unroll
            for (int r = 0; r < 4; ++r) acc[fd][r] *= alr[r];

        bf16x8 pa0 = *(const bf16x8*)&Pw[w][l15][lg * 8];
        bf16x8 pa1 = *(const bf16x8*)&Pw[w][l15][lg * 8 + 32];
        __builtin_amdgcn_s_setprio(1);
        #pragma unroll
        for (int fd = 0; fd < 4; ++fd) {
            int dd = 16 * fd + l15;
            bf16x8 vv0 = *(const bf16x8*)&Vt[cur][dd][8 * (lg ^ (dd >> 3))];
            bf16x8 vv1 = *(const bf16x8*)&Vt[cur][dd][8 * ((4 + lg) ^ (dd >> 3))];
            acc[fd] = __builtin_amdgcn_mfma_f32_16x16x32_bf16(pa0, vv0, acc[fd], 0, 0, 0);
            acc[fd] = __builtin_amdgcn_mfma_f32_16x16x32_bf16(pa1, vv1, acc[fd], 0, 0, 0);
        }
        __builtin_amdgcn_s_setprio(0);

        // ---- pipeline: store next tile, issue load for ci+2 ----
        if (ci + 1 < jn) {
            STORE(cur ^ 1);
            if (ci + 2 < jn) LOAD(ci + 2);
        }
        __syncthreads();
        cur ^= 1;
    }

    float lrr[4], mrr[4];
    #pragma unroll
    for (int r = 0; r < 4; ++r) {
        lrr[r] = __shfl(l_r, lg * 4 + r, 64);
        mrr[r] = __shfl(m_r, lg * 4 + r, 64);
    }
    unsigned long long qbits = qbits_s;

    if (slot == 0xFF) {
        #pragma unroll
        for (int r = 0; r < 4; ++r) {
            int rw = lg * 4 + r;
            int gl = qb * 64 + w * 16 + rw;
            size_t ob = (size_t)(b * L_ + gl) * 512 + h * 64 + l15;
            bool ok = ((qbits >> (w * 16 + rw)) & 1ull) && (lrr[r] > 0.0f);
            if (ok) {
                float inv = 1.0f / lrr[r];
                #pragma unroll
                for (int fd = 0; fd < 4; ++fd) o[ob + 16 * fd] = f2bf(acc[fd][r] * inv);
            } else {
                #pragma unroll
                for (int fd = 0; fd < 4; ++fd) {
                    float s = 0.0f;
                    for (int m = 0; m < L_; ++m)
                        s += bf2f(qkv[(size_t)(b * L_ + m) * 1536 + 1024 + h * 64 + 16 * fd + l15]);
                    o[ob + 16 * fd] = f2bf(s * (1.0f / L_));
                }
            }
        }
    } else {
        size_t pb = ((size_t)slot * B_ + b) * H_ + h;
        #pragma unroll
        for (int r = 0; r < 4; ++r) {
            int rloc = w * 16 + lg * 4 + r;
            #pragma unroll
            for (int fd = 0; fd < 4; ++fd)
                pacc[pb * 4096 + (size_t)rloc * 64 + 16 * fd + l15] = acc[fd][r];
            if (l15 == 0) {
                pm[pb * 64 + rloc] = mrr[r];
                pl[pb * 64 + rloc] = lrr[r];
            }
        }
    }
}

// ---------------------------------------------------------------------------
// Combine partial flash results for split q-blocks.
// ---------------------------------------------------------------------------
__global__ __launch_bounds__(256) void attn_combine(const short* __restrict__ qkv,
                                                    const int* __restrict__ tokens,
                                                    short* __restrict__ o,
                                                    const float* __restrict__ pacc,
                                                    const float* __restrict__ pm,
                                                    const float* __restrict__ pl,
                                                    int lyr) {
    int ci = blockIdx.x, h = blockIdx.y, b = blockIdx.z;
    int qb  = g_wt.cmb_qb[lyr][ci];
    int s0  = g_wt.cmb_slot0[lyr][ci];
    int nch = g_wt.cmb_nch[lyr][ci];
    int t = threadIdx.x;
    int r = t >> 2, dq = t & 3;
    int grow = qb * 64 + r;
    bool pq = tokens[b * L_ + grow] > 0;
    float M = -INFINITY;
    for (int c = 0; c < nch; ++c)
        M = fmaxf(M, pm[(((size_t)(s0 + c) * B_ + b) * H_ + h) * 64 + r]);
    size_t ob = (size_t)(b * L_ + grow) * 512 + h * 64 + dq * 16;
    if (pq && M > -1e30f) {
        float lsum = 0.0f;
        float accd[16] = {};
        for (int c = 0; c < nch; ++c) {
            size_t pb = ((size_t)(s0 + c) * B_ + b) * H_ + h;
            float wgt = __expf(pm[pb * 64 + r] - M);
            lsum += pl[pb * 64 + r] * wgt;
            const float* pa = pacc + pb * 4096 + (size_t)r * 64 + dq * 16;
            #pragma unroll
            for (int j = 0; j < 16; ++j) accd[j] += pa[j] * wgt;
        }
        float inv = 1.0f / lsum;
        #pragma unroll
        for (int j = 0; j < 16; ++j) o[ob + j] = f2bf(accd[j] * inv);
    } else {
        #pragma unroll
        for (int j = 0; j < 16; ++j) {
            float s = 0.0f;
            for (int m = 0; m < L_; ++m)
                s += bf2f(qkv[(size_t)(b * L_ + m) * 1536 + 1024 + h * 64 + dq * 16 + j]);
            o[ob + j] = f2bf(s * (1.0f / L_));
        }
    }
}

// ---------------------------------------------------------------------------
// Launch
// ---------------------------------------------------------------------------
extern "C" void kernel_launch(void* const* d_in, const int* in_sizes, int n_in,
                              void* d_out, int out_size, void* d_ws, size_t ws_size,
                              hipStream_t stream) {
    (void)in_sizes; (void)n_in; (void)out_size; (void)ws_size;
    const int*   tokens = (const int*)d_in[0];
    const float* embed  = (const float*)d_in[1];
    const float* ln1_s  = (const float*)d_in[2];
    const float* ln1_b  = (const float*)d_in[3];
    const float* wq     = (const float*)d_in[4];
    const float* wk     = (const float*)d_in[5];
    const float* wv     = (const float*)d_in[6];
    const float* wo     = (const float*)d_in[7];
    const float* ln2_s  = (const float*)d_in[8];
    const float* ln2_b  = (const float*)d_in[9];
    const float* w1     = (const float*)d_in[10];
    const float* b1     = (const float*)d_in[11];
    const float* w2     = (const float*)d_in[12];
    const float* b2     = (const float*)d_in[13];
    const float* lnf_s  = (const float*)d_in[14];
    const float* lnf_b  = (const float*)d_in[15];
    float* out = (float*)d_out;

    const size_t BLE = (size_t)B_ * L_ * E_;              // 4,194,304
    char* ws = (char*)d_ws;
    float* x    = (float*)ws;                             // 16 MB
    short* yb   = (short*)(x + BLE);                      //  8 MB
    short* R    = yb + BLE;                               // 32 MB (qkv+ob / hb)
    short* qkv  = R;
    short* ob   = R + 3 * BLE;
    short* hb   = R;
    short* qkvt = R + 4 * BLE;                            // bf16 weights
    short* wot  = qkvt + (size_t)NL_ * 1536 * 512;
    short* w1t  = wot + (size_t)NL_ * 512 * 512;
    short* w2t  = w1t + (size_t)NL_ * 2048 * 512;
    float* pacc = (float*)(w2t + (size_t)NL_ * 512 * 2048);   // 8 slots x B x H x 4096 f32
    float* pm   = pacc + (size_t)8 * B_ * H_ * 4096;
    float* pl   = pm + (size_t)8 * B_ * H_ * 64;

    convT_kernel<<<dim3(8, 8, NL_), 256, 0, stream>>>(wq, qkvt,          512, 512, 262144, 786432, 0.125f);
    convT_kernel<<<dim3(8, 8, NL_), 256, 0, stream>>>(wk, qkvt + 262144, 512, 512, 262144, 786432, 1.0f);
    convT_kernel<<<dim3(8, 8, NL_), 256, 0, stream>>>(wv, qkvt + 524288, 512, 512, 262144, 786432, 1.0f);
    convT_kernel<<<dim3(8, 8, NL_), 256, 0, stream>>>(wo, wot,           512, 512, 262144, 262144, 1.0f);
    convT_kernel<<<dim3(32, 8, NL_), 256, 0, stream>>>(w1, w1t,          512, 2048, 1048576, 1048576, 1.0f);
    convT_kernel<<<dim3(8, 32, NL_), 256, 0, stream>>>(w2, w2t,          2048, 512, 1048576, 1048576, 1.0f);

    embed_kernel<<<(L_ * E_ / 8) / 256, 256, 0, stream>>>(tokens, embed, x);

    const int MR = B_ * L_;
    const int LNG = MR / 4;                                // 2048 blocks
    for (int lyr = 0; lyr < NL_; ++lyr) {
        ln_kernel<1><<<LNG, 256, 0, stream>>>(x, ln1_s + lyr * E_, ln1_b + lyr * E_, yb);
        mgemm_kernel<128, 128, 0, 1><<<dim3(12, 64), 512, 0, stream>>>(
            yb, qkvt + (size_t)lyr * 786432, nullptr, nullptr, qkv, MR, 1536, 512);
        attn_kernel<<<dim3(WT_HOST.n_items[lyr], H_, B_), 256, 0, stream>>>(
            qkv, tokens, ob, pacc, pm, pl, lyr);
        attn_combine<<<dim3(WT_HOST.n_cmb[lyr], H_, B_), 256, 0, stream>>>(
            qkv, tokens, ob, pacc, pm, pl, lyr);
        mgemm_kernel<64, 128, 0, 0><<<dim3(4, 128), 512, 0, stream>>>(
            ob, wot + (size_t)lyr * 262144, nullptr, x, x, MR, 512, 512);
        ln_kernel<1><<<LNG, 256, 0, stream>>>(x, ln2_s + lyr * E_, ln2_b + lyr * E_, yb);
        mgemm_kernel<128, 128, 1, 1><<<dim3(16, 64), 512, 0, stream>>>(
            yb, w1t + (size_t)lyr * 1048576, b1 + (size_t)lyr * M_, nullptr, hb, MR, 2048, 512);
        mgemm_kernel<64, 128, 0, 0><<<dim3(4, 128), 512, 0, stream>>>(
            hb, w2t + (size_t)lyr * 1048576, b2 + (size_t)lyr * E_, x, x, MR, 512, 2048);
    }
    ln_kernel<0><<<LNG, 256, 0, stream>>>(x, lnf_s, lnf_b, out);
}

// Round 12
// 588.628 us; speedup vs baseline: 24.6438x; 1.0100x over previous
//
#include <hip/hip_runtime.h>
#include <hip/hip_bf16.h>
#include <cmath>
#include <cstdint>
#include <cstddef>

#define B_   4
#define L_   2048
#define E_   512
#define H_   8
#define DH_  64
#define M_   2048
#define NL_  4
#define NB_  32
#define BS_  64
#define CH_  8    // max 64-key jb-blocks per attention work item

typedef short bf16x8 __attribute__((ext_vector_type(8)));
typedef short bf16x4 __attribute__((ext_vector_type(4)));
typedef float f32x4 __attribute__((ext_vector_type(4)));

__device__ __forceinline__ short f2bf(float f) {
    union { __hip_bfloat16 h; short s; } u;
    u.h = __float2bfloat16(f);
    return u.s;
}
__device__ __forceinline__ float bf2f(short s) {
    union { short s; __hip_bfloat16 h; } u;
    u.s = s;
    return __bfloat162float(u.h);
}

// ---------------------------------------------------------------------------
// BigBird masks + work partition, all at COMPILE TIME.
// ---------------------------------------------------------------------------
struct MaskTable { unsigned m[NL_][NB_]; };
struct CxMT { unsigned key[624]; int pos; };

constexpr unsigned cx_next(CxMT& st) {
    if (st.pos >= 624) {
        for (int i = 0; i < 624; ++i) {
            unsigned y = (st.key[i] & 0x80000000u) | (st.key[(i + 1) % 624] & 0x7fffffffu);
            st.key[i] = st.key[(i + 397) % 624] ^ (y >> 1) ^ ((y & 1u) ? 0x9908b0dfu : 0u);
        }
        st.pos = 0;
    }
    unsigned y = st.key[st.pos++];
    y ^= y >> 11;
    y ^= (y << 7) & 0x9d2c5680u;
    y ^= (y << 15) & 0xefc60000u;
    y ^= y >> 18;
    return y;
}
constexpr unsigned cx_interval(CxMT& st, unsigned maxv) {
    if (maxv == 0u) return 0u;
    unsigned mask = maxv;
    mask |= mask >> 1; mask |= mask >> 2; mask |= mask >> 4;
    mask |= mask >> 8; mask |= mask >> 16;
    unsigned v = cx_next(st) & mask;
    while (v > maxv) v = cx_next(st) & mask;
    return v;
}
constexpr MaskTable compute_masks() {
    MaskTable T{};
    for (int lyr = 0; lyr < NL_; ++lyr) {
        unsigned m[NB_] = {};
        for (int i = 0; i < NB_; ++i) {
            unsigned w = 1u << i;
            if (i > 0) w |= 1u << (i - 1);
            if (i < NB_ - 1) w |= 1u << (i + 1);
            w |= 1u | (1u << (NB_ - 1));
            m[i] = w;
        }
        m[0] = 0xffffffffu;
        m[NB_ - 1] = 0xffffffffu;
        CxMT st{};
        unsigned s = (unsigned)lyr;
        for (int i = 0; i < 624; ++i) {
            st.key[i] = s;
            s = 1812433253u * (s ^ (s >> 30)) + (unsigned)i + 1u;
        }
        st.pos = 624;
        for (int i = 1; i < NB_ - 1; ++i) {
            int cand[NB_] = {};
            int n = 0;
            for (int j = 0; j < NB_; ++j) {
                if (j == 0 || j == NB_ - 1 || j == i - 1 || j == i || j == i + 1) continue;
                cand[n++] = j;
            }
            for (int kk = n - 1; kk >= 1; --kk) {
                int jj = (int)cx_interval(st, (unsigned)kk);
                int tmp = cand[kk]; cand[kk] = cand[jj]; cand[jj] = tmp;
            }
            m[i] |= (1u << cand[0]) | (1u << cand[1]) | (1u << cand[2]);
        }
        for (int i = 0; i < NB_; ++i) T.m[lyr][i] = m[i];
    }
    return T;
}

struct WorkTable {
    int n_items[NL_];
    int n_cmb[NL_];
    unsigned char itm_qb[NL_][48];
    unsigned char itm_j0[NL_][48];
    unsigned char itm_jn[NL_][48];
    unsigned char itm_slot[NL_][48];   // 0xFF = direct write to o
    unsigned char cmb_qb[NL_][8];
    unsigned char cmb_slot0[NL_][8];
    unsigned char cmb_nch[NL_][8];
    unsigned char jlist[NL_][NB_][NB_];
};

constexpr WorkTable compute_work() {
    WorkTable T{};
    MaskTable M = compute_masks();
    for (int lyr = 0; lyr < NL_; ++lyr) {
        int items = 0, slots = 0, ncmb = 0;
        for (int qb = 0; qb < NB_; ++qb) {
            int cnt = 0;
            for (int j = 0; j < NB_; ++j)
                if ((M.m[lyr][qb] >> j) & 1u)
                    T.jlist[lyr][qb][cnt++] = (unsigned char)j;
            int nch = (cnt + CH_ - 1) / CH_;
            if (nch == 1) {
                T.itm_qb[lyr][items] = (unsigned char)qb;
                T.itm_j0[lyr][items] = 0;
                T.itm_jn[lyr][items] = (unsigned char)cnt;
                T.itm_slot[lyr][items] = 0xFF;
                items++;
            } else {
                T.cmb_qb[lyr][ncmb] = (unsigned char)qb;
                T.cmb_slot0[lyr][ncmb] = (unsigned char)slots;
                T.cmb_nch[lyr][ncmb] = (unsigned char)nch;
                ncmb++;
                int base = cnt / nch, rem = cnt % nch, off = 0;
                for (int c = 0; c < nch; ++c) {
                    int cl = base + (c < rem ? 1 : 0);
                    T.itm_qb[lyr][items] = (unsigned char)qb;
                    T.itm_j0[lyr][items] = (unsigned char)off;
                    T.itm_jn[lyr][items] = (unsigned char)cl;
                    T.itm_slot[lyr][items] = (unsigned char)slots;
                    items++; slots++; off += cl;
                }
            }
        }
        T.n_items[lyr] = items;
        T.n_cmb[lyr] = ncmb;
    }
    return T;
}

static constexpr WorkTable WT_HOST = compute_work();
__constant__ WorkTable g_wt = compute_work();

// ---------------------------------------------------------------------------
// Embedding + sinusoidal PE (PE reused across the 4 batches)
// ---------------------------------------------------------------------------
__global__ __launch_bounds__(256) void embed_kernel(const int* __restrict__ tokens,
                                                    const float* __restrict__ embed,
                                                    float* __restrict__ x) {
    int idx = blockIdx.x * 256 + threadIdx.x;      // < L_*E_/8 = 131072
    int l = idx >> 6;
    int e0 = (idx & 63) * 8;
    float pe[8];
    #pragma unroll
    for (int j = 0; j < 8; ++j) {
        int e = e0 + j;
        int jj = e & 255;
        float div = expf((float)jj * -0.03597789207717895f);  // -ln(10000)/256
        float arg = (float)l * div;
        pe[j] = (e < 256) ? sinf(arg) : cosf(arg);
    }
    #pragma unroll
    for (int b = 0; b < B_; ++b) {
        int tok = tokens[b * L_ + l];
        const float* em = embed + (size_t)tok * E_ + e0;
        f32x4 v0 = *(const f32x4*)em;
        f32x4 v1 = *(const f32x4*)(em + 4);
        #pragma unroll
        for (int j = 0; j < 4; ++j) { v0[j] += pe[j]; v1[j] += pe[4 + j]; }
        float* xo = x + ((size_t)(b * L_ + l)) * E_ + e0;
        *(f32x4*)xo = v0;
        *(f32x4*)(xo + 4) = v1;
    }
}

// ---------------------------------------------------------------------------
// LayerNorm: wave-per-row (4 rows per 256-thread block, no barriers).
// ---------------------------------------------------------------------------
template<int OUTBF>
__global__ __launch_bounds__(256) void ln_kernel(const float* __restrict__ x,
                                                 const float* __restrict__ gamma,
                                                 const float* __restrict__ beta,
                                                 void* __restrict__ yout) {
    int t = threadIdx.x;
    int lane = t & 63;
    int row = blockIdx.x * 4 + (t >> 6);
    const float* xr = x + (size_t)row * E_ + lane * 8;
    f32x4 a0 = *(const f32x4*)xr;
    f32x4 a1 = *(const f32x4*)(xr + 4);
    float s = a0[0] + a0[1] + a0[2] + a0[3] + a1[0] + a1[1] + a1[2] + a1[3];
    #pragma unroll
    for (int off = 1; off < 64; off <<= 1) s += __shfl_xor(s, off, 64);
    float mu = s * (1.0f / E_);
    float q = 0.0f;
    #pragma unroll
    for (int j = 0; j < 4; ++j) { float d = a0[j] - mu; q += d * d; }
    #pragma unroll
    for (int j = 0; j < 4; ++j) { float d = a1[j] - mu; q += d * d; }
    #pragma unroll
    for (int off = 1; off < 64; off <<= 1) q += __shfl_xor(q, off, 64);
    float rstd = rsqrtf(q * (1.0f / E_) + 1e-6f);
    f32x4 g0 = *(const f32x4*)(gamma + lane * 8);
    f32x4 g1 = *(const f32x4*)(gamma + lane * 8 + 4);
    f32x4 b0 = *(const f32x4*)(beta + lane * 8);
    f32x4 b1 = *(const f32x4*)(beta + lane * 8 + 4);
    float o[8];
    #pragma unroll
    for (int j = 0; j < 4; ++j) o[j] = (a0[j] - mu) * rstd * g0[j] + b0[j];
    #pragma unroll
    for (int j = 0; j < 4; ++j) o[4 + j] = (a1[j] - mu) * rstd * g1[j] + b1[j];
    if (OUTBF) {
        bf16x8 pk;
        #pragma unroll
        for (int j = 0; j < 8; ++j) pk[j] = f2bf(o[j]);
        *(bf16x8*)((short*)yout + (size_t)row * E_ + lane * 8) = pk;
    } else {
        float* yr = (float*)yout + (size_t)row * E_ + lane * 8;
        *(f32x4*)yr = f32x4{o[0], o[1], o[2], o[3]};
        *(f32x4*)(yr + 4) = f32x4{o[4], o[5], o[6], o[7]};
    }
}

// ---------------------------------------------------------------------------
// Weight convert + transpose: Wt[n][k] = bf16(W[k][n] * scale), per layer (z)
// ---------------------------------------------------------------------------
__global__ __launch_bounds__(256) void convT_kernel(const float* __restrict__ W,
                                                    short* __restrict__ Wt,
                                                    int K, int N,
                                                    size_t wStride, size_t wtStride,
                                                    float scale) {
    __shared__ float Ts[64][65];
    const float* Wl = W + blockIdx.z * wStride;
    short* Wtl = Wt + blockIdx.z * wtStride;
    int n0 = blockIdx.x * 64, k0 = blockIdx.y * 64;
    int t = threadIdx.x;
    int c = t & 63, r0 = t >> 6;
    #pragma unroll
    for (int i = 0; i < 16; ++i) {
        int r = r0 * 16 + i;
        Ts[r][c] = Wl[(size_t)(k0 + r) * N + n0 + c] * scale;
    }
    __syncthreads();
    #pragma unroll
    for (int i = 0; i < 16; ++i) {
        int r = r0 * 16 + i;
        Wtl[(size_t)(n0 + r) * K + k0 + c] = f2bf(Ts[c][r]);
    }
}

// ---------------------------------------------------------------------------
// MFMA bf16 GEMM, 2-phase double-buffered (r10-proven schedule):
//   stage(t+1) issued BEFORE compute(t); single s_waitcnt vmcnt(0) lgkmcnt(0)
//   (with "memory" clobber) + raw s_barrier per K-iter.
// 512 threads = 8 waves (2x4); XCD-aware bijective block swizzle (T1);
// T2 XOR swizzle on LDS; LDS-staged epilogue.
// ---------------------------------------------------------------------------
__device__ __forceinline__ float gelu_tanh(float x) {
    float u = x * (1.5957691216057308f + 0.07135480122394604f * x * x);
    return x / (1.0f + __expf(-u));
}

template<int BM, int BN, int ACT, int OUTBF>
__global__ __launch_bounds__(512) void mgemm_kernel(const short* __restrict__ A,
                                                    const short* __restrict__ Bt,
                                                    const float* __restrict__ bias,
                                                    const float* __restrict__ res,
                                                    void* __restrict__ Cout,
                                                    int M, int N, int K) {
    constexpr int WR = 2, WC = 4;      // 8 waves
    constexpr int FM = BM / WR / 16;
    constexpr int FN = BN / WC / 16;
    constexpr int ASZ = BM * 64;
    constexpr int BSZ = BN * 64;
    constexpr int PAD = 8;
    constexpr int CW = BN + PAD;
    static_assert((size_t)(OUTBF ? BM * CW * 2 : BM * CW * 4) <= (size_t)2 * (ASZ + BSZ) * 2,
                  "epilogue stage must fit in dbuf LDS");
    __shared__ __align__(16) short smem[2 * (ASZ + BSZ)];

    int t = threadIdx.x;
    int w = t >> 6, l = t & 63;
    int l15 = l & 15, lg = l >> 4;
    int wr = w >> 2, wc = w & 3;
    int rowbase = wr * (BM / WR), colbase = wc * (BN / WC);

    int nwg = (int)(gridDim.x * gridDim.y);
    int orig = (int)(blockIdx.y * gridDim.x + blockIdx.x);
    int sid = (orig & 7) * (nwg >> 3) + (orig >> 3);
    int bx = sid % (int)gridDim.x, by = sid / (int)gridDim.x;
    int brow = by * BM, bcol = bx * BN;

    int swz = ((t & 7) ^ ((t >> 3) & 7)) * 8;
    f32x4 acc[FM][FN] = {};

    const int nt = K >> 6;

    auto stage = [&](int buf, int k0) {
        short* Ad = smem + buf * ASZ;
        short* Bd = smem + 2 * ASZ + buf * BSZ;
        #pragma unroll
        for (int it = 0; it < BM / 64; ++it) {
            int row = it * 64 + (t >> 3);
            const short* ga = A + (size_t)(brow + row) * K + k0 + swz;
            __builtin_amdgcn_global_load_lds(
                (const __attribute__((address_space(1))) unsigned int*)ga,
                (__attribute__((address_space(3))) unsigned int*)(Ad + (it * 64 + w * 8) * 64),
                16, 0, 0);
        }
        #pragma unroll
        for (int it = 0; it < BN / 64; ++it) {
            int row = it * 64 + (t >> 3);
            const short* gb = Bt + (size_t)(bcol + row) * K + k0 + swz;
            __builtin_amdgcn_global_load_lds(
                (const __attribute__((address_space(1))) unsigned int*)gb,
                (__attribute__((address_space(3))) unsigned int*)(Bd + (it * 64 + w * 8) * 64),
                16, 0, 0);
        }
    };

    stage(0, 0);
    asm volatile("s_waitcnt vmcnt(0)" ::: "memory");
    __builtin_amdgcn_s_barrier();

    int cur = 0;
    for (int kt = 0; kt < nt; ++kt) {
        if (kt + 1 < nt) stage(cur ^ 1, (kt + 1) << 6);
        const short* Ar = smem + cur * ASZ;
        const short* Br = smem + 2 * ASZ + cur * BSZ;
        #pragma unroll
        for (int kk = 0; kk < 64; kk += 32) {
            bf16x8 af[FM], bfr[FN];
            #pragma unroll
            for (int m = 0; m < FM; ++m)
                af[m] = *(const bf16x8*)(Ar + (rowbase + m * 16 + l15) * 64
                                            + (((kk >> 3) + lg) ^ (l15 & 7)) * 8);
            #pragma unroll
            for (int n = 0; n < FN; ++n)
                bfr[n] = *(const bf16x8*)(Br + (colbase + n * 16 + l15) * 64
                                             + (((kk >> 3) + lg) ^ (l15 & 7)) * 8);
            #pragma unroll
            for (int m = 0; m < FM; ++m)
                #pragma unroll
                for (int n = 0; n < FN; ++n)
                    acc[m][n] = __builtin_amdgcn_mfma_f32_16x16x32_bf16(af[m], bfr[n], acc[m][n], 0, 0, 0);
        }
        asm volatile("s_waitcnt vmcnt(0) lgkmcnt(0)" ::: "memory");
        __builtin_amdgcn_s_barrier();
        cur ^= 1;
    }

    if (OUTBF) {
        short* Cs = smem;
        #pragma unroll
        for (int m = 0; m < FM; ++m) {
            int row = rowbase + m * 16 + lg * 4;
            #pragma unroll
            for (int n = 0; n < FN; ++n) {
                int col = colbase + n * 16 + l15;
                float bv = bias ? bias[bcol + col] : 0.0f;
                #pragma unroll
                for (int r = 0; r < 4; ++r) {
                    float vv = acc[m][n][r] + bv;
                    if (ACT == 1) vv = gelu_tanh(vv);
                    Cs[(row + r) * CW + col] = f2bf(vv);
                }
            }
        }
        __syncthreads();
        #pragma unroll
        for (int it = 0; it < BM * BN / 8 / 512; ++it) {
            int c = it * 512 + t;
            int row = c / (BN / 8), c8 = c % (BN / 8);
            *(bf16x8*)((short*)Cout + (size_t)(brow + row) * N + bcol + c8 * 8) =
                *(const bf16x8*)(Cs + row * CW + c8 * 8);
        }
    } else {
        float* Cs = (float*)smem;
        #pragma unroll
        for (int m = 0; m < FM; ++m) {
            int row = rowbase + m * 16 + lg * 4;
            #pragma unroll
            for (int n = 0; n < FN; ++n) {
                int col = colbase + n * 16 + l15;
                float bv = bias ? bias[bcol + col] : 0.0f;
                #pragma unroll
                for (int r = 0; r < 4; ++r)
                    Cs[(row + r) * CW + col] = acc[m][n][r] + bv;
            }
        }
        __syncthreads();
        #pragma unroll
        for (int it = 0; it < BM * BN / 4 / 512; ++it) {
            int c = it * 512 + t;
            int row = c / (BN / 4), c4 = c % (BN / 4);
            f32x4 vv = *(const f32x4*)(Cs + row * CW + c4 * 4);
            size_t gi = (size_t)(brow + row) * N + bcol + c4 * 4;
            if (res) vv += *(const f32x4*)(res + gi);
            *(f32x4*)((float*)Cout + gi) = vv;
        }
    }
}

// ---------------------------------------------------------------------------
// Sparse block attention, MFMA bf16, KVBLK=64, swapped QK^T, dbuf K/V LDS.
// Grid is FLAT 1-D: id = (b*H + h)*n_items + item, with bijective XCD chunk
// swizzle so all items sharing (b,h) land on one XCD -> K/V L2 hits.
// ---------------------------------------------------------------------------
#define KSTR 72

__global__ __launch_bounds__(256) void attn_kernel(const short* __restrict__ qkv,
                                                   const int* __restrict__ tokens,
                                                   short* __restrict__ o,
                                                   float* __restrict__ pacc,
                                                   float* __restrict__ pm,
                                                   float* __restrict__ pl,
                                                   int lyr) {
    __shared__ __align__(16) short Ks[2][64][KSTR];
    __shared__ __align__(16) short Vt[2][64][KSTR];
    __shared__ __align__(16) short Pw[4][16][KSTR];
    __shared__ unsigned long long qbits_s;
    __shared__ unsigned long long kbits_s[2];

    int nit = g_wt.n_items[lyr];
    int nwg = (int)gridDim.x;                    // nit * 32, divisible by 8
    int orig = (int)blockIdx.x;
    int sid = (orig & 7) * (nwg >> 3) + (orig >> 3);
    int item = sid % nit;
    int bh = sid / nit;
    int h = bh & 7, b = bh >> 3;

    int qb   = g_wt.itm_qb[lyr][item];
    int j0   = g_wt.itm_j0[lyr][item];
    int jn   = g_wt.itm_jn[lyr][item];
    int slot = g_wt.itm_slot[lyr][item];
    const unsigned char* jl = g_wt.jlist[lyr][qb];

    int t = threadIdx.x;
    int l = t & 63, w = t >> 6;
    int l15 = l & 15, lg = l >> 4;
    int srow = t >> 3, sdb = t & 7;

    if (t < 64) {
        unsigned long long qm = __ballot(tokens[b * L_ + qb * 64 + t] > 0);
        if (t == 0) qbits_s = qm;
    }

    int qrow = qb * 64 + w * 16 + l15;
    const short* qp = qkv + (size_t)(b * L_ + qrow) * 1536 + h * 64;
    bf16x8 qf0 = *(const bf16x8*)(qp + lg * 8);
    bf16x8 qf1 = *(const bf16x8*)(qp + lg * 8 + 32);

    f32x4 acc[4] = {};
    float m_r = -INFINITY, l_r = 0.0f;

    bf16x8 kr0, kr1, vr0, vr1;
    int pn = 0;
    auto LOAD = [&](int ci) {
        int jb = jl[j0 + ci];
        const short* base = qkv + (size_t)(b * L_ + jb * 64 + srow) * 1536 + h * 64;
        kr0 = *(const bf16x8*)(base + 512 + sdb * 8);
        kr1 = *(const bf16x8*)(base + (size_t)32 * 1536 + 512 + sdb * 8);
        vr0 = *(const bf16x8*)(base + 1024 + sdb * 8);
        vr1 = *(const bf16x8*)(base + (size_t)32 * 1536 + 1024 + sdb * 8);
        if (t < 64) pn = tokens[b * L_ + jb * 64 + t];
    };
    auto STORE = [&](int buf) {
        *(bf16x8*)&Ks[buf][srow][sdb * 8] = kr0;
        *(bf16x8*)&Ks[buf][srow + 32][sdb * 8] = kr1;
        #pragma unroll
        for (int j = 0; j < 8; ++j) {
            Vt[buf][sdb * 8 + j][(srow & 7) + 8 * ((srow >> 3) ^ sdb)] = vr0[j];
            Vt[buf][sdb * 8 + j][(srow & 7) + 8 * (((srow >> 3) + 4) ^ sdb)] = vr1[j];
        }
        if (t < 64) {
            unsigned long long km = __ballot(pn > 0);
            if (t == 0) kbits_s[buf] = km;
        }
    };

    LOAD(0);
    STORE(0);
    if (jn > 1) LOAD(1);
    __syncthreads();

    int cur = 0;
    for (int ci = 0; ci < jn; ++ci) {
        f32x4 sacc[4];
        __builtin_amdgcn_s_setprio(1);
        #pragma unroll
        for (int f = 0; f < 4; ++f) {
            bf16x8 kk0 = *(const bf16x8*)&Ks[cur][16 * f + l15][lg * 8];
            bf16x8 kk1 = *(const bf16x8*)&Ks[cur][16 * f + l15][lg * 8 + 32];
            f32x4 z = {};
            z = __builtin_amdgcn_mfma_f32_16x16x32_bf16(kk0, qf0, z, 0, 0, 0);
            z = __builtin_amdgcn_mfma_f32_16x16x32_bf16(kk1, qf1, z, 0, 0, 0);
            sacc[f] = z;
        }
        __builtin_amdgcn_s_setprio(0);

        unsigned long long kb = kbits_s[cur];
        bool pq = (qbits_s >> (w * 16 + l15)) & 1ull;
        unsigned vm = 0;
        #pragma unroll
        for (int f = 0; f < 4; ++f)
            vm |= ((unsigned)(kb >> (16 * f + 4 * lg)) & 0xFu) << (4 * f);
        if (!pq) vm = 0;

        float mx = -INFINITY;
        #pragma unroll
        for (int f = 0; f < 4; ++f)
            #pragma unroll
            for (int r = 0; r < 4; ++r)
                if ((vm >> (4 * f + r)) & 1u) mx = fmaxf(mx, sacc[f][r]);
        mx = fmaxf(mx, __shfl_xor(mx, 16, 64));
        mx = fmaxf(mx, __shfl_xor(mx, 32, 64));
        float nm = fmaxf(m_r, mx);

        float pv[16];
        float sum = 0.0f;
        #pragma unroll
        for (int f = 0; f < 4; ++f)
            #pragma unroll
            for (int r = 0; r < 4; ++r) {
                float p = ((vm >> (4 * f + r)) & 1u) ? __expf(sacc[f][r] - nm) : 0.0f;
                pv[4 * f + r] = p;
                sum += p;
            }
        sum += __shfl_xor(sum, 16, 64);
        sum += __shfl_xor(sum, 32, 64);
        float al = (nm == -INFINITY) ? 1.0f : __expf(m_r - nm);
        m_r = nm;
        l_r = l_r * al + sum;

        #pragma unroll
        for (int f = 0; f < 4; ++f) {
            bf16x4 pk;
            #pragma unroll
            for (int r = 0; r < 4; ++r) pk[r] = f2bf(pv[4 * f + r]);
            *(bf16x4*)&Pw[w][l15][16 * f + 4 * lg] = pk;
        }

        float alr[4];
        #pragma unroll
        for (int r = 0; r < 4; ++r) alr[r] = __shfl(al, lg * 4 + r, 64);
        #pragma unroll
        for (int fd = 0; fd < 4; ++fd)
            #pragma unroll
            for (int r = 0; r < 4; ++r) acc[fd][r] *= alr[r];

        bf16x8 pa0 = *(const bf16x8*)&Pw[w][l15][lg * 8];
        bf16x8 pa1 = *(const bf16x8*)&Pw[w][l15][lg * 8 + 32];
        __builtin_amdgcn_s_setprio(1);
        #pragma unroll
        for (int fd = 0; fd < 4; ++fd) {
            int dd = 16 * fd + l15;
            bf16x8 vv0 = *(const bf16x8*)&Vt[cur][dd][8 * (lg ^ (dd >> 3))];
            bf16x8 vv1 = *(const bf16x8*)&Vt[cur][dd][8 * ((4 + lg) ^ (dd >> 3))];
            acc[fd] = __builtin_amdgcn_mfma_f32_16x16x32_bf16(pa0, vv0, acc[fd], 0, 0, 0);
            acc[fd] = __builtin_amdgcn_mfma_f32_16x16x32_bf16(pa1, vv1, acc[fd], 0, 0, 0);
        }
        __builtin_amdgcn_s_setprio(0);

        if (ci + 1 < jn) {
            STORE(cur ^ 1);
            if (ci + 2 < jn) LOAD(ci + 2);
        }
        __syncthreads();
        cur ^= 1;
    }

    float lrr[4], mrr[4];
    #pragma unroll
    for (int r = 0; r < 4; ++r) {
        lrr[r] = __shfl(l_r, lg * 4 + r, 64);
        mrr[r] = __shfl(m_r, lg * 4 + r, 64);
    }
    unsigned long long qbits = qbits_s;

    if (slot == 0xFF) {
        #pragma unroll
        for (int r = 0; r < 4; ++r) {
            int rw = lg * 4 + r;
            int gl = qb * 64 + w * 16 + rw;
            size_t ob = (size_t)(b * L_ + gl) * 512 + h * 64 + l15;
            bool ok = ((qbits >> (w * 16 + rw)) & 1ull) && (lrr[r] > 0.0f);
            if (ok) {
                float inv = 1.0f / lrr[r];
                #pragma unroll
                for (int fd = 0; fd < 4; ++fd) o[ob + 16 * fd] = f2bf(acc[fd][r] * inv);
            } else {
                #pragma unroll
                for (int fd = 0; fd < 4; ++fd) {
                    float s = 0.0f;
                    for (int m = 0; m < L_; ++m)
                        s += bf2f(qkv[(size_t)(b * L_ + m) * 1536 + 1024 + h * 64 + 16 * fd + l15]);
                    o[ob + 16 * fd] = f2bf(s * (1.0f / L_));
                }
            }
        }
    } else {
        size_t pb = ((size_t)slot * B_ + b) * H_ + h;
        #pragma unroll
        for (int r = 0; r < 4; ++r) {
            int rloc = w * 16 + lg * 4 + r;
            #pragma unroll
            for (int fd = 0; fd < 4; ++fd)
                pacc[pb * 4096 + (size_t)rloc * 64 + 16 * fd + l15] = acc[fd][r];
            if (l15 == 0) {
                pm[pb * 64 + rloc] = mrr[r];
                pl[pb * 64 + rloc] = lrr[r];
            }
        }
    }
}

// ---------------------------------------------------------------------------
// Combine partial flash results for split q-blocks.
// ---------------------------------------------------------------------------
__global__ __launch_bounds__(256) void attn_combine(const short* __restrict__ qkv,
                                                    const int* __restrict__ tokens,
                                                    short* __restrict__ o,
                                                    const float* __restrict__ pacc,
                                                    const float* __restrict__ pm,
                                                    const float* __restrict__ pl,
                                                    int lyr) {
    int ci = blockIdx.x, h = blockIdx.y, b = blockIdx.z;
    int qb  = g_wt.cmb_qb[lyr][ci];
    int s0  = g_wt.cmb_slot0[lyr][ci];
    int nch = g_wt.cmb_nch[lyr][ci];
    int t = threadIdx.x;
    int r = t >> 2, dq = t & 3;
    int grow = qb * 64 + r;
    bool pq = tokens[b * L_ + grow] > 0;
    float M = -INFINITY;
    for (int c = 0; c < nch; ++c)
        M = fmaxf(M, pm[(((size_t)(s0 + c) * B_ + b) * H_ + h) * 64 + r]);
    size_t ob = (size_t)(b * L_ + grow) * 512 + h * 64 + dq * 16;
    if (pq && M > -1e30f) {
        float lsum = 0.0f;
        float accd[16] = {};
        for (int c = 0; c < nch; ++c) {
            size_t pb = ((size_t)(s0 + c) * B_ + b) * H_ + h;
            float wgt = __expf(pm[pb * 64 + r] - M);
            lsum += pl[pb * 64 + r] * wgt;
            const float* pa = pacc + pb * 4096 + (size_t)r * 64 + dq * 16;
            #pragma unroll
            for (int j = 0; j < 16; ++j) accd[j] += pa[j] * wgt;
        }
        float inv = 1.0f / lsum;
        #pragma unroll
        for (int j = 0; j < 16; ++j) o[ob + j] = f2bf(accd[j] * inv);
    } else {
        #pragma unroll
        for (int j = 0; j < 16; ++j) {
            float s = 0.0f;
            for (int m = 0; m < L_; ++m)
                s += bf2f(qkv[(size_t)(b * L_ + m) * 1536 + 1024 + h * 64 + dq * 16 + j]);
            o[ob + j] = f2bf(s * (1.0f / L_));
        }
    }
}

// ---------------------------------------------------------------------------
// Launch
// ---------------------------------------------------------------------------
extern "C" void kernel_launch(void* const* d_in, const int* in_sizes, int n_in,
                              void* d_out, int out_size, void* d_ws, size_t ws_size,
                              hipStream_t stream) {
    (void)in_sizes; (void)n_in; (void)out_size; (void)ws_size;
    const int*   tokens = (const int*)d_in[0];
    const float* embed  = (const float*)d_in[1];
    const float* ln1_s  = (const float*)d_in[2];
    const float* ln1_b  = (const float*)d_in[3];
    const float* wq     = (const float*)d_in[4];
    const float* wk     = (const float*)d_in[5];
    const float* wv     = (const float*)d_in[6];
    const float* wo     = (const float*)d_in[7];
    const float* ln2_s  = (const float*)d_in[8];
    const float* ln2_b  = (const float*)d_in[9];
    const float* w1     = (const float*)d_in[10];
    const float* b1     = (const float*)d_in[11];
    const float* w2     = (const float*)d_in[12];
    const float* b2     = (const float*)d_in[13];
    const float* lnf_s  = (const float*)d_in[14];
    const float* lnf_b  = (const float*)d_in[15];
    float* out = (float*)d_out;

    const size_t BLE = (size_t)B_ * L_ * E_;              // 4,194,304
    char* ws = (char*)d_ws;
    float* x    = (float*)ws;                             // 16 MB
    short* yb   = (short*)(x + BLE);                      //  8 MB
    short* R    = yb + BLE;                               // 32 MB (qkv+ob / hb)
    short* qkv  = R;
    short* ob   = R + 3 * BLE;
    short* hb   = R;
    short* qkvt = R + 4 * BLE;                            // bf16 weights
    short* wot  = qkvt + (size_t)NL_ * 1536 * 512;
    short* w1t  = wot + (size_t)NL_ * 512 * 512;
    short* w2t  = w1t + (size_t)NL_ * 2048 * 512;
    float* pacc = (float*)(w2t + (size_t)NL_ * 512 * 2048);   // 8 slots x B x H x 4096 f32
    float* pm   = pacc + (size_t)8 * B_ * H_ * 4096;
    float* pl   = pm + (size_t)8 * B_ * H_ * 64;

    convT_kernel<<<dim3(8, 8, NL_), 256, 0, stream>>>(wq, qkvt,          512, 512, 262144, 786432, 0.125f);
    convT_kernel<<<dim3(8, 8, NL_), 256, 0, stream>>>(wk, qkvt + 262144, 512, 512, 262144, 786432, 1.0f);
    convT_kernel<<<dim3(8, 8, NL_), 256, 0, stream>>>(wv, qkvt + 524288, 512, 512, 262144, 786432, 1.0f);
    convT_kernel<<<dim3(8, 8, NL_), 256, 0, stream>>>(wo, wot,           512, 512, 262144, 262144, 1.0f);
    convT_kernel<<<dim3(32, 8, NL_), 256, 0, stream>>>(w1, w1t,          512, 2048, 1048576, 1048576, 1.0f);
    convT_kernel<<<dim3(8, 32, NL_), 256, 0, stream>>>(w2, w2t,          2048, 512, 1048576, 1048576, 1.0f);

    embed_kernel<<<(L_ * E_ / 8) / 256, 256, 0, stream>>>(tokens, embed, x);

    const int MR = B_ * L_;
    const int LNG = MR / 4;                                // 2048 blocks
    for (int lyr = 0; lyr < NL_; ++lyr) {
        ln_kernel<1><<<LNG, 256, 0, stream>>>(x, ln1_s + lyr * E_, ln1_b + lyr * E_, yb);
        mgemm_kernel<128, 128, 0, 1><<<dim3(12, 64), 512, 0, stream>>>(
            yb, qkvt + (size_t)lyr * 786432, nullptr, nullptr, qkv, MR, 1536, 512);
        attn_kernel<<<dim3(WT_HOST.n_items[lyr] * H_ * B_), 256, 0, stream>>>(
            qkv, tokens, ob, pacc, pm, pl, lyr);
        attn_combine<<<dim3(WT_HOST.n_cmb[lyr], H_, B_), 256, 0, stream>>>(
            qkv, tokens, ob, pacc, pm, pl, lyr);
        mgemm_kernel<64, 128, 0, 0><<<dim3(4, 128), 512, 0, stream>>>(
            ob, wot + (size_t)lyr * 262144, nullptr, x, x, MR, 512, 512);
        ln_kernel<1><<<LNG, 256, 0, stream>>>(x, ln2_s + lyr * E_, ln2_b + lyr * E_, yb);
        mgemm_kernel<128, 128, 1, 1><<<dim3(16, 64), 512, 0, stream>>>(
            yb, w1t + (size_t)lyr * 1048576, b1 + (size_t)lyr * M_, nullptr, hb, MR, 2048, 512);
        mgemm_kernel<64, 128, 0, 0><<<dim3(4, 128), 512, 0, stream>>>(
            hb, w2t + (size_t)lyr * 1048576, b2 + (size_t)lyr * E_, x, x, MR, 512, 2048);
    }
    ln_kernel<0><<<LNG, 256, 0, stream>>>(x, lnf_s, lnf_b, out);
}

// Round 14
// 580.872 us; speedup vs baseline: 24.9729x; 1.0134x over previous
//
#include <hip/hip_runtime.h>
#include <hip/hip_bf16.h>
#include <cmath>
#include <cstdint>
#include <cstddef>

#define B_   4
#define L_   2048
#define E_   512
#define H_   8
#define DH_  64
#define M_   2048
#define NL_  4
#define NB_  32
#define BS_  64
#define CH_  8    // max 64-key jb-blocks per attention work item

typedef short bf16x8 __attribute__((ext_vector_type(8)));
typedef short bf16x4 __attribute__((ext_vector_type(4)));
typedef float f32x4 __attribute__((ext_vector_type(4)));

__device__ __forceinline__ short f2bf(float f) {
    union { __hip_bfloat16 h; short s; } u;
    u.h = __float2bfloat16(f);
    return u.s;
}
__device__ __forceinline__ float bf2f(short s) {
    union { short s; __hip_bfloat16 h; } u;
    u.s = s;
    return __bfloat162float(u.h);
}

// ---------------------------------------------------------------------------
// BigBird masks + work partition, all at COMPILE TIME.
// ---------------------------------------------------------------------------
struct MaskTable { unsigned m[NL_][NB_]; };
struct CxMT { unsigned key[624]; int pos; };

constexpr unsigned cx_next(CxMT& st) {
    if (st.pos >= 624) {
        for (int i = 0; i < 624; ++i) {
            unsigned y = (st.key[i] & 0x80000000u) | (st.key[(i + 1) % 624] & 0x7fffffffu);
            st.key[i] = st.key[(i + 397) % 624] ^ (y >> 1) ^ ((y & 1u) ? 0x9908b0dfu : 0u);
        }
        st.pos = 0;
    }
    unsigned y = st.key[st.pos++];
    y ^= y >> 11;
    y ^= (y << 7) & 0x9d2c5680u;
    y ^= (y << 15) & 0xefc60000u;
    y ^= y >> 18;
    return y;
}
constexpr unsigned cx_interval(CxMT& st, unsigned maxv) {
    if (maxv == 0u) return 0u;
    unsigned mask = maxv;
    mask |= mask >> 1; mask |= mask >> 2; mask |= mask >> 4;
    mask |= mask >> 8; mask |= mask >> 16;
    unsigned v = cx_next(st) & mask;
    while (v > maxv) v = cx_next(st) & mask;
    return v;
}
constexpr MaskTable compute_masks() {
    MaskTable T{};
    for (int lyr = 0; lyr < NL_; ++lyr) {
        unsigned m[NB_] = {};
        for (int i = 0; i < NB_; ++i) {
            unsigned w = 1u << i;
            if (i > 0) w |= 1u << (i - 1);
            if (i < NB_ - 1) w |= 1u << (i + 1);
            w |= 1u | (1u << (NB_ - 1));
            m[i] = w;
        }
        m[0] = 0xffffffffu;
        m[NB_ - 1] = 0xffffffffu;
        CxMT st{};
        unsigned s = (unsigned)lyr;
        for (int i = 0; i < 624; ++i) {
            st.key[i] = s;
            s = 1812433253u * (s ^ (s >> 30)) + (unsigned)i + 1u;
        }
        st.pos = 624;
        for (int i = 1; i < NB_ - 1; ++i) {
            int cand[NB_] = {};
            int n = 0;
            for (int j = 0; j < NB_; ++j) {
                if (j == 0 || j == NB_ - 1 || j == i - 1 || j == i || j == i + 1) continue;
                cand[n++] = j;
            }
            for (int kk = n - 1; kk >= 1; --kk) {
                int jj = (int)cx_interval(st, (unsigned)kk);
                int tmp = cand[kk]; cand[kk] = cand[jj]; cand[jj] = tmp;
            }
            m[i] |= (1u << cand[0]) | (1u << cand[1]) | (1u << cand[2]);
        }
        for (int i = 0; i < NB_; ++i) T.m[lyr][i] = m[i];
    }
    return T;
}

struct WorkTable {
    int n_items[NL_];
    int n_cmb[NL_];
    unsigned char itm_qb[NL_][48];
    unsigned char itm_j0[NL_][48];
    unsigned char itm_jn[NL_][48];
    unsigned char itm_slot[NL_][48];   // 0xFF = direct write to o
    unsigned char cmb_qb[NL_][8];
    unsigned char cmb_slot0[NL_][8];
    unsigned char cmb_nch[NL_][8];
    unsigned char jlist[NL_][NB_][NB_];
};

constexpr WorkTable compute_work() {
    WorkTable T{};
    MaskTable M = compute_masks();
    for (int lyr = 0; lyr < NL_; ++lyr) {
        int items = 0, slots = 0, ncmb = 0;
        for (int qb = 0; qb < NB_; ++qb) {
            int cnt = 0;
            for (int j = 0; j < NB_; ++j)
                if ((M.m[lyr][qb] >> j) & 1u)
                    T.jlist[lyr][qb][cnt++] = (unsigned char)j;
            int nch = (cnt + CH_ - 1) / CH_;
            if (nch == 1) {
                T.itm_qb[lyr][items] = (unsigned char)qb;
                T.itm_j0[lyr][items] = 0;
                T.itm_jn[lyr][items] = (unsigned char)cnt;
                T.itm_slot[lyr][items] = 0xFF;
                items++;
            } else {
                T.cmb_qb[lyr][ncmb] = (unsigned char)qb;
                T.cmb_slot0[lyr][ncmb] = (unsigned char)slots;
                T.cmb_nch[lyr][ncmb] = (unsigned char)nch;
                ncmb++;
                int base = cnt / nch, rem = cnt % nch, off = 0;
                for (int c = 0; c < nch; ++c) {
                    int cl = base + (c < rem ? 1 : 0);
                    T.itm_qb[lyr][items] = (unsigned char)qb;
                    T.itm_j0[lyr][items] = (unsigned char)off;
                    T.itm_jn[lyr][items] = (unsigned char)cl;
                    T.itm_slot[lyr][items] = (unsigned char)slots;
                    items++; slots++; off += cl;
                }
            }
        }
        T.n_items[lyr] = items;
        T.n_cmb[lyr] = ncmb;
    }
    return T;
}

static constexpr WorkTable WT_HOST = compute_work();
__constant__ WorkTable g_wt = compute_work();

// ---------------------------------------------------------------------------
// Embedding + sinusoidal PE (PE reused across the 4 batches)
// ---------------------------------------------------------------------------
__global__ __launch_bounds__(256) void embed_kernel(const int* __restrict__ tokens,
                                                    const float* __restrict__ embed,
                                                    float* __restrict__ x) {
    int idx = blockIdx.x * 256 + threadIdx.x;      // < L_*E_/8 = 131072
    int l = idx >> 6;
    int e0 = (idx & 63) * 8;
    float pe[8];
    #pragma unroll
    for (int j = 0; j < 8; ++j) {
        int e = e0 + j;
        int jj = e & 255;
        float div = expf((float)jj * -0.03597789207717895f);  // -ln(10000)/256
        float arg = (float)l * div;
        pe[j] = (e < 256) ? sinf(arg) : cosf(arg);
    }
    #pragma unroll
    for (int b = 0; b < B_; ++b) {
        int tok = tokens[b * L_ + l];
        const float* em = embed + (size_t)tok * E_ + e0;
        f32x4 v0 = *(const f32x4*)em;
        f32x4 v1 = *(const f32x4*)(em + 4);
        #pragma unroll
        for (int j = 0; j < 4; ++j) { v0[j] += pe[j]; v1[j] += pe[4 + j]; }
        float* xo = x + ((size_t)(b * L_ + l)) * E_ + e0;
        *(f32x4*)xo = v0;
        *(f32x4*)(xo + 4) = v1;
    }
}

// ---------------------------------------------------------------------------
// LayerNorm: wave-per-row (4 rows per 256-thread block, no barriers).
// ---------------------------------------------------------------------------
template<int OUTBF>
__global__ __launch_bounds__(256) void ln_kernel(const float* __restrict__ x,
                                                 const float* __restrict__ gamma,
                                                 const float* __restrict__ beta,
                                                 void* __restrict__ yout) {
    int t = threadIdx.x;
    int lane = t & 63;
    int row = blockIdx.x * 4 + (t >> 6);
    const float* xr = x + (size_t)row * E_ + lane * 8;
    f32x4 a0 = *(const f32x4*)xr;
    f32x4 a1 = *(const f32x4*)(xr + 4);
    float s = a0[0] + a0[1] + a0[2] + a0[3] + a1[0] + a1[1] + a1[2] + a1[3];
    #pragma unroll
    for (int off = 1; off < 64; off <<= 1) s += __shfl_xor(s, off, 64);
    float mu = s * (1.0f / E_);
    float q = 0.0f;
    #pragma unroll
    for (int j = 0; j < 4; ++j) { float d = a0[j] - mu; q += d * d; }
    #pragma unroll
    for (int j = 0; j < 4; ++j) { float d = a1[j] - mu; q += d * d; }
    #pragma unroll
    for (int off = 1; off < 64; off <<= 1) q += __shfl_xor(q, off, 64);
    float rstd = rsqrtf(q * (1.0f / E_) + 1e-6f);
    f32x4 g0 = *(const f32x4*)(gamma + lane * 8);
    f32x4 g1 = *(const f32x4*)(gamma + lane * 8 + 4);
    f32x4 b0 = *(const f32x4*)(beta + lane * 8);
    f32x4 b1 = *(const f32x4*)(beta + lane * 8 + 4);
    float o[8];
    #pragma unroll
    for (int j = 0; j < 4; ++j) o[j] = (a0[j] - mu) * rstd * g0[j] + b0[j];
    #pragma unroll
    for (int j = 0; j < 4; ++j) o[4 + j] = (a1[j] - mu) * rstd * g1[j] + b1[j];
    if (OUTBF) {
        bf16x8 pk;
        #pragma unroll
        for (int j = 0; j < 8; ++j) pk[j] = f2bf(o[j]);
        *(bf16x8*)((short*)yout + (size_t)row * E_ + lane * 8) = pk;
    } else {
        float* yr = (float*)yout + (size_t)row * E_ + lane * 8;
        *(f32x4*)yr = f32x4{o[0], o[1], o[2], o[3]};
        *(f32x4*)(yr + 4) = f32x4{o[4], o[5], o[6], o[7]};
    }
}

// ---------------------------------------------------------------------------
// Weight convert + transpose: Wt[n][k] = bf16(W[k][n] * scale), per layer (z)
// ---------------------------------------------------------------------------
__global__ __launch_bounds__(256) void convT_kernel(const float* __restrict__ W,
                                                    short* __restrict__ Wt,
                                                    int K, int N,
                                                    size_t wStride, size_t wtStride,
                                                    float scale) {
    __shared__ float Ts[64][65];
    const float* Wl = W + blockIdx.z * wStride;
    short* Wtl = Wt + blockIdx.z * wtStride;
    int n0 = blockIdx.x * 64, k0 = blockIdx.y * 64;
    int t = threadIdx.x;
    int c = t & 63, r0 = t >> 6;
    #pragma unroll
    for (int i = 0; i < 16; ++i) {
        int r = r0 * 16 + i;
        Ts[r][c] = Wl[(size_t)(k0 + r) * N + n0 + c] * scale;
    }
    __syncthreads();
    #pragma unroll
    for (int i = 0; i < 16; ++i) {
        int r = r0 * 16 + i;
        Wtl[(size_t)(n0 + r) * K + k0 + c] = f2bf(Ts[c][r]);
    }
}

// ---------------------------------------------------------------------------
// MFMA bf16 GEMM, 2-phase double-buffered (r12-proven schedule, UNCHANGED):
//   stage(t+1) issued BEFORE compute(t); single s_waitcnt vmcnt(0) lgkmcnt(0)
//   (with "memory" clobber) + s_barrier per K-iter.
// 512 threads = 8 waves (2x4); XCD-aware bijective block swizzle (T1);
// T2 XOR swizzle on LDS; LDS-staged epilogue.
// NOTE: depth-2 counted-vmcnt (r11/r13) raced intermittently -- retired.
// ---------------------------------------------------------------------------
__device__ __forceinline__ float gelu_tanh(float x) {
    float u = x * (1.5957691216057308f + 0.07135480122394604f * x * x);
    return x / (1.0f + __expf(-u));
}

template<int BM, int BN, int ACT, int OUTBF>
__global__ __launch_bounds__(512) void mgemm_kernel(const short* __restrict__ A,
                                                    const short* __restrict__ Bt,
                                                    const float* __restrict__ bias,
                                                    const float* __restrict__ res,
                                                    void* __restrict__ Cout,
                                                    int M, int N, int K) {
    constexpr int WR = 2, WC = 4;      // 8 waves
    constexpr int FM = BM / WR / 16;
    constexpr int FN = BN / WC / 16;
    constexpr int ASZ = BM * 64;
    constexpr int BSZ = BN * 64;
    constexpr int PAD = 8;
    constexpr int CW = BN + PAD;
    static_assert((size_t)(OUTBF ? BM * CW * 2 : BM * CW * 4) <= (size_t)2 * (ASZ + BSZ) * 2,
                  "epilogue stage must fit in dbuf LDS");
    __shared__ __align__(16) short smem[2 * (ASZ + BSZ)];

    int t = threadIdx.x;
    int w = t >> 6, l = t & 63;
    int l15 = l & 15, lg = l >> 4;
    int wr = w >> 2, wc = w & 3;
    int rowbase = wr * (BM / WR), colbase = wc * (BN / WC);

    int nwg = (int)(gridDim.x * gridDim.y);
    int orig = (int)(blockIdx.y * gridDim.x + blockIdx.x);
    int sid = (orig & 7) * (nwg >> 3) + (orig >> 3);
    int bx = sid % (int)gridDim.x, by = sid / (int)gridDim.x;
    int brow = by * BM, bcol = bx * BN;

    int swz = ((t & 7) ^ ((t >> 3) & 7)) * 8;
    f32x4 acc[FM][FN] = {};

    const int nt = K >> 6;

    auto stage = [&](int buf, int k0) {
        short* Ad = smem + buf * ASZ;
        short* Bd = smem + 2 * ASZ + buf * BSZ;
        #pragma unroll
        for (int it = 0; it < BM / 64; ++it) {
            int row = it * 64 + (t >> 3);
            const short* ga = A + (size_t)(brow + row) * K + k0 + swz;
            __builtin_amdgcn_global_load_lds(
                (const __attribute__((address_space(1))) unsigned int*)ga,
                (__attribute__((address_space(3))) unsigned int*)(Ad + (it * 64 + w * 8) * 64),
                16, 0, 0);
        }
        #pragma unroll
        for (int it = 0; it < BN / 64; ++it) {
            int row = it * 64 + (t >> 3);
            const short* gb = Bt + (size_t)(bcol + row) * K + k0 + swz;
            __builtin_amdgcn_global_load_lds(
                (const __attribute__((address_space(1))) unsigned int*)gb,
                (__attribute__((address_space(3))) unsigned int*)(Bd + (it * 64 + w * 8) * 64),
                16, 0, 0);
        }
    };

    stage(0, 0);
    asm volatile("s_waitcnt vmcnt(0)" ::: "memory");
    __builtin_amdgcn_s_barrier();

    int cur = 0;
    for (int kt = 0; kt < nt; ++kt) {
        if (kt + 1 < nt) stage(cur ^ 1, (kt + 1) << 6);
        const short* Ar = smem + cur * ASZ;
        const short* Br = smem + 2 * ASZ + cur * BSZ;
        #pragma unroll
        for (int kk = 0; kk < 64; kk += 32) {
            bf16x8 af[FM], bfr[FN];
            #pragma unroll
            for (int m = 0; m < FM; ++m)
                af[m] = *(const bf16x8*)(Ar + (rowbase + m * 16 + l15) * 64
                                            + (((kk >> 3) + lg) ^ (l15 & 7)) * 8);
            #pragma unroll
            for (int n = 0; n < FN; ++n)
                bfr[n] = *(const bf16x8*)(Br + (colbase + n * 16 + l15) * 64
                                             + (((kk >> 3) + lg) ^ (l15 & 7)) * 8);
            #pragma unroll
            for (int m = 0; m < FM; ++m)
                #pragma unroll
                for (int n = 0; n < FN; ++n)
                    acc[m][n] = __builtin_amdgcn_mfma_f32_16x16x32_bf16(af[m], bfr[n], acc[m][n], 0, 0, 0);
        }
        asm volatile("s_waitcnt vmcnt(0) lgkmcnt(0)" ::: "memory");
        __builtin_amdgcn_s_barrier();
        cur ^= 1;
    }

    if (OUTBF) {
        short* Cs = smem;
        #pragma unroll
        for (int m = 0; m < FM; ++m) {
            int row = rowbase + m * 16 + lg * 4;
            #pragma unroll
            for (int n = 0; n < FN; ++n) {
                int col = colbase + n * 16 + l15;
                float bv = bias ? bias[bcol + col] : 0.0f;
                #pragma unroll
                for (int r = 0; r < 4; ++r) {
                    float vv = acc[m][n][r] + bv;
                    if (ACT == 1) vv = gelu_tanh(vv);
                    Cs[(row + r) * CW + col] = f2bf(vv);
                }
            }
        }
        __syncthreads();
        #pragma unroll
        for (int it = 0; it < BM * BN / 8 / 512; ++it) {
            int c = it * 512 + t;
            int row = c / (BN / 8), c8 = c % (BN / 8);
            *(bf16x8*)((short*)Cout + (size_t)(brow + row) * N + bcol + c8 * 8) =
                *(const bf16x8*)(Cs + row * CW + c8 * 8);
        }
    } else {
        float* Cs = (float*)smem;
        #pragma unroll
        for (int m = 0; m < FM; ++m) {
            int row = rowbase + m * 16 + lg * 4;
            #pragma unroll
            for (int n = 0; n < FN; ++n) {
                int col = colbase + n * 16 + l15;
                float bv = bias ? bias[bcol + col] : 0.0f;
                #pragma unroll
                for (int r = 0; r < 4; ++r)
                    Cs[(row + r) * CW + col] = acc[m][n][r] + bv;
            }
        }
        __syncthreads();
        #pragma unroll
        for (int it = 0; it < BM * BN / 4 / 512; ++it) {
            int c = it * 512 + t;
            int row = c / (BN / 4), c4 = c % (BN / 4);
            f32x4 vv = *(const f32x4*)(Cs + row * CW + c4 * 4);
            size_t gi = (size_t)(brow + row) * N + bcol + c4 * 4;
            if (res) vv += *(const f32x4*)(res + gi);
            *(f32x4*)((float*)Cout + gi) = vv;
        }
    }
}

// ---------------------------------------------------------------------------
// Sparse block attention, MFMA bf16, KVBLK=64, swapped QK^T, dbuf K/V LDS.
// Flat 1-D grid with bijective XCD chunk swizzle (r12-proven: FETCH 55->12MB).
// NEW (r14): tree reductions for row max/sum + T13 defer-max (THR=8) --
// register-only restructuring, no sync/layout changes.
// ---------------------------------------------------------------------------
#define KSTR 72

__global__ __launch_bounds__(256) void attn_kernel(const short* __restrict__ qkv,
                                                   const int* __restrict__ tokens,
                                                   short* __restrict__ o,
                                                   float* __restrict__ pacc,
                                                   float* __restrict__ pm,
                                                   float* __restrict__ pl,
                                                   int lyr) {
    __shared__ __align__(16) short Ks[2][64][KSTR];
    __shared__ __align__(16) short Vt[2][64][KSTR];
    __shared__ __align__(16) short Pw[4][16][KSTR];
    __shared__ unsigned long long qbits_s;
    __shared__ unsigned long long kbits_s[2];

    int nit = g_wt.n_items[lyr];
    int nwg = (int)gridDim.x;                    // nit * 32, divisible by 8
    int orig = (int)blockIdx.x;
    int sid = (orig & 7) * (nwg >> 3) + (orig >> 3);
    int item = sid % nit;
    int bh = sid / nit;
    int h = bh & 7, b = bh >> 3;

    int qb   = g_wt.itm_qb[lyr][item];
    int j0   = g_wt.itm_j0[lyr][item];
    int jn   = g_wt.itm_jn[lyr][item];
    int slot = g_wt.itm_slot[lyr][item];
    const unsigned char* jl = g_wt.jlist[lyr][qb];

    int t = threadIdx.x;
    int l = t & 63, w = t >> 6;
    int l15 = l & 15, lg = l >> 4;
    int srow = t >> 3, sdb = t & 7;

    if (t < 64) {
        unsigned long long qm = __ballot(tokens[b * L_ + qb * 64 + t] > 0);
        if (t == 0) qbits_s = qm;
    }

    int qrow = qb * 64 + w * 16 + l15;
    const short* qp = qkv + (size_t)(b * L_ + qrow) * 1536 + h * 64;
    bf16x8 qf0 = *(const bf16x8*)(qp + lg * 8);
    bf16x8 qf1 = *(const bf16x8*)(qp + lg * 8 + 32);

    f32x4 acc[4] = {};
    float m_r = -INFINITY, l_r = 0.0f;

    bf16x8 kr0, kr1, vr0, vr1;
    int pn = 0;
    auto LOAD = [&](int ci) {
        int jb = jl[j0 + ci];
        const short* base = qkv + (size_t)(b * L_ + jb * 64 + srow) * 1536 + h * 64;
        kr0 = *(const bf16x8*)(base + 512 + sdb * 8);
        kr1 = *(const bf16x8*)(base + (size_t)32 * 1536 + 512 + sdb * 8);
        vr0 = *(const bf16x8*)(base + 1024 + sdb * 8);
        vr1 = *(const bf16x8*)(base + (size_t)32 * 1536 + 1024 + sdb * 8);
        if (t < 64) pn = tokens[b * L_ + jb * 64 + t];
    };
    auto STORE = [&](int buf) {
        *(bf16x8*)&Ks[buf][srow][sdb * 8] = kr0;
        *(bf16x8*)&Ks[buf][srow + 32][sdb * 8] = kr1;
        #pragma unroll
        for (int j = 0; j < 8; ++j) {
            Vt[buf][sdb * 8 + j][(srow & 7) + 8 * ((srow >> 3) ^ sdb)] = vr0[j];
            Vt[buf][sdb * 8 + j][(srow & 7) + 8 * (((srow >> 3) + 4) ^ sdb)] = vr1[j];
        }
        if (t < 64) {
            unsigned long long km = __ballot(pn > 0);
            if (t == 0) kbits_s[buf] = km;
        }
    };

    LOAD(0);
    STORE(0);
    if (jn > 1) LOAD(1);
    __syncthreads();

    int cur = 0;
    for (int ci = 0; ci < jn; ++ci) {
        f32x4 sacc[4];
        __builtin_amdgcn_s_setprio(1);
        #pragma unroll
        for (int f = 0; f < 4; ++f) {
            bf16x8 kk0 = *(const bf16x8*)&Ks[cur][16 * f + l15][lg * 8];
            bf16x8 kk1 = *(const bf16x8*)&Ks[cur][16 * f + l15][lg * 8 + 32];
            f32x4 z = {};
            z = __builtin_amdgcn_mfma_f32_16x16x32_bf16(kk0, qf0, z, 0, 0, 0);
            z = __builtin_amdgcn_mfma_f32_16x16x32_bf16(kk1, qf1, z, 0, 0, 0);
            sacc[f] = z;
        }
        __builtin_amdgcn_s_setprio(0);

        unsigned long long kb = kbits_s[cur];
        bool pq = (qbits_s >> (w * 16 + l15)) & 1ull;
        unsigned vm = 0;
        #pragma unroll
        for (int f = 0; f < 4; ++f)
            vm |= ((unsigned)(kb >> (16 * f + 4 * lg)) & 0xFu) << (4 * f);
        if (!pq) vm = 0;

        // masked scores -> tree max (4 levels, not 16-deep chain)
        float sv[16];
        #pragma unroll
        for (int i = 0; i < 16; ++i)
            sv[i] = ((vm >> i) & 1u) ? sacc[i >> 2][i & 3] : -INFINITY;
        float t8[8], t4[4];
        #pragma unroll
        for (int i = 0; i < 8; ++i) t8[i] = fmaxf(sv[i], sv[i + 8]);
        #pragma unroll
        for (int i = 0; i < 4; ++i) t4[i] = fmaxf(t8[i], t8[i + 4]);
        float mx = fmaxf(fmaxf(t4[0], t4[1]), fmaxf(t4[2], t4[3]));
        mx = fmaxf(mx, __shfl_xor(mx, 16, 64));
        mx = fmaxf(mx, __shfl_xor(mx, 32, 64));

        // T13 defer-max: skip rescale when max didn't grow past THR=8
        bool defer = __all((mx <= m_r + 8.0f) && (m_r > -1e30f));
        float nm = defer ? m_r : fmaxf(m_r, mx);

        float pv[16];
        #pragma unroll
        for (int i = 0; i < 16; ++i)
            pv[i] = ((vm >> i) & 1u) ? __expf(sv[i] - nm) : 0.0f;
        float s8[8], s4[4];
        #pragma unroll
        for (int i = 0; i < 8; ++i) s8[i] = pv[i] + pv[i + 8];
        #pragma unroll
        for (int i = 0; i < 4; ++i) s4[i] = s8[i] + s8[i + 4];
        float sum = (s4[0] + s4[1]) + (s4[2] + s4[3]);
        sum += __shfl_xor(sum, 16, 64);
        sum += __shfl_xor(sum, 32, 64);

        if (defer) {
            l_r += sum;
        } else {
            float al = (nm == -INFINITY) ? 1.0f : __expf(m_r - nm);
            m_r = nm;
            l_r = l_r * al + sum;
            float alr[4];
            #pragma unroll
            for (int r = 0; r < 4; ++r) alr[r] = __shfl(al, lg * 4 + r, 64);
            #pragma unroll
            for (int fd = 0; fd < 4; ++fd)
                #pragma unroll
                for (int r = 0; r < 4; ++r) acc[fd][r] *= alr[r];
        }

        #pragma unroll
        for (int f = 0; f < 4; ++f) {
            bf16x4 pk;
            #pragma unroll
            for (int r = 0; r < 4; ++r) pk[r] = f2bf(pv[4 * f + r]);
            *(bf16x4*)&Pw[w][l15][16 * f + 4 * lg] = pk;
        }

        bf16x8 pa0 = *(const bf16x8*)&Pw[w][l15][lg * 8];
        bf16x8 pa1 = *(const bf16x8*)&Pw[w][l15][lg * 8 + 32];
        __builtin_amdgcn_s_setprio(1);
        #pragma unroll
        for (int fd = 0; fd < 4; ++fd) {
            int dd = 16 * fd + l15;
            bf16x8 vv0 = *(const bf16x8*)&Vt[cur][dd][8 * (lg ^ (dd >> 3))];
            bf16x8 vv1 = *(const bf16x8*)&Vt[cur][dd][8 * ((4 + lg) ^ (dd >> 3))];
            acc[fd] = __builtin_amdgcn_mfma_f32_16x16x32_bf16(pa0, vv0, acc[fd], 0, 0, 0);
            acc[fd] = __builtin_amdgcn_mfma_f32_16x16x32_bf16(pa1, vv1, acc[fd], 0, 0, 0);
        }
        __builtin_amdgcn_s_setprio(0);

        if (ci + 1 < jn) {
            STORE(cur ^ 1);
            if (ci + 2 < jn) LOAD(ci + 2);
        }
        __syncthreads();
        cur ^= 1;
    }

    float lrr[4], mrr[4];
    #pragma unroll
    for (int r = 0; r < 4; ++r) {
        lrr[r] = __shfl(l_r, lg * 4 + r, 64);
        mrr[r] = __shfl(m_r, lg * 4 + r, 64);
    }
    unsigned long long qbits = qbits_s;

    if (slot == 0xFF) {
        #pragma unroll
        for (int r = 0; r < 4; ++r) {
            int rw = lg * 4 + r;
            int gl = qb * 64 + w * 16 + rw;
            size_t ob = (size_t)(b * L_ + gl) * 512 + h * 64 + l15;
            bool ok = ((qbits >> (w * 16 + rw)) & 1ull) && (lrr[r] > 0.0f);
            if (ok) {
                float inv = 1.0f / lrr[r];
                #pragma unroll
                for (int fd = 0; fd < 4; ++fd) o[ob + 16 * fd] = f2bf(acc[fd][r] * inv);
            } else {
                #pragma unroll
                for (int fd = 0; fd < 4; ++fd) {
                    float s = 0.0f;
                    for (int m = 0; m < L_; ++m)
                        s += bf2f(qkv[(size_t)(b * L_ + m) * 1536 + 1024 + h * 64 + 16 * fd + l15]);
                    o[ob + 16 * fd] = f2bf(s * (1.0f / L_));
                }
            }
        }
    } else {
        size_t pb = ((size_t)slot * B_ + b) * H_ + h;
        #pragma unroll
        for (int r = 0; r < 4; ++r) {
            int rloc = w * 16 + lg * 4 + r;
            #pragma unroll
            for (int fd = 0; fd < 4; ++fd)
                pacc[pb * 4096 + (size_t)rloc * 64 + 16 * fd + l15] = acc[fd][r];
            if (l15 == 0) {
                pm[pb * 64 + rloc] = mrr[r];
                pl[pb * 64 + rloc] = lrr[r];
            }
        }
    }
}

// ---------------------------------------------------------------------------
// Combine partial flash results for split q-blocks.
// ---------------------------------------------------------------------------
__global__ __launch_bounds__(256) void attn_combine(const short* __restrict__ qkv,
                                                    const int* __restrict__ tokens,
                                                    short* __restrict__ o,
                                                    const float* __restrict__ pacc,
                                                    const float* __restrict__ pm,
                                                    const float* __restrict__ pl,
                                                    int lyr) {
    int ci = blockIdx.x, h = blockIdx.y, b = blockIdx.z;
    int qb  = g_wt.cmb_qb[lyr][ci];
    int s0  = g_wt.cmb_slot0[lyr][ci];
    int nch = g_wt.cmb_nch[lyr][ci];
    int t = threadIdx.x;
    int r = t >> 2, dq = t & 3;
    int grow = qb * 64 + r;
    bool pq = tokens[b * L_ + grow] > 0;
    float M = -INFINITY;
    for (int c = 0; c < nch; ++c)
        M = fmaxf(M, pm[(((size_t)(s0 + c) * B_ + b) * H_ + h) * 64 + r]);
    size_t ob = (size_t)(b * L_ + grow) * 512 + h * 64 + dq * 16;
    if (pq && M > -1e30f) {
        float lsum = 0.0f;
        float accd[16] = {};
        for (int c = 0; c < nch; ++c) {
            size_t pb = ((size_t)(s0 + c) * B_ + b) * H_ + h;
            float wgt = __expf(pm[pb * 64 + r] - M);
            lsum += pl[pb * 64 + r] * wgt;
            const float* pa = pacc + pb * 4096 + (size_t)r * 64 + dq * 16;
            #pragma unroll
            for (int j = 0; j < 16; ++j) accd[j] += pa[j] * wgt;
        }
        float inv = 1.0f / lsum;
        #pragma unroll
        for (int j = 0; j < 16; ++j) o[ob + j] = f2bf(accd[j] * inv);
    } else {
        #pragma unroll
        for (int j = 0; j < 16; ++j) {
            float s = 0.0f;
            for (int m = 0; m < L_; ++m)
                s += bf2f(qkv[(size_t)(b * L_ + m) * 1536 + 1024 + h * 64 + dq * 16 + j]);
            o[ob + j] = f2bf(s * (1.0f / L_));
        }
    }
}

// ---------------------------------------------------------------------------
// Launch
// ---------------------------------------------------------------------------
extern "C" void kernel_launch(void* const* d_in, const int* in_sizes, int n_in,
                              void* d_out, int out_size, void* d_ws, size_t ws_size,
                              hipStream_t stream) {
    (void)in_sizes; (void)n_in; (void)out_size; (void)ws_size;
    const int*   tokens = (const int*)d_in[0];
    const float* embed  = (const float*)d_in[1];
    const float* ln1_s  = (const float*)d_in[2];
    const float* ln1_b  = (const float*)d_in[3];
    const float* wq     = (const float*)d_in[4];
    const float* wk     = (const float*)d_in[5];
    const float* wv     = (const float*)d_in[6];
    const float* wo     = (const float*)d_in[7];
    const float* ln2_s  = (const float*)d_in[8];
    const float* ln2_b  = (const float*)d_in[9];
    const float* w1     = (const float*)d_in[10];
    const float* b1     = (const float*)d_in[11];
    const float* w2     = (const float*)d_in[12];
    const float* b2     = (const float*)d_in[13];
    const float* lnf_s  = (const float*)d_in[14];
    const float* lnf_b  = (const float*)d_in[15];
    float* out = (float*)d_out;

    const size_t BLE = (size_t)B_ * L_ * E_;              // 4,194,304
    char* ws = (char*)d_ws;
    float* x    = (float*)ws;                             // 16 MB
    short* yb   = (short*)(x + BLE);                      //  8 MB
    short* R    = yb + BLE;                               // 32 MB (qkv+ob / hb)
    short* qkv  = R;
    short* ob   = R + 3 * BLE;
    short* hb   = R;
    short* qkvt = R + 4 * BLE;                            // bf16 weights
    short* wot  = qkvt + (size_t)NL_ * 1536 * 512;
    short* w1t  = wot + (size_t)NL_ * 512 * 512;
    short* w2t  = w1t + (size_t)NL_ * 2048 * 512;
    float* pacc = (float*)(w2t + (size_t)NL_ * 512 * 2048);   // 8 slots x B x H x 4096 f32
    float* pm   = pacc + (size_t)8 * B_ * H_ * 4096;
    float* pl   = pm + (size_t)8 * B_ * H_ * 64;

    convT_kernel<<<dim3(8, 8, NL_), 256, 0, stream>>>(wq, qkvt,          512, 512, 262144, 786432, 0.125f);
    convT_kernel<<<dim3(8, 8, NL_), 256, 0, stream>>>(wk, qkvt + 262144, 512, 512, 262144, 786432, 1.0f);
    convT_kernel<<<dim3(8, 8, NL_), 256, 0, stream>>>(wv, qkvt + 524288, 512, 512, 262144, 786432, 1.0f);
    convT_kernel<<<dim3(8, 8, NL_), 256, 0, stream>>>(wo, wot,           512, 512, 262144, 262144, 1.0f);
    convT_kernel<<<dim3(32, 8, NL_), 256, 0, stream>>>(w1, w1t,          512, 2048, 1048576, 1048576, 1.0f);
    convT_kernel<<<dim3(8, 32, NL_), 256, 0, stream>>>(w2, w2t,          2048, 512, 1048576, 1048576, 1.0f);

    embed_kernel<<<(L_ * E_ / 8) / 256, 256, 0, stream>>>(tokens, embed, x);

    const int MR = B_ * L_;
    const int LNG = MR / 4;                                // 2048 blocks
    for (int lyr = 0; lyr < NL_; ++lyr) {
        ln_kernel<1><<<LNG, 256, 0, stream>>>(x, ln1_s + lyr * E_, ln1_b + lyr * E_, yb);
        mgemm_kernel<128, 128, 0, 1><<<dim3(12, 64), 512, 0, stream>>>(
            yb, qkvt + (size_t)lyr * 786432, nullptr, nullptr, qkv, MR, 1536, 512);
        attn_kernel<<<dim3(WT_HOST.n_items[lyr] * H_ * B_), 256, 0, stream>>>(
            qkv, tokens, ob, pacc, pm, pl, lyr);
        attn_combine<<<dim3(WT_HOST.n_cmb[lyr], H_, B_), 256, 0, stream>>>(
            qkv, tokens, ob, pacc, pm, pl, lyr);
        mgemm_kernel<64, 128, 0, 0><<<dim3(4, 128), 512, 0, stream>>>(
            ob, wot + (size_t)lyr * 262144, nullptr, x, x, MR, 512, 512);
        ln_kernel<1><<<LNG, 256, 0, stream>>>(x, ln2_s + lyr * E_, ln2_b + lyr * E_, yb);
        mgemm_kernel<128, 128, 1, 1><<<dim3(16, 64), 512, 0, stream>>>(
            yb, w1t + (size_t)lyr * 1048576, b1 + (size_t)lyr * M_, nullptr, hb, MR, 2048, 512);
        mgemm_kernel<64, 128, 0, 0><<<dim3(4, 128), 512, 0, stream>>>(
            hb, w2t + (size_t)lyr * 1048576, b2 + (size_t)lyr * E_, x, x, MR, 512, 2048);
    }
    ln_kernel<0><<<LNG, 256, 0, stream>>>(x, lnf_s, lnf_b, out);
}

// Round 15
// 555.595 us; speedup vs baseline: 26.1090x; 1.0455x over previous
//
#include <hip/hip_runtime.h>
#include <hip/hip_bf16.h>
#include <cmath>
#include <cstdint>
#include <cstddef>

#define B_   4
#define L_   2048
#define E_   512
#define H_   8
#define DH_  64
#define M_   2048
#define NL_  4
#define NB_  32
#define BS_  64
#define CH_  8    // max 64-key jb-blocks per attention work item

typedef short bf16x8 __attribute__((ext_vector_type(8)));
typedef short bf16x4 __attribute__((ext_vector_type(4)));
typedef float f32x4 __attribute__((ext_vector_type(4)));

__device__ __forceinline__ short f2bf(float f) {
    union { __hip_bfloat16 h; short s; } u;
    u.h = __float2bfloat16(f);
    return u.s;
}
__device__ __forceinline__ float bf2f(short s) {
    union { short s; __hip_bfloat16 h; } u;
    u.s = s;
    return __bfloat162float(u.h);
}

// ---------------------------------------------------------------------------
// BigBird masks + work partition, all at COMPILE TIME.
// ---------------------------------------------------------------------------
struct MaskTable { unsigned m[NL_][NB_]; };
struct CxMT { unsigned key[624]; int pos; };

constexpr unsigned cx_next(CxMT& st) {
    if (st.pos >= 624) {
        for (int i = 0; i < 624; ++i) {
            unsigned y = (st.key[i] & 0x80000000u) | (st.key[(i + 1) % 624] & 0x7fffffffu);
            st.key[i] = st.key[(i + 397) % 624] ^ (y >> 1) ^ ((y & 1u) ? 0x9908b0dfu : 0u);
        }
        st.pos = 0;
    }
    unsigned y = st.key[st.pos++];
    y ^= y >> 11;
    y ^= (y << 7) & 0x9d2c5680u;
    y ^= (y << 15) & 0xefc60000u;
    y ^= y >> 18;
    return y;
}
constexpr unsigned cx_interval(CxMT& st, unsigned maxv) {
    if (maxv == 0u) return 0u;
    unsigned mask = maxv;
    mask |= mask >> 1; mask |= mask >> 2; mask |= mask >> 4;
    mask |= mask >> 8; mask |= mask >> 16;
    unsigned v = cx_next(st) & mask;
    while (v > maxv) v = cx_next(st) & mask;
    return v;
}
constexpr MaskTable compute_masks() {
    MaskTable T{};
    for (int lyr = 0; lyr < NL_; ++lyr) {
        unsigned m[NB_] = {};
        for (int i = 0; i < NB_; ++i) {
            unsigned w = 1u << i;
            if (i > 0) w |= 1u << (i - 1);
            if (i < NB_ - 1) w |= 1u << (i + 1);
            w |= 1u | (1u << (NB_ - 1));
            m[i] = w;
        }
        m[0] = 0xffffffffu;
        m[NB_ - 1] = 0xffffffffu;
        CxMT st{};
        unsigned s = (unsigned)lyr;
        for (int i = 0; i < 624; ++i) {
            st.key[i] = s;
            s = 1812433253u * (s ^ (s >> 30)) + (unsigned)i + 1u;
        }
        st.pos = 624;
        for (int i = 1; i < NB_ - 1; ++i) {
            int cand[NB_] = {};
            int n = 0;
            for (int j = 0; j < NB_; ++j) {
                if (j == 0 || j == NB_ - 1 || j == i - 1 || j == i || j == i + 1) continue;
                cand[n++] = j;
            }
            for (int kk = n - 1; kk >= 1; --kk) {
                int jj = (int)cx_interval(st, (unsigned)kk);
                int tmp = cand[kk]; cand[kk] = cand[jj]; cand[jj] = tmp;
            }
            m[i] |= (1u << cand[0]) | (1u << cand[1]) | (1u << cand[2]);
        }
        for (int i = 0; i < NB_; ++i) T.m[lyr][i] = m[i];
    }
    return T;
}

struct WorkTable {
    int n_items[NL_];
    int n_cmb[NL_];
    unsigned char itm_qb[NL_][48];
    unsigned char itm_j0[NL_][48];
    unsigned char itm_jn[NL_][48];
    unsigned char itm_slot[NL_][48];   // 0xFF = direct write to o
    unsigned char cmb_qb[NL_][8];
    unsigned char cmb_slot0[NL_][8];
    unsigned char cmb_nch[NL_][8];
    unsigned char jlist[NL_][NB_][NB_];
};

constexpr WorkTable compute_work() {
    WorkTable T{};
    MaskTable M = compute_masks();
    for (int lyr = 0; lyr < NL_; ++lyr) {
        int items = 0, slots = 0, ncmb = 0;
        for (int qb = 0; qb < NB_; ++qb) {
            int cnt = 0;
            for (int j = 0; j < NB_; ++j)
                if ((M.m[lyr][qb] >> j) & 1u)
                    T.jlist[lyr][qb][cnt++] = (unsigned char)j;
            int nch = (cnt + CH_ - 1) / CH_;
            if (nch == 1) {
                T.itm_qb[lyr][items] = (unsigned char)qb;
                T.itm_j0[lyr][items] = 0;
                T.itm_jn[lyr][items] = (unsigned char)cnt;
                T.itm_slot[lyr][items] = 0xFF;
                items++;
            } else {
                T.cmb_qb[lyr][ncmb] = (unsigned char)qb;
                T.cmb_slot0[lyr][ncmb] = (unsigned char)slots;
                T.cmb_nch[lyr][ncmb] = (unsigned char)nch;
                ncmb++;
                int base = cnt / nch, rem = cnt % nch, off = 0;
                for (int c = 0; c < nch; ++c) {
                    int cl = base + (c < rem ? 1 : 0);
                    T.itm_qb[lyr][items] = (unsigned char)qb;
                    T.itm_j0[lyr][items] = (unsigned char)off;
                    T.itm_jn[lyr][items] = (unsigned char)cl;
                    T.itm_slot[lyr][items] = (unsigned char)slots;
                    items++; slots++; off += cl;
                }
            }
        }
        T.n_items[lyr] = items;
        T.n_cmb[lyr] = ncmb;
    }
    return T;
}

static constexpr WorkTable WT_HOST = compute_work();
__constant__ WorkTable g_wt = compute_work();

// ---------------------------------------------------------------------------
// Embedding + sinusoidal PE -> bf16 residual stream x
// ---------------------------------------------------------------------------
__global__ __launch_bounds__(256) void embed_kernel(const int* __restrict__ tokens,
                                                    const float* __restrict__ embed,
                                                    short* __restrict__ x) {
    int idx = blockIdx.x * 256 + threadIdx.x;      // < L_*E_/8 = 131072
    int l = idx >> 6;
    int e0 = (idx & 63) * 8;
    float pe[8];
    #pragma unroll
    for (int j = 0; j < 8; ++j) {
        int e = e0 + j;
        int jj = e & 255;
        float div = expf((float)jj * -0.03597789207717895f);  // -ln(10000)/256
        float arg = (float)l * div;
        pe[j] = (e < 256) ? sinf(arg) : cosf(arg);
    }
    #pragma unroll
    for (int b = 0; b < B_; ++b) {
        int tok = tokens[b * L_ + l];
        const float* em = embed + (size_t)tok * E_ + e0;
        f32x4 v0 = *(const f32x4*)em;
        f32x4 v1 = *(const f32x4*)(em + 4);
        bf16x8 pk;
        #pragma unroll
        for (int j = 0; j < 4; ++j) {
            pk[j] = f2bf(v0[j] + pe[j]);
            pk[4 + j] = f2bf(v1[j] + pe[4 + j]);
        }
        *(bf16x8*)(x + ((size_t)(b * L_ + l)) * E_ + e0) = pk;
    }
}

// ---------------------------------------------------------------------------
// LayerNorm: bf16 input, bf16 (OUTBF=1) or fp32 (OUTBF=0) output.
// Wave-per-row (4 rows per 256-thread block, no barriers).
// ---------------------------------------------------------------------------
template<int OUTBF>
__global__ __launch_bounds__(256) void ln_kernel(const short* __restrict__ x,
                                                 const float* __restrict__ gamma,
                                                 const float* __restrict__ beta,
                                                 void* __restrict__ yout) {
    int t = threadIdx.x;
    int lane = t & 63;
    int row = blockIdx.x * 4 + (t >> 6);
    bf16x8 av = *(const bf16x8*)(x + (size_t)row * E_ + lane * 8);
    float a[8];
    #pragma unroll
    for (int j = 0; j < 8; ++j) a[j] = bf2f(av[j]);
    float s = ((a[0] + a[1]) + (a[2] + a[3])) + ((a[4] + a[5]) + (a[6] + a[7]));
    #pragma unroll
    for (int off = 1; off < 64; off <<= 1) s += __shfl_xor(s, off, 64);
    float mu = s * (1.0f / E_);
    float q = 0.0f;
    #pragma unroll
    for (int j = 0; j < 8; ++j) { float d = a[j] - mu; q += d * d; }
    #pragma unroll
    for (int off = 1; off < 64; off <<= 1) q += __shfl_xor(q, off, 64);
    float rstd = rsqrtf(q * (1.0f / E_) + 1e-6f);
    f32x4 g0 = *(const f32x4*)(gamma + lane * 8);
    f32x4 g1 = *(const f32x4*)(gamma + lane * 8 + 4);
    f32x4 b0 = *(const f32x4*)(beta + lane * 8);
    f32x4 b1 = *(const f32x4*)(beta + lane * 8 + 4);
    float o[8];
    #pragma unroll
    for (int j = 0; j < 4; ++j) o[j] = (a[j] - mu) * rstd * g0[j] + b0[j];
    #pragma unroll
    for (int j = 0; j < 4; ++j) o[4 + j] = (a[4 + j] - mu) * rstd * g1[j] + b1[j];
    if (OUTBF) {
        bf16x8 pk;
        #pragma unroll
        for (int j = 0; j < 8; ++j) pk[j] = f2bf(o[j]);
        *(bf16x8*)((short*)yout + (size_t)row * E_ + lane * 8) = pk;
    } else {
        float* yr = (float*)yout + (size_t)row * E_ + lane * 8;
        *(f32x4*)yr = f32x4{o[0], o[1], o[2], o[3]};
        *(f32x4*)(yr + 4) = f32x4{o[4], o[5], o[6], o[7]};
    }
}

// ---------------------------------------------------------------------------
// Weight convert + transpose: Wt[n][k] = bf16(W[k][n] * scale), per layer (z)
// ---------------------------------------------------------------------------
__global__ __launch_bounds__(256) void convT_kernel(const float* __restrict__ W,
                                                    short* __restrict__ Wt,
                                                    int K, int N,
                                                    size_t wStride, size_t wtStride,
                                                    float scale) {
    __shared__ float Ts[64][65];
    const float* Wl = W + blockIdx.z * wStride;
    short* Wtl = Wt + blockIdx.z * wtStride;
    int n0 = blockIdx.x * 64, k0 = blockIdx.y * 64;
    int t = threadIdx.x;
    int c = t & 63, r0 = t >> 6;
    #pragma unroll
    for (int i = 0; i < 16; ++i) {
        int r = r0 * 16 + i;
        Ts[r][c] = Wl[(size_t)(k0 + r) * N + n0 + c] * scale;
    }
    __syncthreads();
    #pragma unroll
    for (int i = 0; i < 16; ++i) {
        int r = r0 * 16 + i;
        Wtl[(size_t)(n0 + r) * K + k0 + c] = f2bf(Ts[c][r]);
    }
}

// ---------------------------------------------------------------------------
// MFMA bf16 GEMM, 2-phase double-buffered (r12-proven schedule, UNCHANGED):
//   stage(t+1) issued BEFORE compute(t); single s_waitcnt vmcnt(0) lgkmcnt(0)
//   (with "memory" clobber) + s_barrier per K-iter.
// 512 threads = 8 waves (2x4); XCD-aware bijective block swizzle (T1);
// T2 XOR swizzle on LDS; LDS-staged epilogue.
// OUTBF=1: bf16 out, no residual. OUTBF=0: bf16 residual in, bf16 out
// (f32 LDS C-staging, residual add in f32, single rounding).
// ---------------------------------------------------------------------------
__device__ __forceinline__ float gelu_tanh(float x) {
    float u = x * (1.5957691216057308f + 0.07135480122394604f * x * x);
    return x / (1.0f + __expf(-u));
}

template<int BM, int BN, int ACT, int OUTBF>
__global__ __launch_bounds__(512) void mgemm_kernel(const short* __restrict__ A,
                                                    const short* __restrict__ Bt,
                                                    const float* __restrict__ bias,
                                                    const short* __restrict__ res,
                                                    short* __restrict__ Cout,
                                                    int M, int N, int K) {
    constexpr int WR = 2, WC = 4;      // 8 waves
    constexpr int FM = BM / WR / 16;
    constexpr int FN = BN / WC / 16;
    constexpr int ASZ = BM * 64;
    constexpr int BSZ = BN * 64;
    constexpr int PAD = 8;
    constexpr int CW = BN + PAD;
    static_assert((size_t)(OUTBF ? BM * CW * 2 : BM * CW * 4) <= (size_t)2 * (ASZ + BSZ) * 2,
                  "epilogue stage must fit in dbuf LDS");
    __shared__ __align__(16) short smem[2 * (ASZ + BSZ)];

    int t = threadIdx.x;
    int w = t >> 6, l = t & 63;
    int l15 = l & 15, lg = l >> 4;
    int wr = w >> 2, wc = w & 3;
    int rowbase = wr * (BM / WR), colbase = wc * (BN / WC);

    int nwg = (int)(gridDim.x * gridDim.y);
    int orig = (int)(blockIdx.y * gridDim.x + blockIdx.x);
    int sid = (orig & 7) * (nwg >> 3) + (orig >> 3);
    int bx = sid % (int)gridDim.x, by = sid / (int)gridDim.x;
    int brow = by * BM, bcol = bx * BN;

    int swz = ((t & 7) ^ ((t >> 3) & 7)) * 8;
    f32x4 acc[FM][FN] = {};

    const int nt = K >> 6;

    auto stage = [&](int buf, int k0) {
        short* Ad = smem + buf * ASZ;
        short* Bd = smem + 2 * ASZ + buf * BSZ;
        #pragma unroll
        for (int it = 0; it < BM / 64; ++it) {
            int row = it * 64 + (t >> 3);
            const short* ga = A + (size_t)(brow + row) * K + k0 + swz;
            __builtin_amdgcn_global_load_lds(
                (const __attribute__((address_space(1))) unsigned int*)ga,
                (__attribute__((address_space(3))) unsigned int*)(Ad + (it * 64 + w * 8) * 64),
                16, 0, 0);
        }
        #pragma unroll
        for (int it = 0; it < BN / 64; ++it) {
            int row = it * 64 + (t >> 3);
            const short* gb = Bt + (size_t)(bcol + row) * K + k0 + swz;
            __builtin_amdgcn_global_load_lds(
                (const __attribute__((address_space(1))) unsigned int*)gb,
                (__attribute__((address_space(3))) unsigned int*)(Bd + (it * 64 + w * 8) * 64),
                16, 0, 0);
        }
    };

    stage(0, 0);
    asm volatile("s_waitcnt vmcnt(0)" ::: "memory");
    __builtin_amdgcn_s_barrier();

    int cur = 0;
    for (int kt = 0; kt < nt; ++kt) {
        if (kt + 1 < nt) stage(cur ^ 1, (kt + 1) << 6);
        const short* Ar = smem + cur * ASZ;
        const short* Br = smem + 2 * ASZ + cur * BSZ;
        #pragma unroll
        for (int kk = 0; kk < 64; kk += 32) {
            bf16x8 af[FM], bfr[FN];
            #pragma unroll
            for (int m = 0; m < FM; ++m)
                af[m] = *(const bf16x8*)(Ar + (rowbase + m * 16 + l15) * 64
                                            + (((kk >> 3) + lg) ^ (l15 & 7)) * 8);
            #pragma unroll
            for (int n = 0; n < FN; ++n)
                bfr[n] = *(const bf16x8*)(Br + (colbase + n * 16 + l15) * 64
                                             + (((kk >> 3) + lg) ^ (l15 & 7)) * 8);
            #pragma unroll
            for (int m = 0; m < FM; ++m)
                #pragma unroll
                for (int n = 0; n < FN; ++n)
                    acc[m][n] = __builtin_amdgcn_mfma_f32_16x16x32_bf16(af[m], bfr[n], acc[m][n], 0, 0, 0);
        }
        asm volatile("s_waitcnt vmcnt(0) lgkmcnt(0)" ::: "memory");
        __builtin_amdgcn_s_barrier();
        cur ^= 1;
    }

    if (OUTBF) {
        short* Cs = smem;
        #pragma unroll
        for (int m = 0; m < FM; ++m) {
            int row = rowbase + m * 16 + lg * 4;
            #pragma unroll
            for (int n = 0; n < FN; ++n) {
                int col = colbase + n * 16 + l15;
                float bv = bias ? bias[bcol + col] : 0.0f;
                #pragma unroll
                for (int r = 0; r < 4; ++r) {
                    float vv = acc[m][n][r] + bv;
                    if (ACT == 1) vv = gelu_tanh(vv);
                    Cs[(row + r) * CW + col] = f2bf(vv);
                }
            }
        }
        __syncthreads();
        #pragma unroll
        for (int it = 0; it < BM * BN / 8 / 512; ++it) {
            int c = it * 512 + t;
            int row = c / (BN / 8), c8 = c % (BN / 8);
            *(bf16x8*)(Cout + (size_t)(brow + row) * N + bcol + c8 * 8) =
                *(const bf16x8*)(Cs + row * CW + c8 * 8);
        }
    } else {
        float* Cs = (float*)smem;              // f32 staging: single rounding
        #pragma unroll
        for (int m = 0; m < FM; ++m) {
            int row = rowbase + m * 16 + lg * 4;
            #pragma unroll
            for (int n = 0; n < FN; ++n) {
                int col = colbase + n * 16 + l15;
                float bv = bias ? bias[bcol + col] : 0.0f;
                #pragma unroll
                for (int r = 0; r < 4; ++r)
                    Cs[(row + r) * CW + col] = acc[m][n][r] + bv;
            }
        }
        __syncthreads();
        #pragma unroll
        for (int it = 0; it < BM * BN / 8 / 512; ++it) {
            int c = it * 512 + t;
            int row = c / (BN / 8), c8 = c % (BN / 8);
            const float* cr = Cs + row * CW + c8 * 8;
            size_t gi = (size_t)(brow + row) * N + bcol + c8 * 8;
            bf16x8 rv = {};
            if (res) rv = *(const bf16x8*)(res + gi);
            bf16x8 outv;
            #pragma unroll
            for (int j = 0; j < 8; ++j) {
                float v = cr[j] + (res ? bf2f(rv[j]) : 0.0f);
                outv[j] = f2bf(v);
            }
            *(bf16x8*)(Cout + gi) = outv;
        }
    }
}

// ---------------------------------------------------------------------------
// Sparse block attention, MFMA bf16, KVBLK=64, swapped QK^T, dbuf K/V LDS.
// Flat 1-D grid with bijective XCD chunk swizzle (r12-proven: FETCH 55->12MB).
// Tree reductions + T13 defer-max (r14-proven).
// ---------------------------------------------------------------------------
#define KSTR 72

__global__ __launch_bounds__(256) void attn_kernel(const short* __restrict__ qkv,
                                                   const int* __restrict__ tokens,
                                                   short* __restrict__ o,
                                                   float* __restrict__ pacc,
                                                   float* __restrict__ pm,
                                                   float* __restrict__ pl,
                                                   int lyr) {
    __shared__ __align__(16) short Ks[2][64][KSTR];
    __shared__ __align__(16) short Vt[2][64][KSTR];
    __shared__ __align__(16) short Pw[4][16][KSTR];
    __shared__ unsigned long long qbits_s;
    __shared__ unsigned long long kbits_s[2];

    int nit = g_wt.n_items[lyr];
    int nwg = (int)gridDim.x;                    // nit * 32, divisible by 8
    int orig = (int)blockIdx.x;
    int sid = (orig & 7) * (nwg >> 3) + (orig >> 3);
    int item = sid % nit;
    int bh = sid / nit;
    int h = bh & 7, b = bh >> 3;

    int qb   = g_wt.itm_qb[lyr][item];
    int j0   = g_wt.itm_j0[lyr][item];
    int jn   = g_wt.itm_jn[lyr][item];
    int slot = g_wt.itm_slot[lyr][item];
    const unsigned char* jl = g_wt.jlist[lyr][qb];

    int t = threadIdx.x;
    int l = t & 63, w = t >> 6;
    int l15 = l & 15, lg = l >> 4;
    int srow = t >> 3, sdb = t & 7;

    if (t < 64) {
        unsigned long long qm = __ballot(tokens[b * L_ + qb * 64 + t] > 0);
        if (t == 0) qbits_s = qm;
    }

    int qrow = qb * 64 + w * 16 + l15;
    const short* qp = qkv + (size_t)(b * L_ + qrow) * 1536 + h * 64;
    bf16x8 qf0 = *(const bf16x8*)(qp + lg * 8);
    bf16x8 qf1 = *(const bf16x8*)(qp + lg * 8 + 32);

    f32x4 acc[4] = {};
    float m_r = -INFINITY, l_r = 0.0f;

    bf16x8 kr0, kr1, vr0, vr1;
    int pn = 0;
    auto LOAD = [&](int ci) {
        int jb = jl[j0 + ci];
        const short* base = qkv + (size_t)(b * L_ + jb * 64 + srow) * 1536 + h * 64;
        kr0 = *(const bf16x8*)(base + 512 + sdb * 8);
        kr1 = *(const bf16x8*)(base + (size_t)32 * 1536 + 512 + sdb * 8);
        vr0 = *(const bf16x8*)(base + 1024 + sdb * 8);
        vr1 = *(const bf16x8*)(base + (size_t)32 * 1536 + 1024 + sdb * 8);
        if (t < 64) pn = tokens[b * L_ + jb * 64 + t];
    };
    auto STORE = [&](int buf) {
        *(bf16x8*)&Ks[buf][srow][sdb * 8] = kr0;
        *(bf16x8*)&Ks[buf][srow + 32][sdb * 8] = kr1;
        #pragma unroll
        for (int j = 0; j < 8; ++j) {
            Vt[buf][sdb * 8 + j][(srow & 7) + 8 * ((srow >> 3) ^ sdb)] = vr0[j];
            Vt[buf][sdb * 8 + j][(srow & 7) + 8 * (((srow >> 3) + 4) ^ sdb)] = vr1[j];
        }
        if (t < 64) {
            unsigned long long km = __ballot(pn > 0);
            if (t == 0) kbits_s[buf] = km;
        }
    };

    LOAD(0);
    STORE(0);
    if (jn > 1) LOAD(1);
    __syncthreads();

    int cur = 0;
    for (int ci = 0; ci < jn; ++ci) {
        f32x4 sacc[4];
        __builtin_amdgcn_s_setprio(1);
        #pragma unroll
        for (int f = 0; f < 4; ++f) {
            bf16x8 kk0 = *(const bf16x8*)&Ks[cur][16 * f + l15][lg * 8];
            bf16x8 kk1 = *(const bf16x8*)&Ks[cur][16 * f + l15][lg * 8 + 32];
            f32x4 z = {};
            z = __builtin_amdgcn_mfma_f32_16x16x32_bf16(kk0, qf0, z, 0, 0, 0);
            z = __builtin_amdgcn_mfma_f32_16x16x32_bf16(kk1, qf1, z, 0, 0, 0);
            sacc[f] = z;
        }
        __builtin_amdgcn_s_setprio(0);

        unsigned long long kb = kbits_s[cur];
        bool pq = (qbits_s >> (w * 16 + l15)) & 1ull;
        unsigned vm = 0;
        #pragma unroll
        for (int f = 0; f < 4; ++f)
            vm |= ((unsigned)(kb >> (16 * f + 4 * lg)) & 0xFu) << (4 * f);
        if (!pq) vm = 0;

        float sv[16];
        #pragma unroll
        for (int i = 0; i < 16; ++i)
            sv[i] = ((vm >> i) & 1u) ? sacc[i >> 2][i & 3] : -INFINITY;
        float t8[8], t4[4];
        #pragma unroll
        for (int i = 0; i < 8; ++i) t8[i] = fmaxf(sv[i], sv[i + 8]);
        #pragma unroll
        for (int i = 0; i < 4; ++i) t4[i] = fmaxf(t8[i], t8[i + 4]);
        float mx = fmaxf(fmaxf(t4[0], t4[1]), fmaxf(t4[2], t4[3]));
        mx = fmaxf(mx, __shfl_xor(mx, 16, 64));
        mx = fmaxf(mx, __shfl_xor(mx, 32, 64));

        bool defer = __all((mx <= m_r + 8.0f) && (m_r > -1e30f));
        float nm = defer ? m_r : fmaxf(m_r, mx);

        float pv[16];
        #pragma unroll
        for (int i = 0; i < 16; ++i)
            pv[i] = ((vm >> i) & 1u) ? __expf(sv[i] - nm) : 0.0f;
        float s8[8], s4[4];
        #pragma unroll
        for (int i = 0; i < 8; ++i) s8[i] = pv[i] + pv[i + 8];
        #pragma unroll
        for (int i = 0; i < 4; ++i) s4[i] = s8[i] + s8[i + 4];
        float sum = (s4[0] + s4[1]) + (s4[2] + s4[3]);
        sum += __shfl_xor(sum, 16, 64);
        sum += __shfl_xor(sum, 32, 64);

        if (defer) {
            l_r += sum;
        } else {
            float al = (nm == -INFINITY) ? 1.0f : __expf(m_r - nm);
            m_r = nm;
            l_r = l_r * al + sum;
            float alr[4];
            #pragma unroll
            for (int r = 0; r < 4; ++r) alr[r] = __shfl(al, lg * 4 + r, 64);
            #pragma unroll
            for (int fd = 0; fd < 4; ++fd)
                #pragma unroll
                for (int r = 0; r < 4; ++r) acc[fd][r] *= alr[r];
        }

        #pragma unroll
        for (int f = 0; f < 4; ++f) {
            bf16x4 pk;
            #pragma unroll
            for (int r = 0; r < 4; ++r) pk[r] = f2bf(pv[4 * f + r]);
            *(bf16x4*)&Pw[w][l15][16 * f + 4 * lg] = pk;
        }

        bf16x8 pa0 = *(const bf16x8*)&Pw[w][l15][lg * 8];
        bf16x8 pa1 = *(const bf16x8*)&Pw[w][l15][lg * 8 + 32];
        __builtin_amdgcn_s_setprio(1);
        #pragma unroll
        for (int fd = 0; fd < 4; ++fd) {
            int dd = 16 * fd + l15;
            bf16x8 vv0 = *(const bf16x8*)&Vt[cur][dd][8 * (lg ^ (dd >> 3))];
            bf16x8 vv1 = *(const bf16x8*)&Vt[cur][dd][8 * ((4 + lg) ^ (dd >> 3))];
            acc[fd] = __builtin_amdgcn_mfma_f32_16x16x32_bf16(pa0, vv0, acc[fd], 0, 0, 0);
            acc[fd] = __builtin_amdgcn_mfma_f32_16x16x32_bf16(pa1, vv1, acc[fd], 0, 0, 0);
        }
        __builtin_amdgcn_s_setprio(0);

        if (ci + 1 < jn) {
            STORE(cur ^ 1);
            if (ci + 2 < jn) LOAD(ci + 2);
        }
        __syncthreads();
        cur ^= 1;
    }

    float lrr[4], mrr[4];
    #pragma unroll
    for (int r = 0; r < 4; ++r) {
        lrr[r] = __shfl(l_r, lg * 4 + r, 64);
        mrr[r] = __shfl(m_r, lg * 4 + r, 64);
    }
    unsigned long long qbits = qbits_s;

    if (slot == 0xFF) {
        #pragma unroll
        for (int r = 0; r < 4; ++r) {
            int rw = lg * 4 + r;
            int gl = qb * 64 + w * 16 + rw;
            size_t ob = (size_t)(b * L_ + gl) * 512 + h * 64 + l15;
            bool ok = ((qbits >> (w * 16 + rw)) & 1ull) && (lrr[r] > 0.0f);
            if (ok) {
                float inv = 1.0f / lrr[r];
                #pragma unroll
                for (int fd = 0; fd < 4; ++fd) o[ob + 16 * fd] = f2bf(acc[fd][r] * inv);
            } else {
                #pragma unroll
                for (int fd = 0; fd < 4; ++fd) {
                    float s = 0.0f;
                    for (int m = 0; m < L_; ++m)
                        s += bf2f(qkv[(size_t)(b * L_ + m) * 1536 + 1024 + h * 64 + 16 * fd + l15]);
                    o[ob + 16 * fd] = f2bf(s * (1.0f / L_));
                }
            }
        }
    } else {
        size_t pb = ((size_t)slot * B_ + b) * H_ + h;
        #pragma unroll
        for (int r = 0; r < 4; ++r) {
            int rloc = w * 16 + lg * 4 + r;
            #pragma unroll
            for (int fd = 0; fd < 4; ++fd)
                pacc[pb * 4096 + (size_t)rloc * 64 + 16 * fd + l15] = acc[fd][r];
            if (l15 == 0) {
                pm[pb * 64 + rloc] = mrr[r];
                pl[pb * 64 + rloc] = lrr[r];
            }
        }
    }
}

// ---------------------------------------------------------------------------
// Combine partial flash results for split q-blocks.
// ---------------------------------------------------------------------------
__global__ __launch_bounds__(256) void attn_combine(const short* __restrict__ qkv,
                                                    const int* __restrict__ tokens,
                                                    short* __restrict__ o,
                                                    const float* __restrict__ pacc,
                                                    const float* __restrict__ pm,
                                                    const float* __restrict__ pl,
                                                    int lyr) {
    int ci = blockIdx.x, h = blockIdx.y, b = blockIdx.z;
    int qb  = g_wt.cmb_qb[lyr][ci];
    int s0  = g_wt.cmb_slot0[lyr][ci];
    int nch = g_wt.cmb_nch[lyr][ci];
    int t = threadIdx.x;
    int r = t >> 2, dq = t & 3;
    int grow = qb * 64 + r;
    bool pq = tokens[b * L_ + grow] > 0;
    float M = -INFINITY;
    for (int c = 0; c < nch; ++c)
        M = fmaxf(M, pm[(((size_t)(s0 + c) * B_ + b) * H_ + h) * 64 + r]);
    size_t ob = (size_t)(b * L_ + grow) * 512 + h * 64 + dq * 16;
    if (pq && M > -1e30f) {
        float lsum = 0.0f;
        float accd[16] = {};
        for (int c = 0; c < nch; ++c) {
            size_t pb = ((size_t)(s0 + c) * B_ + b) * H_ + h;
            float wgt = __expf(pm[pb * 64 + r] - M);
            lsum += pl[pb * 64 + r] * wgt;
            const float* pa = pacc + pb * 4096 + (size_t)r * 64 + dq * 16;
            #pragma unroll
            for (int j = 0; j < 16; ++j) accd[j] += pa[j] * wgt;
        }
        float inv = 1.0f / lsum;
        #pragma unroll
        for (int j = 0; j < 16; ++j) o[ob + j] = f2bf(accd[j] * inv);
    } else {
        #pragma unroll
        for (int j = 0; j < 16; ++j) {
            float s = 0.0f;
            for (int m = 0; m < L_; ++m)
                s += bf2f(qkv[(size_t)(b * L_ + m) * 1536 + 1024 + h * 64 + dq * 16 + j]);
            o[ob + j] = f2bf(s * (1.0f / L_));
        }
    }
}

// ---------------------------------------------------------------------------
// Launch
// ---------------------------------------------------------------------------
extern "C" void kernel_launch(void* const* d_in, const int* in_sizes, int n_in,
                              void* d_out, int out_size, void* d_ws, size_t ws_size,
                              hipStream_t stream) {
    (void)in_sizes; (void)n_in; (void)out_size; (void)ws_size;
    const int*   tokens = (const int*)d_in[0];
    const float* embed  = (const float*)d_in[1];
    const float* ln1_s  = (const float*)d_in[2];
    const float* ln1_b  = (const float*)d_in[3];
    const float* wq     = (const float*)d_in[4];
    const float* wk     = (const float*)d_in[5];
    const float* wv     = (const float*)d_in[6];
    const float* wo     = (const float*)d_in[7];
    const float* ln2_s  = (const float*)d_in[8];
    const float* ln2_b  = (const float*)d_in[9];
    const float* w1     = (const float*)d_in[10];
    const float* b1     = (const float*)d_in[11];
    const float* w2     = (const float*)d_in[12];
    const float* b2     = (const float*)d_in[13];
    const float* lnf_s  = (const float*)d_in[14];
    const float* lnf_b  = (const float*)d_in[15];
    float* out = (float*)d_out;

    const size_t BLE = (size_t)B_ * L_ * E_;              // 4,194,304
    char* ws = (char*)d_ws;
    short* x    = (short*)ws;                             // bf16 residual, 8 MB
    short* yb   = x + BLE;                                //  8 MB
    short* R    = yb + BLE;                               // 32 MB (qkv+ob / hb)
    short* qkv  = R;
    short* ob   = R + 3 * BLE;
    short* hb   = R;
    short* qkvt = R + 4 * BLE;                            // bf16 weights
    short* wot  = qkvt + (size_t)NL_ * 1536 * 512;
    short* w1t  = wot + (size_t)NL_ * 512 * 512;
    short* w2t  = w1t + (size_t)NL_ * 2048 * 512;
    float* pacc = (float*)(w2t + (size_t)NL_ * 512 * 2048);   // 8 slots x B x H x 4096 f32
    float* pm   = pacc + (size_t)8 * B_ * H_ * 4096;
    float* pl   = pm + (size_t)8 * B_ * H_ * 64;

    convT_kernel<<<dim3(8, 8, NL_), 256, 0, stream>>>(wq, qkvt,          512, 512, 262144, 786432, 0.125f);
    convT_kernel<<<dim3(8, 8, NL_), 256, 0, stream>>>(wk, qkvt + 262144, 512, 512, 262144, 786432, 1.0f);
    convT_kernel<<<dim3(8, 8, NL_), 256, 0, stream>>>(wv, qkvt + 524288, 512, 512, 262144, 786432, 1.0f);
    convT_kernel<<<dim3(8, 8, NL_), 256, 0, stream>>>(wo, wot,           512, 512, 262144, 262144, 1.0f);
    convT_kernel<<<dim3(32, 8, NL_), 256, 0, stream>>>(w1, w1t,          512, 2048, 1048576, 1048576, 1.0f);
    convT_kernel<<<dim3(8, 32, NL_), 256, 0, stream>>>(w2, w2t,          2048, 512, 1048576, 1048576, 1.0f);

    embed_kernel<<<(L_ * E_ / 8) / 256, 256, 0, stream>>>(tokens, embed, x);

    const int MR = B_ * L_;
    const int LNG = MR / 4;                                // 2048 blocks
    for (int lyr = 0; lyr < NL_; ++lyr) {
        ln_kernel<1><<<LNG, 256, 0, stream>>>(x, ln1_s + lyr * E_, ln1_b + lyr * E_, yb);
        mgemm_kernel<128, 128, 0, 1><<<dim3(12, 64), 512, 0, stream>>>(
            yb, qkvt + (size_t)lyr * 786432, nullptr, nullptr, qkv, MR, 1536, 512);
        attn_kernel<<<dim3(WT_HOST.n_items[lyr] * H_ * B_), 256, 0, stream>>>(
            qkv, tokens, ob, pacc, pm, pl, lyr);
        attn_combine<<<dim3(WT_HOST.n_cmb[lyr], H_, B_), 256, 0, stream>>>(
            qkv, tokens, ob, pacc, pm, pl, lyr);
        mgemm_kernel<64, 128, 0, 0><<<dim3(4, 128), 512, 0, stream>>>(
            ob, wot + (size_t)lyr * 262144, nullptr, x, x, MR, 512, 512);
        ln_kernel<1><<<LNG, 256, 0, stream>>>(x, ln2_s + lyr * E_, ln2_b + lyr * E_, yb);
        mgemm_kernel<128, 128, 1, 1><<<dim3(16, 64), 512, 0, stream>>>(
            yb, w1t + (size_t)lyr * 1048576, b1 + (size_t)lyr * M_, nullptr, hb, MR, 2048, 512);
        mgemm_kernel<64, 128, 0, 0><<<dim3(4, 128), 512, 0, stream>>>(
            hb, w2t + (size_t)lyr * 1048576, b2 + (size_t)lyr * E_, x, x, MR, 512, 2048);
    }
    ln_kernel<0><<<LNG, 256, 0, stream>>>(x, lnf_s, lnf_b, out);
}